// Round 13
// baseline (347.093 us; speedup 1.0000x reference)
//
#include <hip/hip_runtime.h>
#include <stdint.h>

typedef __attribute__((ext_vector_type(8))) short short8;
typedef __attribute__((ext_vector_type(4))) float f32x4;

#define NN 1024
#define NBATCH 16384
#define ME ((size_t)NN * NN)

__device__ __forceinline__ unsigned short f32_to_bf16_rne(float f) {
  unsigned int u = __float_as_uint(f);
  unsigned int r = (u + 0x7fffu + ((u >> 16) & 1u)) >> 16;
  return (unsigned short)r;
}

__device__ __forceinline__ unsigned int pack2bf(float lo, float hi) {
  return (unsigned int)f32_to_bf16_rne(lo) | ((unsigned int)f32_to_bf16_rne(hi) << 16);
}

// split f32 -> bf16 hi + bf16 lo (x ~= hi + lo, captures ~16 mantissa bits)
__device__ __forceinline__ void split_bf16(float x, unsigned short& h, unsigned short& l) {
  h = f32_to_bf16_rne(x);
  float hf = __uint_as_float((unsigned int)h << 16);
  l = f32_to_bf16_rne(x - hf);
}

// 64-lane all-reduce sum (VALU only).
__device__ __forceinline__ float allsum64(float x) {
  x += __int_as_float(__builtin_amdgcn_update_dpp(0, __float_as_int(x), 0xB1, 0xF, 0xF, true));
  x += __int_as_float(__builtin_amdgcn_update_dpp(0, __float_as_int(x), 0x4E, 0xF, 0xF, true));
  x += __int_as_float(__builtin_amdgcn_update_dpp(0, __float_as_int(x), 0x141, 0xF, 0xF, true));
  x += __int_as_float(__builtin_amdgcn_update_dpp(0, __float_as_int(x), 0x140, 0xF, 0xF, true));
#if __has_builtin(__builtin_amdgcn_permlane16_swap) && __has_builtin(__builtin_amdgcn_permlane32_swap)
  {
    auto r16 = __builtin_amdgcn_permlane16_swap(__float_as_uint(x), __float_as_uint(x), false, false);
    x = __uint_as_float(r16[0]) + __uint_as_float(r16[1]);
    auto r32 = __builtin_amdgcn_permlane32_swap(__float_as_uint(x), __float_as_uint(x), false, false);
    x = __uint_as_float(r32[0]) + __uint_as_float(r32[1]);
  }
#else
  x += __int_as_float(__builtin_amdgcn_ds_swizzle(__float_as_int(x), 0x401F));
  x += __shfl_xor(x, 32);
#endif
  return x;
}

// -------------------- prep: tau = 2/(u.u), sigmas --------------------
__global__ __launch_bounds__(256) void prep_kernel(
    const float* __restrict__ U, const float* __restrict__ V,
    const float* __restrict__ p, float* __restrict__ tau_u,
    float* __restrict__ tau_v, float* __restrict__ sigmas) {
  int wave = threadIdx.x >> 6, lane = threadIdx.x & 63;
  int row = blockIdx.x * 4 + wave;
  if (row < 2048) {
    const float* u = (row < NN) ? (U + (size_t)row * NN) : (V + (size_t)(row - NN) * NN);
    float s = 0.f;
#pragma unroll
    for (int t = 0; t < 16; ++t) { float a = u[lane + (t << 6)]; s += a * a; }
    s = allsum64(s);
    if (lane == 0) {
      float tau = 2.0f / s;
      if (row < NN) tau_u[row] = tau;
      else tau_v[row - NN] = tau;
    }
  } else if (row < 2064) {
    int j = ((row - 2048) << 6) + lane;
    float pj = p[j];
    float sg = 1.0f / (1.0f + expf(-pj));
    sigmas[j] = 0.9f * (sg - 0.5f) + 0.55f;  // r=0.45, mean=0.55
  }
}

// -------------------- gram + T8 per block of 8 reflectors --------------------
__global__ __launch_bounds__(64) void gram_t8_kernel(
    const float* __restrict__ U, const float* __restrict__ V,
    const float* __restrict__ tau_u, const float* __restrict__ tau_v,
    float* __restrict__ T8all) {
  __shared__ float G[64];
  const int blk = blockIdx.x;
  const int lane = threadIdx.x;
  const float* bank;
  int rbase, rsign, st;
  if (blk < 128) { bank = U; rbase = 8 * blk; rsign = 1; st = 8 * blk; }
  else { int s = blk - 128; bank = V; rbase = 1023 - 8 * s; rsign = -1; st = 1016 - 8 * s; }

  if (lane < 28) {
    int j = 1, k = 0, t = lane;
    for (int jj = 1; jj < 8; ++jj) {
      int lo = jj * (jj - 1) / 2, hi = jj * (jj + 1) / 2;
      if (t >= lo && t < hi) { j = jj; k = t - lo; }
    }
    const float* rk = bank + (size_t)(rbase + rsign * k) * NN;
    const float* rj = bank + (size_t)(rbase + rsign * j) * NN;
    float acc = 0.f;
    for (int i = st >> 2; i < 256; ++i) {
      float4 a = *reinterpret_cast<const float4*>(rk + 4 * i);
      float4 b = *reinterpret_cast<const float4*>(rj + 4 * i);
      acc += a.x * b.x + a.y * b.y + a.z * b.z + a.w * b.w;
    }
    G[k * 8 + j] = acc;
  }
  __syncthreads();

  if (lane < 8) {
    float Tr[8];
#pragma unroll
    for (int j = 0; j < 8; ++j) Tr[j] = 0.f;
#pragma unroll
    for (int j = 0; j < 8; ++j) {
      int grow = rbase + rsign * j;
      float tj = (blk < 128) ? tau_u[grow] : tau_v[grow];
      float a = 0.f;
#pragma unroll
      for (int k = 0; k < 8; ++k) {
        if (k < j) a += Tr[k] * G[k * 8 + j];
      }
      Tr[j] = (lane == j) ? tj : (-tj * a);
    }
#pragma unroll
    for (int j = 0; j < 8; ++j) T8all[(size_t)blk * 64 + lane * 8 + j] = Tr[j];
  }
}

// -------------------- splitY: chain-slot rows -> split bf16, rm + transposed ----
__global__ __launch_bounds__(256) void splity_kernel(
    const float* __restrict__ U, const float* __restrict__ V,
    unsigned short* __restrict__ Yhi, unsigned short* __restrict__ Ylo,
    unsigned short* __restrict__ YThi, unsigned short* __restrict__ YTlo) {
  __shared__ float ys[128][129];
  const int tid = threadIdx.x;
  const int c = blockIdx.x >> 3, et = blockIdx.x & 7;
  const int half = tid & 1;
  const int slot = tid >> 1;
  const int e0 = et << 7;
  const int grow = (c < 8) ? ((c << 7) + slot) : (1023 - ((c - 8) << 7) - slot);
  const float* src = ((c < 8) ? U : V) + (size_t)grow * NN + e0 + (half << 6);
#pragma unroll
  for (int i = 0; i < 16; ++i) {
    float4 v4 = *reinterpret_cast<const float4*>(src + (i << 2));
    const int kk = (half << 6) + (i << 2);
    ys[slot][kk + 0] = v4.x; ys[slot][kk + 1] = v4.y;
    ys[slot][kk + 2] = v4.z; ys[slot][kk + 3] = v4.w;
  }
  __syncthreads();
  {
    const size_t rbase = ((size_t)(c * 128 + slot)) * NN + e0 + (half << 6);
#pragma unroll
    for (int i = 0; i < 16; ++i) {
      const int kk = (half << 6) + (i << 2);
      ushort4 h4, l4;
      split_bf16(ys[slot][kk + 0], h4.x, l4.x);
      split_bf16(ys[slot][kk + 1], h4.y, l4.y);
      split_bf16(ys[slot][kk + 2], h4.z, l4.z);
      split_bf16(ys[slot][kk + 3], h4.w, l4.w);
      *reinterpret_cast<ushort4*>(&Yhi[rbase + (i << 2)]) = h4;
      *reinterpret_cast<ushort4*>(&Ylo[rbase + (i << 2)]) = l4;
    }
  }
  {
    const int e = slot;
    const size_t tbase = ((size_t)c * 1024 + e0 + e) * 128 + (half << 6);
#pragma unroll
    for (int i = 0; i < 16; ++i) {
      const int k0 = (half << 6) + (i << 2);
      ushort4 h4, l4;
      split_bf16(ys[k0 + 0][e], h4.x, l4.x);
      split_bf16(ys[k0 + 1][e], h4.y, l4.y);
      split_bf16(ys[k0 + 2][e], h4.z, l4.z);
      split_bf16(ys[k0 + 3][e], h4.w, l4.w);
      *reinterpret_cast<ushort4*>(&YThi[tbase + (i << 2)]) = h4;
      *reinterpret_cast<ushort4*>(&YTlo[tbase + (i << 2)]) = l4;
    }
  }
}

#define LDK 40
#define BM 128
#define BN 128
#define BK 32

// legacy fragment+MFMA step (LDK-stride LDS; used by reg-staged kernels)
__device__ __forceinline__ void tile_compute(
    const unsigned short* __restrict__ As, const unsigned short* __restrict__ Bs,
    f32x4 acc[4][4], int arow0, int brow0, int fr, int kb) {
  short8 af[4], bf[4];
#pragma unroll
  for (int tr = 0; tr < 4; ++tr)
    af[tr] = *reinterpret_cast<const short8*>(&As[(arow0 + tr * 16 + fr) * LDK + kb]);
#pragma unroll
  for (int tc = 0; tc < 4; ++tc)
    bf[tc] = *reinterpret_cast<const short8*>(&Bs[(brow0 + tc * 16 + fr) * LDK + kb]);
#pragma unroll
  for (int tr = 0; tr < 4; ++tr)
#pragma unroll
    for (int tc = 0; tc < 4; ++tc)
      acc[tr][tc] = __builtin_amdgcn_mfma_f32_16x16x32_bf16(af[tr], bf[tc], acc[tr][tc], 0, 0, 0);
}

// -------------------- gramT (K-split 8x): Gp[c*8+ks] partial grams ----
__global__ __launch_bounds__(256) void gramt_kernel(
    const unsigned short* __restrict__ Yhi, const unsigned short* __restrict__ Ylo,
    float* __restrict__ Gp) {
  __shared__ unsigned short Hs[128 * LDK];
  __shared__ unsigned short Ls[128 * LDK];
  const int tid = threadIdx.x;
  const int lane = tid & 63, wave = tid >> 6;
  const int c = blockIdx.x >> 3, ks = blockIdx.x & 7;
  const int wm = wave & 1, wn = wave >> 1;
  const int srow = tid >> 1, scol = (tid & 1) << 4;
  const unsigned short* ph = Yhi + ((size_t)(c * 128 + srow)) * NN + ks * 128 + scol;
  const unsigned short* pl = Ylo + ((size_t)(c * 128 + srow)) * NN + ks * 128 + scol;

  f32x4 acc[4][4];
#pragma unroll
  for (int a = 0; a < 4; ++a)
#pragma unroll
    for (int b = 0; b < 4; ++b) acc[a][b] = 0.f;

  const int arow0 = wm * 64, brow0 = wn * 64;
  const int fr = lane & 15, kb = (lane >> 4) << 3;

#pragma unroll 1
  for (int kt = 0; kt < 4; ++kt) {
    __syncthreads();
    *reinterpret_cast<uint4*>(&Hs[srow * LDK + scol]) = *reinterpret_cast<const uint4*>(ph + kt * 32);
    *reinterpret_cast<uint4*>(&Hs[srow * LDK + scol + 8]) = *reinterpret_cast<const uint4*>(ph + kt * 32 + 8);
    *reinterpret_cast<uint4*>(&Ls[srow * LDK + scol]) = *reinterpret_cast<const uint4*>(pl + kt * 32);
    *reinterpret_cast<uint4*>(&Ls[srow * LDK + scol + 8]) = *reinterpret_cast<const uint4*>(pl + kt * 32 + 8);
    __syncthreads();
    short8 ah[4], al[4], bh[4], bl[4];
#pragma unroll
    for (int tr = 0; tr < 4; ++tr) {
      ah[tr] = *reinterpret_cast<const short8*>(&Hs[(arow0 + tr * 16 + fr) * LDK + kb]);
      al[tr] = *reinterpret_cast<const short8*>(&Ls[(arow0 + tr * 16 + fr) * LDK + kb]);
    }
#pragma unroll
    for (int tc = 0; tc < 4; ++tc) {
      bh[tc] = *reinterpret_cast<const short8*>(&Hs[(brow0 + tc * 16 + fr) * LDK + kb]);
      bl[tc] = *reinterpret_cast<const short8*>(&Ls[(brow0 + tc * 16 + fr) * LDK + kb]);
    }
#pragma unroll
    for (int tr = 0; tr < 4; ++tr)
#pragma unroll
      for (int tc = 0; tc < 4; ++tc) {
        acc[tr][tc] = __builtin_amdgcn_mfma_f32_16x16x32_bf16(ah[tr], bh[tc], acc[tr][tc], 0, 0, 0);
        acc[tr][tc] = __builtin_amdgcn_mfma_f32_16x16x32_bf16(ah[tr], bl[tc], acc[tr][tc], 0, 0, 0);
        acc[tr][tc] = __builtin_amdgcn_mfma_f32_16x16x32_bf16(al[tr], bh[tc], acc[tr][tc], 0, 0, 0);
      }
  }
  const int rq = (lane >> 4) << 2;
#pragma unroll
  for (int tc = 0; tc < 4; ++tc) {
    const int gc = brow0 + tc * 16 + fr;
#pragma unroll
    for (int tr = 0; tr < 4; ++tr) {
      const int gr = arow0 + tr * 16 + rq;
#pragma unroll
      for (int q = 0; q < 4; ++q)
        Gp[(((size_t)c * 8 + ks) * 128 + gr + q) * 128 + gc] = acc[tr][tc][q];
    }
  }
}

// -------------------- ttree: aggregate T8 -> T128 per chain (f32, in LDS) ----
__global__ __launch_bounds__(256) void ttree_kernel(
    const float* __restrict__ Gp, const float* __restrict__ T8all,
    unsigned short* __restrict__ Thi, unsigned short* __restrict__ Tlo) {
  __shared__ float Ts[128 * 128];  // 64 KB
  __shared__ float Gb[64 * 64];    // 16 KB
  __shared__ float Xb[64 * 64];    // 16 KB
  const int c = blockIdx.x, tid = threadIdx.x;
  for (int i = tid; i < 128 * 128; i += 256) Ts[i] = 0.f;
  __syncthreads();
  for (int i = tid; i < 1024; i += 256) {
    const int sb = i >> 6, ij = i & 63, r = ij >> 3, col = ij & 7;
    const int t8i = (c < 8) ? (16 * c + sb) : (128 + 16 * (c - 8) + sb);
    Ts[(8 * sb + r) * 128 + 8 * sb + col] = T8all[(size_t)t8i * 64 + ij];
  }
  __syncthreads();
  for (int b = 8; b <= 64; b <<= 1) {
    const int nm = 128 / (2 * b);
    for (int m = 0; m < nm; ++m) {
      const int a0 = 2 * b * m;
      for (int i = tid; i < b * b; i += 256) {
        const int r = i / b, cl = i % b;
        float s = 0.f;
#pragma unroll
        for (int sl = 0; sl < 8; ++sl)
          s += Gp[(((size_t)c * 8 + sl) * 128 + a0 + r) * 128 + a0 + b + cl];
        Gb[i] = s;
      }
      __syncthreads();
      for (int i = tid; i < b * b; i += 256) {
        const int r = i / b, cl = i % b;
        float s = 0.f;
        for (int k = 0; k <= cl; ++k)
          s += Gb[r * b + k] * Ts[(a0 + b + k) * 128 + a0 + b + cl];
        Xb[i] = s;
      }
      __syncthreads();
      for (int i = tid; i < b * b; i += 256) {
        const int r = i / b, cl = i % b;
        float s = 0.f;
        for (int k = r; k < b; ++k)
          s -= Ts[(a0 + r) * 128 + a0 + k] * Xb[k * b + cl];
        Ts[(a0 + r) * 128 + a0 + b + cl] = s;
      }
      __syncthreads();
    }
  }
  for (int i = tid; i < 128 * 128; i += 256) {
    unsigned short h, l;
    split_bf16(Ts[i], h, l);
    Thi[(size_t)c * 128 * 128 + i] = h;
    Tlo[(size_t)c * 128 * 128 + i] = l;
  }
}

// -------------------- zw: W = T*Y -> store W^T split bf16 ----
__global__ __launch_bounds__(256) void zw_kernel(
    const unsigned short* __restrict__ Thi, const unsigned short* __restrict__ Tlo,
    const unsigned short* __restrict__ YThi, const unsigned short* __restrict__ YTlo,
    unsigned short* __restrict__ WThi, unsigned short* __restrict__ WTlo) {
  __shared__ unsigned short Xh[128 * LDK], Xl[128 * LDK];
  __shared__ unsigned short Wh[128 * LDK], Wl[128 * LDK];
  const int tid = threadIdx.x;
  const int lane = tid & 63, wave = tid >> 6;
  const int c = blockIdx.x >> 3, bn = blockIdx.x & 7;
  const int n0 = bn * 128;
  const int wm = wave & 1, wn = wave >> 1;
  const int srow = tid >> 1, scol = (tid & 1) << 4;
  const unsigned short* pxh = Thi + ((size_t)c * 128 + srow) * 128 + scol;
  const unsigned short* pxl = Tlo + ((size_t)c * 128 + srow) * 128 + scol;
  const unsigned short* pwh = YThi + ((size_t)c * 1024 + n0 + srow) * 128 + scol;
  const unsigned short* pwl = YTlo + ((size_t)c * 1024 + n0 + srow) * 128 + scol;

  f32x4 acc[4][4];
#pragma unroll
  for (int a = 0; a < 4; ++a)
#pragma unroll
    for (int b = 0; b < 4; ++b) acc[a][b] = 0.f;

  const int arow0 = wm * 64, brow0 = wn * 64;
  const int fr = lane & 15, kb = (lane >> 4) << 3;

#pragma unroll 1
  for (int kt = 0; kt < 4; ++kt) {
    __syncthreads();
    *reinterpret_cast<uint4*>(&Xh[srow * LDK + scol]) = *reinterpret_cast<const uint4*>(pxh + kt * 32);
    *reinterpret_cast<uint4*>(&Xh[srow * LDK + scol + 8]) = *reinterpret_cast<const uint4*>(pxh + kt * 32 + 8);
    *reinterpret_cast<uint4*>(&Xl[srow * LDK + scol]) = *reinterpret_cast<const uint4*>(pxl + kt * 32);
    *reinterpret_cast<uint4*>(&Xl[srow * LDK + scol + 8]) = *reinterpret_cast<const uint4*>(pxl + kt * 32 + 8);
    *reinterpret_cast<uint4*>(&Wh[srow * LDK + scol]) = *reinterpret_cast<const uint4*>(pwh + kt * 32);
    *reinterpret_cast<uint4*>(&Wh[srow * LDK + scol + 8]) = *reinterpret_cast<const uint4*>(pwh + kt * 32 + 8);
    *reinterpret_cast<uint4*>(&Wl[srow * LDK + scol]) = *reinterpret_cast<const uint4*>(pwl + kt * 32);
    *reinterpret_cast<uint4*>(&Wl[srow * LDK + scol + 8]) = *reinterpret_cast<const uint4*>(pwl + kt * 32 + 8);
    __syncthreads();
    short8 ah[4], al[4], bh[4], bl[4];
#pragma unroll
    for (int tr = 0; tr < 4; ++tr) {
      ah[tr] = *reinterpret_cast<const short8*>(&Xh[(arow0 + tr * 16 + fr) * LDK + kb]);
      al[tr] = *reinterpret_cast<const short8*>(&Xl[(arow0 + tr * 16 + fr) * LDK + kb]);
    }
#pragma unroll
    for (int tc = 0; tc < 4; ++tc) {
      bh[tc] = *reinterpret_cast<const short8*>(&Wh[(brow0 + tc * 16 + fr) * LDK + kb]);
      bl[tc] = *reinterpret_cast<const short8*>(&Wl[(brow0 + tc * 16 + fr) * LDK + kb]);
    }
#pragma unroll
    for (int tr = 0; tr < 4; ++tr)
#pragma unroll
      for (int tc = 0; tc < 4; ++tc) {
        acc[tr][tc] = __builtin_amdgcn_mfma_f32_16x16x32_bf16(ah[tr], bh[tc], acc[tr][tc], 0, 0, 0);
        acc[tr][tc] = __builtin_amdgcn_mfma_f32_16x16x32_bf16(ah[tr], bl[tc], acc[tr][tc], 0, 0, 0);
        acc[tr][tc] = __builtin_amdgcn_mfma_f32_16x16x32_bf16(al[tr], bh[tc], acc[tr][tc], 0, 0, 0);
      }
  }
  const int rq = (lane >> 4) << 2;
#pragma unroll
  for (int tc = 0; tc < 4; ++tc) {
    const int gc = brow0 + tc * 16 + fr;
#pragma unroll
    for (int tr = 0; tr < 4; ++tr) {
      const int gr = arow0 + tr * 16 + rq;
      ushort4 h4, l4;
      split_bf16(acc[tr][tc][0], h4.x, l4.x);
      split_bf16(acc[tr][tc][1], h4.y, l4.y);
      split_bf16(acc[tr][tc][2], h4.z, l4.z);
      split_bf16(acc[tr][tc][3], h4.w, l4.w);
      const size_t off = ((size_t)c * 1024 + n0 + gc) * 128 + gr;
      *reinterpret_cast<ushort4*>(&WThi[off]) = h4;
      *reinterpret_cast<ushort4*>(&WTlo[off]) = l4;
    }
  }
}

// -------------------- chainC: C = I - Y^T W per chain ----
__global__ __launch_bounds__(256) void chainc_kernel(
    const unsigned short* __restrict__ YThi, const unsigned short* __restrict__ YTlo,
    const unsigned short* __restrict__ WThi, const unsigned short* __restrict__ WTlo,
    unsigned short* __restrict__ chains) {
  __shared__ unsigned short Xh[128 * LDK], Xl[128 * LDK];
  __shared__ unsigned short Wh[128 * LDK], Wl[128 * LDK];
  const int tid = threadIdx.x;
  const int lane = tid & 63, wave = tid >> 6;
  const int c = blockIdx.x >> 6, b6 = blockIdx.x & 63;
  const int bm = b6 & 7, bn = b6 >> 3;
  const int m0 = bm * 128, n0 = bn * 128;
  const int wm = wave & 1, wn = wave >> 1;
  const int srow = tid >> 1, scol = (tid & 1) << 4;
  const unsigned short* pxh = YThi + ((size_t)c * 1024 + m0 + srow) * 128 + scol;
  const unsigned short* pxl = YTlo + ((size_t)c * 1024 + m0 + srow) * 128 + scol;
  const unsigned short* pwh = WThi + ((size_t)c * 1024 + n0 + srow) * 128 + scol;
  const unsigned short* pwl = WTlo + ((size_t)c * 1024 + n0 + srow) * 128 + scol;

  f32x4 acc[4][4];
#pragma unroll
  for (int a = 0; a < 4; ++a)
#pragma unroll
    for (int b = 0; b < 4; ++b) acc[a][b] = 0.f;

  const int arow0 = wm * 64, brow0 = wn * 64;
  const int fr = lane & 15, kb = (lane >> 4) << 3;

#pragma unroll 1
  for (int kt = 0; kt < 4; ++kt) {
    __syncthreads();
    *reinterpret_cast<uint4*>(&Xh[srow * LDK + scol]) = *reinterpret_cast<const uint4*>(pxh + kt * 32);
    *reinterpret_cast<uint4*>(&Xh[srow * LDK + scol + 8]) = *reinterpret_cast<const uint4*>(pxh + kt * 32 + 8);
    *reinterpret_cast<uint4*>(&Xl[srow * LDK + scol]) = *reinterpret_cast<const uint4*>(pxl + kt * 32);
    *reinterpret_cast<uint4*>(&Xl[srow * LDK + scol + 8]) = *reinterpret_cast<const uint4*>(pxl + kt * 32 + 8);
    *reinterpret_cast<uint4*>(&Wh[srow * LDK + scol]) = *reinterpret_cast<const uint4*>(pwh + kt * 32);
    *reinterpret_cast<uint4*>(&Wh[srow * LDK + scol + 8]) = *reinterpret_cast<const uint4*>(pwh + kt * 32 + 8);
    *reinterpret_cast<uint4*>(&Wl[srow * LDK + scol]) = *reinterpret_cast<const uint4*>(pwl + kt * 32);
    *reinterpret_cast<uint4*>(&Wl[srow * LDK + scol + 8]) = *reinterpret_cast<const uint4*>(pwl + kt * 32 + 8);
    __syncthreads();
    short8 ah[4], al[4], bh[4], bl[4];
#pragma unroll
    for (int tr = 0; tr < 4; ++tr) {
      ah[tr] = *reinterpret_cast<const short8*>(&Xh[(arow0 + tr * 16 + fr) * LDK + kb]);
      al[tr] = *reinterpret_cast<const short8*>(&Xl[(arow0 + tr * 16 + fr) * LDK + kb]);
    }
#pragma unroll
    for (int tc = 0; tc < 4; ++tc) {
      bh[tc] = *reinterpret_cast<const short8*>(&Wh[(brow0 + tc * 16 + fr) * LDK + kb]);
      bl[tc] = *reinterpret_cast<const short8*>(&Wl[(brow0 + tc * 16 + fr) * LDK + kb]);
    }
#pragma unroll
    for (int tr = 0; tr < 4; ++tr)
#pragma unroll
      for (int tc = 0; tc < 4; ++tc) {
        acc[tr][tc] = __builtin_amdgcn_mfma_f32_16x16x32_bf16(ah[tr], bh[tc], acc[tr][tc], 0, 0, 0);
        acc[tr][tc] = __builtin_amdgcn_mfma_f32_16x16x32_bf16(ah[tr], bl[tc], acc[tr][tc], 0, 0, 0);
        acc[tr][tc] = __builtin_amdgcn_mfma_f32_16x16x32_bf16(al[tr], bh[tc], acc[tr][tc], 0, 0, 0);
      }
  }
  unsigned short* dst = chains + (size_t)c * ME;
  const int rq = (lane >> 4) << 2;
  if ((c & 1) == 0) {
#pragma unroll
    for (int tc = 0; tc < 4; ++tc) {
      const int gcg = n0 + brow0 + tc * 16 + fr;
#pragma unroll
      for (int tr = 0; tr < 4; ++tr) {
        const int grg = m0 + arow0 + tr * 16 + rq;
#pragma unroll
        for (int q = 0; q < 4; ++q) {
          const float val = ((grg + q) == gcg ? 1.0f : 0.0f) - acc[tr][tc][q];
          dst[(size_t)(grg + q) * NN + gcg] = f32_to_bf16_rne(val);
        }
      }
    }
  } else {
#pragma unroll
    for (int tc = 0; tc < 4; ++tc) {
      const int gcg = n0 + brow0 + tc * 16 + fr;
#pragma unroll
      for (int tr = 0; tr < 4; ++tr) {
        const int grg = m0 + arow0 + tr * 16 + rq;
        ushort4 pk;
        pk.x = f32_to_bf16_rne(((grg + 0) == gcg ? 1.0f : 0.0f) - acc[tr][tc][0]);
        pk.y = f32_to_bf16_rne(((grg + 1) == gcg ? 1.0f : 0.0f) - acc[tr][tc][1]);
        pk.z = f32_to_bf16_rne(((grg + 2) == gcg ? 1.0f : 0.0f) - acc[tr][tc][2]);
        pk.w = f32_to_bf16_rne(((grg + 3) == gcg ? 1.0f : 0.0f) - acc[tr][tc][3]);
        *reinterpret_cast<ushort4*>(&dst[(size_t)gcg * NN + grg]) = pk;
      }
    }
  }
}

// -------------------- 1024^3 bf16 compose, m97-style (global_load_lds) ----
// Linear LDS [128][32] bf16, dbuf; both-sides XOR swizzle: 16B chunk slot s of
// row r holds global chunk s ^ ((r>>1)&3)  -> ds_read 2-way conflicts only.
__device__ __forceinline__ void stage_bf16_tile(
    const unsigned short* __restrict__ gbase, unsigned short* __restrict__ lds,
    int tid, int kt) {
#pragma unroll
  for (int i = 0; i < 2; ++i) {
    const int slot = tid + 256 * i;
    const int row = slot >> 2, s = slot & 3;
    const int cs = s ^ ((row >> 1) & 3);
    __builtin_amdgcn_global_load_lds(
        (const __attribute__((address_space(1))) void*)(gbase + (size_t)row * NN + kt * 32 + cs * 8),
        (__attribute__((address_space(3))) void*)(lds + row * 32 + s * 8), 16, 0, 0);
  }
}

__device__ __forceinline__ void tile_compute32(
    const unsigned short* __restrict__ As, const unsigned short* __restrict__ Bs,
    f32x4 acc[4][4], int arow0, int brow0, int fr, int kb) {
  short8 af[4], bf[4];
  const int ck = kb >> 3;
#pragma unroll
  for (int tr = 0; tr < 4; ++tr) {
    const int row = arow0 + tr * 16 + fr;
    const int sl = ck ^ ((row >> 1) & 3);
    af[tr] = *reinterpret_cast<const short8*>(&As[row * 32 + sl * 8]);
  }
#pragma unroll
  for (int tc = 0; tc < 4; ++tc) {
    const int row = brow0 + tc * 16 + fr;
    const int sl = ck ^ ((row >> 1) & 3);
    bf[tc] = *reinterpret_cast<const short8*>(&Bs[row * 32 + sl * 8]);
  }
#pragma unroll
  for (int tr = 0; tr < 4; ++tr)
#pragma unroll
    for (int tc = 0; tc < 4; ++tc)
      acc[tr][tc] = __builtin_amdgcn_mfma_f32_16x16x32_bf16(af[tr], bf[tc], acc[tr][tc], 0, 0, 0);
}

__device__ __forceinline__ void compose_body(
    const unsigned short* __restrict__ Xb, const unsigned short* __restrict__ Wb,
    unsigned short* __restrict__ Op, const float* __restrict__ sig, int b, bool tstore) {
  __shared__ unsigned short As[2][BM * 32];
  __shared__ unsigned short Bs[2][BN * 32];
  const int tid = threadIdx.x;
  const int lane = tid & 63, wave = tid >> 6;
  const int bm = b & 7, bn = b >> 3;
  const int m0 = bm * BM, n0 = bn * BN;
  const int wm = wave & 1, wn = wave >> 1;
  const int arow0 = wm * 64, brow0 = wn * 64;
  const int fr = lane & 15, kb = (lane >> 4) << 3;

  f32x4 acc[4][4];
#pragma unroll
  for (int a = 0; a < 4; ++a)
#pragma unroll
    for (int bb = 0; bb < 4; ++bb) acc[a][bb] = 0.f;

  const unsigned short* agbase = Xb + (size_t)m0 * NN;
  const unsigned short* bgbase = Wb + (size_t)n0 * NN;

  stage_bf16_tile(agbase, &As[0][0], tid, 0);
  stage_bf16_tile(bgbase, &Bs[0][0], tid, 0);
  int pb = 0;
#pragma unroll 1
  for (int kt = 0; kt < 32; ++kt) {
    __syncthreads();  // staged buf landed (vmcnt drain), prev buf's reads done
    if (kt + 1 < 32) {
      stage_bf16_tile(agbase, &As[pb ^ 1][0], tid, kt + 1);
      stage_bf16_tile(bgbase, &Bs[pb ^ 1][0], tid, kt + 1);
    }
    tile_compute32(&As[pb][0], &Bs[pb][0], acc, arow0, brow0, fr, kb);
    pb ^= 1;
  }

  const int rq = (lane >> 4) << 2;
  if (!tstore) {
#pragma unroll
    for (int tc = 0; tc < 4; ++tc) {
      const int gc = n0 + brow0 + tc * 16 + fr;
      const float s = sig ? sig[gc] : 1.0f;
#pragma unroll
      for (int tr = 0; tr < 4; ++tr) {
        const int gr = m0 + arow0 + tr * 16 + rq;
#pragma unroll
        for (int q = 0; q < 4; ++q) {
          Op[(size_t)(gr + q) * NN + gc] = f32_to_bf16_rne(acc[tr][tc][q] * s);
        }
      }
    }
  } else {
#pragma unroll
    for (int tc = 0; tc < 4; ++tc) {
      const int gc = n0 + brow0 + tc * 16 + fr;
#pragma unroll
      for (int tr = 0; tr < 4; ++tr) {
        const int gr = m0 + arow0 + tr * 16 + rq;
        ushort4 pk;
        pk.x = f32_to_bf16_rne(acc[tr][tc][0]);
        pk.y = f32_to_bf16_rne(acc[tr][tc][1]);
        pk.z = f32_to_bf16_rne(acc[tr][tc][2]);
        pk.w = f32_to_bf16_rne(acc[tr][tc][3]);
        *reinterpret_cast<ushort4*>(&Op[(size_t)gc * NN + gr]) = pk;  // gr % 4 == 0
      }
    }
  }
}

// L1: 8 pair-products, 512 blocks.
__global__ __launch_bounds__(256) void composeL1_kernel(
    const unsigned short* __restrict__ ch, unsigned short* __restrict__ P) {
  const int sub = blockIdx.x >> 6, b = blockIdx.x & 63;
  const int i = sub & 3;
  const unsigned short* x = ch + (size_t)((sub < 4 ? 0 : 8) + 2 * i) * ME;
  compose_body(x, x + ME, P + (size_t)sub * ME, nullptr, b, (i & 1) != 0);
}

// L2: 4 products, 256 blocks.
__global__ __launch_bounds__(256) void composeL2_kernel(
    const unsigned short* __restrict__ P, unsigned short* __restrict__ Q) {
  const int sub = blockIdx.x >> 6, b = blockIdx.x & 63;
  compose_body(P + (size_t)(2 * sub) * ME, P + (size_t)(2 * sub + 1) * ME,
               Q + (size_t)sub * ME, nullptr, b, (sub & 1) != 0);
}

// L3: MUsig = (Q0*Q1)*sigma (rm), MVt = (Q2*Q3)^T. 128 blocks.
__global__ __launch_bounds__(256) void composeL3_kernel(
    const unsigned short* __restrict__ Q, const float* __restrict__ sigmas,
    unsigned short* __restrict__ F) {
  const int sub = blockIdx.x >> 6, b = blockIdx.x & 63;
  if (sub == 0) compose_body(Q, Q + ME, F, sigmas, b, false);
  else compose_body(Q + 2 * ME, Q + 3 * ME, F + ME, nullptr, b, true);
}

// L4: Mt[n][k] = sum_j MVt[n][j] * MUsig[k][j]. 64 blocks.
__global__ __launch_bounds__(256) void composeL4_kernel(
    const unsigned short* __restrict__ F, unsigned short* __restrict__ Mt) {
  compose_body(F + ME, F, Mt, nullptr, blockIdx.x, false);
}

// -------------------- GEMM: out = x @ M + bias, m97-style ----
// A stays f32 in LDS (global_load_lds can't convert); fragments cvt in-register
// (identical rounding to the reg-staged path). A-swizzle: chunk s^(row&7) of
// the 8 x 16B chunks per 128B row; B-swizzle as compose.
__global__ __launch_bounds__(256) void gemm_kernel(
    const float* __restrict__ X, const unsigned short* __restrict__ Mt,
    const float* __restrict__ bias, float* __restrict__ Out) {
  __shared__ float Af[2][BM * 32];            // 16 KB each
  __shared__ unsigned short Bs[2][BN * 32];   // 8 KB each
  const int tid = threadIdx.x;
  const int lane = tid & 63, wave = tid >> 6;
  const int bm = blockIdx.x & 127;
  const int bn = blockIdx.x >> 7;
  const int m0 = bm * BM, n0 = bn * BN;
  const int wm = wave & 1, wn = wave >> 1;
  const int arow0 = wm * 64, brow0 = wn * 64;
  const int fr = lane & 15, kb = (lane >> 4) << 3;

  f32x4 acc[4][4];
#pragma unroll
  for (int a = 0; a < 4; ++a)
#pragma unroll
    for (int b = 0; b < 4; ++b) acc[a][b] = 0.f;

  const float* agbase = X + (size_t)m0 * NN;
  const unsigned short* bgbase = Mt + (size_t)n0 * NN;

#define GSTAGE(PB, KT)                                                          \
  {                                                                             \
    _Pragma("unroll")                                                           \
    for (int i = 0; i < 4; ++i) {                                               \
      const int slot = tid + 256 * i;                                           \
      const int row = slot >> 3, s = slot & 7;                                  \
      const int cs = s ^ (row & 7);                                             \
      __builtin_amdgcn_global_load_lds(                                         \
          (const __attribute__((address_space(1))) void*)(agbase + (size_t)row * NN + (KT) * 32 + cs * 4), \
          (__attribute__((address_space(3))) void*)(&Af[PB][row * 32 + s * 4]), 16, 0, 0); \
    }                                                                           \
    stage_bf16_tile(bgbase, &Bs[PB][0], tid, KT);                               \
  }

  GSTAGE(0, 0)
  int pb = 0;
#pragma unroll 1
  for (int kt = 0; kt < 32; ++kt) {
    __syncthreads();
    if (kt + 1 < 32) GSTAGE(pb ^ 1, kt + 1)
    // compute from buf pb
    {
      short8 af[4], bf[4];
      const int c0 = kb >> 2;       // f32 chunk pair c0, c0+1
      const int ckb = kb >> 3;      // bf16 chunk
#pragma unroll
      for (int tr = 0; tr < 4; ++tr) {
        const int row = arow0 + tr * 16 + fr;
        const int s0 = c0 ^ (row & 7), s1 = (c0 + 1) ^ (row & 7);
        const f32x4 a0 = *reinterpret_cast<const f32x4*>(&Af[pb][row * 32 + s0 * 4]);
        const f32x4 a1 = *reinterpret_cast<const f32x4*>(&Af[pb][row * 32 + s1 * 4]);
        uint4 w;
        w.x = pack2bf(a0[0], a0[1]); w.y = pack2bf(a0[2], a0[3]);
        w.z = pack2bf(a1[0], a1[1]); w.w = pack2bf(a1[2], a1[3]);
        af[tr] = *reinterpret_cast<const short8*>(&w);
      }
#pragma unroll
      for (int tc = 0; tc < 4; ++tc) {
        const int row = brow0 + tc * 16 + fr;
        const int sl = ckb ^ ((row >> 1) & 3);
        bf[tc] = *reinterpret_cast<const short8*>(&Bs[pb][row * 32 + sl * 8]);
      }
#pragma unroll
      for (int tr = 0; tr < 4; ++tr)
#pragma unroll
        for (int tc = 0; tc < 4; ++tc)
          acc[tr][tc] = __builtin_amdgcn_mfma_f32_16x16x32_bf16(af[tr], bf[tc], acc[tr][tc], 0, 0, 0);
    }
    pb ^= 1;
  }
#undef GSTAGE

  const int rq = (lane >> 4) << 2;
#pragma unroll
  for (int tc = 0; tc < 4; ++tc) {
    const int gc = n0 + brow0 + tc * 16 + fr;
    const float bv = bias[gc];
#pragma unroll
    for (int tr = 0; tr < 4; ++tr) {
      const int gr = m0 + arow0 + tr * 16 + rq;
#pragma unroll
      for (int q = 0; q < 4; ++q) {
        Out[(size_t)(gr + q) * NN + gc] = acc[tr][tc][q] + bv;
      }
    }
  }
}

extern "C" void kernel_launch(void* const* d_in, const int* in_sizes, int n_in,
                              void* d_out, int out_size, void* d_ws, size_t ws_size,
                              hipStream_t stream) {
  const float* x = (const float*)d_in[0];
  const float* U = (const float*)d_in[1];
  const float* V = (const float*)d_in[2];
  const float* p = (const float*)d_in[3];
  const float* bias = (const float*)d_in[4];
  float* out = (float*)d_out;

  char* ws = (char*)d_ws;
  float* tau_u = (float*)(ws);
  float* tau_v = (float*)(ws + 4096);
  float* sigmas = (float*)(ws + 8192);
  float* T8all = (float*)(ws + 16384);                 // 64 KB
  unsigned short* Mt = (unsigned short*)(ws + 81920);  // 2 MB (survives until gemm)

  // d_out (64 MB = 32 ME-units) scratch, lifetime-overlapped:
  //  [0,16)  chains (chainC -> L1)
  //  [16,24) YT/WT (splity/zw -> chainc), then P (L1 -> L2)
  //  [24,28) Yhi/Ylo (splity -> gramt), then Thi/Tlo (ttree -> zw), then Q (L2 -> L3)
  //  [28,32) Gp 8MB f32 (gramt -> ttree), then F at [28,30) (L3 -> L4)
  unsigned short* sc = (unsigned short*)d_out;
  unsigned short* chains = sc;
  unsigned short* P = sc + 16 * ME;
  unsigned short* Q = sc + 24 * ME;
  unsigned short* F = sc + 28 * ME;
  unsigned short* YThi = sc + 16 * ME;
  unsigned short* YTlo = sc + 18 * ME;
  unsigned short* WThi = sc + 20 * ME;
  unsigned short* WTlo = sc + 22 * ME;
  unsigned short* Yhi = sc + 24 * ME;
  unsigned short* Ylo = sc + 26 * ME;
  float* Gp = (float*)(sc + 28 * ME);                  // 8 MB
  unsigned short* Thi = sc + 24 * ME;                  // reuses dead Yhi region
  unsigned short* Tlo = Thi + 262144;

  prep_kernel<<<516, 256, 0, stream>>>(U, V, p, tau_u, tau_v, sigmas);
  gram_t8_kernel<<<256, 64, 0, stream>>>(U, V, tau_u, tau_v, T8all);
  splity_kernel<<<128, 256, 0, stream>>>(U, V, Yhi, Ylo, YThi, YTlo);
  gramt_kernel<<<128, 256, 0, stream>>>(Yhi, Ylo, Gp);
  ttree_kernel<<<16, 256, 0, stream>>>(Gp, T8all, Thi, Tlo);
  zw_kernel<<<128, 256, 0, stream>>>(Thi, Tlo, YThi, YTlo, WThi, WTlo);
  chainc_kernel<<<1024, 256, 0, stream>>>(YThi, YTlo, WThi, WTlo, chains);
  composeL1_kernel<<<512, 256, 0, stream>>>(chains, P);
  composeL2_kernel<<<256, 256, 0, stream>>>(P, Q);
  composeL3_kernel<<<128, 256, 0, stream>>>(Q, sigmas, F);
  composeL4_kernel<<<64, 256, 0, stream>>>(F, Mt);
  gemm_kernel<<<1024, 256, 0, stream>>>(x, Mt, bias, out);
}

// Round 14
// 335.454 us; speedup vs baseline: 1.0347x; 1.0347x over previous
//
#include <hip/hip_runtime.h>
#include <stdint.h>

typedef __attribute__((ext_vector_type(8))) short short8;
typedef __attribute__((ext_vector_type(4))) float f32x4;

#define NN 1024
#define NBATCH 16384
#define ME ((size_t)NN * NN)
#define AS1 (const __attribute__((address_space(1))) void*)
#define AS3 (__attribute__((address_space(3))) void*)

__device__ __forceinline__ unsigned short f32_to_bf16_rne(float f) {
  unsigned int u = __float_as_uint(f);
  unsigned int r = (u + 0x7fffu + ((u >> 16) & 1u)) >> 16;
  return (unsigned short)r;
}

__device__ __forceinline__ unsigned int pack2bf(float lo, float hi) {
  return (unsigned int)f32_to_bf16_rne(lo) | ((unsigned int)f32_to_bf16_rne(hi) << 16);
}

__device__ __forceinline__ void split_bf16(float x, unsigned short& h, unsigned short& l) {
  h = f32_to_bf16_rne(x);
  float hf = __uint_as_float((unsigned int)h << 16);
  l = f32_to_bf16_rne(x - hf);
}

__device__ __forceinline__ float allsum64(float x) {
  x += __int_as_float(__builtin_amdgcn_update_dpp(0, __float_as_int(x), 0xB1, 0xF, 0xF, true));
  x += __int_as_float(__builtin_amdgcn_update_dpp(0, __float_as_int(x), 0x4E, 0xF, 0xF, true));
  x += __int_as_float(__builtin_amdgcn_update_dpp(0, __float_as_int(x), 0x141, 0xF, 0xF, true));
  x += __int_as_float(__builtin_amdgcn_update_dpp(0, __float_as_int(x), 0x140, 0xF, 0xF, true));
#if __has_builtin(__builtin_amdgcn_permlane16_swap) && __has_builtin(__builtin_amdgcn_permlane32_swap)
  {
    auto r16 = __builtin_amdgcn_permlane16_swap(__float_as_uint(x), __float_as_uint(x), false, false);
    x = __uint_as_float(r16[0]) + __uint_as_float(r16[1]);
    auto r32 = __builtin_amdgcn_permlane32_swap(__float_as_uint(x), __float_as_uint(x), false, false);
    x = __uint_as_float(r32[0]) + __uint_as_float(r32[1]);
  }
#else
  x += __int_as_float(__builtin_amdgcn_ds_swizzle(__float_as_int(x), 0x401F));
  x += __shfl_xor(x, 32);
#endif
  return x;
}

// -------------------- prep --------------------
__global__ __launch_bounds__(256) void prep_kernel(
    const float* __restrict__ U, const float* __restrict__ V,
    const float* __restrict__ p, float* __restrict__ tau_u,
    float* __restrict__ tau_v, float* __restrict__ sigmas) {
  int wave = threadIdx.x >> 6, lane = threadIdx.x & 63;
  int row = blockIdx.x * 4 + wave;
  if (row < 2048) {
    const float* u = (row < NN) ? (U + (size_t)row * NN) : (V + (size_t)(row - NN) * NN);
    float s = 0.f;
#pragma unroll
    for (int t = 0; t < 16; ++t) { float a = u[lane + (t << 6)]; s += a * a; }
    s = allsum64(s);
    if (lane == 0) {
      float tau = 2.0f / s;
      if (row < NN) tau_u[row] = tau;
      else tau_v[row - NN] = tau;
    }
  } else if (row < 2064) {
    int j = ((row - 2048) << 6) + lane;
    float pj = p[j];
    float sg = 1.0f / (1.0f + expf(-pj));
    sigmas[j] = 0.9f * (sg - 0.5f) + 0.55f;
  }
}

// -------------------- castx: X f32 -> bf16 (same RNE as gemm's on-the-fly cvt) ----
__global__ __launch_bounds__(256) void castx_kernel(
    const float* __restrict__ X, unsigned short* __restrict__ Xb) {
  const size_t n4 = (size_t)NBATCH * NN / 4;  // float4 count
  for (size_t i = (size_t)blockIdx.x * 256 + threadIdx.x; i < n4; i += (size_t)gridDim.x * 256) {
    float4 v = reinterpret_cast<const float4*>(X)[i];
    uint2 o;
    o.x = pack2bf(v.x, v.y);
    o.y = pack2bf(v.z, v.w);
    reinterpret_cast<uint2*>(Xb)[i] = o;
  }
}

// -------------------- gram + T8 --------------------
__global__ __launch_bounds__(64) void gram_t8_kernel(
    const float* __restrict__ U, const float* __restrict__ V,
    const float* __restrict__ tau_u, const float* __restrict__ tau_v,
    float* __restrict__ T8all) {
  __shared__ float G[64];
  const int blk = blockIdx.x;
  const int lane = threadIdx.x;
  const float* bank;
  int rbase, rsign, st;
  if (blk < 128) { bank = U; rbase = 8 * blk; rsign = 1; st = 8 * blk; }
  else { int s = blk - 128; bank = V; rbase = 1023 - 8 * s; rsign = -1; st = 1016 - 8 * s; }

  if (lane < 28) {
    int j = 1, k = 0, t = lane;
    for (int jj = 1; jj < 8; ++jj) {
      int lo = jj * (jj - 1) / 2, hi = jj * (jj + 1) / 2;
      if (t >= lo && t < hi) { j = jj; k = t - lo; }
    }
    const float* rk = bank + (size_t)(rbase + rsign * k) * NN;
    const float* rj = bank + (size_t)(rbase + rsign * j) * NN;
    float acc = 0.f;
    for (int i = st >> 2; i < 256; ++i) {
      float4 a = *reinterpret_cast<const float4*>(rk + 4 * i);
      float4 b = *reinterpret_cast<const float4*>(rj + 4 * i);
      acc += a.x * b.x + a.y * b.y + a.z * b.z + a.w * b.w;
    }
    G[k * 8 + j] = acc;
  }
  __syncthreads();

  if (lane < 8) {
    float Tr[8];
#pragma unroll
    for (int j = 0; j < 8; ++j) Tr[j] = 0.f;
#pragma unroll
    for (int j = 0; j < 8; ++j) {
      int grow = rbase + rsign * j;
      float tj = (blk < 128) ? tau_u[grow] : tau_v[grow];
      float a = 0.f;
#pragma unroll
      for (int k = 0; k < 8; ++k) {
        if (k < j) a += Tr[k] * G[k * 8 + j];
      }
      Tr[j] = (lane == j) ? tj : (-tj * a);
    }
#pragma unroll
    for (int j = 0; j < 8; ++j) T8all[(size_t)blk * 64 + lane * 8 + j] = Tr[j];
  }
}

// -------------------- splitY --------------------
__global__ __launch_bounds__(256) void splity_kernel(
    const float* __restrict__ U, const float* __restrict__ V,
    unsigned short* __restrict__ Yhi, unsigned short* __restrict__ Ylo,
    unsigned short* __restrict__ YThi, unsigned short* __restrict__ YTlo) {
  __shared__ float ys[128][129];
  const int tid = threadIdx.x;
  const int c = blockIdx.x >> 3, et = blockIdx.x & 7;
  const int half = tid & 1;
  const int slot = tid >> 1;
  const int e0 = et << 7;
  const int grow = (c < 8) ? ((c << 7) + slot) : (1023 - ((c - 8) << 7) - slot);
  const float* src = ((c < 8) ? U : V) + (size_t)grow * NN + e0 + (half << 6);
#pragma unroll
  for (int i = 0; i < 16; ++i) {
    float4 v4 = *reinterpret_cast<const float4*>(src + (i << 2));
    const int kk = (half << 6) + (i << 2);
    ys[slot][kk + 0] = v4.x; ys[slot][kk + 1] = v4.y;
    ys[slot][kk + 2] = v4.z; ys[slot][kk + 3] = v4.w;
  }
  __syncthreads();
  {
    const size_t rbase = ((size_t)(c * 128 + slot)) * NN + e0 + (half << 6);
#pragma unroll
    for (int i = 0; i < 16; ++i) {
      const int kk = (half << 6) + (i << 2);
      ushort4 h4, l4;
      split_bf16(ys[slot][kk + 0], h4.x, l4.x);
      split_bf16(ys[slot][kk + 1], h4.y, l4.y);
      split_bf16(ys[slot][kk + 2], h4.z, l4.z);
      split_bf16(ys[slot][kk + 3], h4.w, l4.w);
      *reinterpret_cast<ushort4*>(&Yhi[rbase + (i << 2)]) = h4;
      *reinterpret_cast<ushort4*>(&Ylo[rbase + (i << 2)]) = l4;
    }
  }
  {
    const int e = slot;
    const size_t tbase = ((size_t)c * 1024 + e0 + e) * 128 + (half << 6);
#pragma unroll
    for (int i = 0; i < 16; ++i) {
      const int k0 = (half << 6) + (i << 2);
      ushort4 h4, l4;
      split_bf16(ys[k0 + 0][e], h4.x, l4.x);
      split_bf16(ys[k0 + 1][e], h4.y, l4.y);
      split_bf16(ys[k0 + 2][e], h4.z, l4.z);
      split_bf16(ys[k0 + 3][e], h4.w, l4.w);
      *reinterpret_cast<ushort4*>(&YThi[tbase + (i << 2)]) = h4;
      *reinterpret_cast<ushort4*>(&YTlo[tbase + (i << 2)]) = l4;
    }
  }
}

#define LDK 40
#define BM 128
#define BN 128
#define BK 32

// -------------------- gramT (K-split 8x) --------------------
__global__ __launch_bounds__(256) void gramt_kernel(
    const unsigned short* __restrict__ Yhi, const unsigned short* __restrict__ Ylo,
    float* __restrict__ Gp) {
  __shared__ unsigned short Hs[128 * LDK];
  __shared__ unsigned short Ls[128 * LDK];
  const int tid = threadIdx.x;
  const int lane = tid & 63, wave = tid >> 6;
  const int c = blockIdx.x >> 3, ks = blockIdx.x & 7;
  const int wm = wave & 1, wn = wave >> 1;
  const int srow = tid >> 1, scol = (tid & 1) << 4;
  const unsigned short* ph = Yhi + ((size_t)(c * 128 + srow)) * NN + ks * 128 + scol;
  const unsigned short* pl = Ylo + ((size_t)(c * 128 + srow)) * NN + ks * 128 + scol;

  f32x4 acc[4][4];
#pragma unroll
  for (int a = 0; a < 4; ++a)
#pragma unroll
    for (int b = 0; b < 4; ++b) acc[a][b] = 0.f;

  const int arow0 = wm * 64, brow0 = wn * 64;
  const int fr = lane & 15, kb = (lane >> 4) << 3;

#pragma unroll 1
  for (int kt = 0; kt < 4; ++kt) {
    __syncthreads();
    *reinterpret_cast<uint4*>(&Hs[srow * LDK + scol]) = *reinterpret_cast<const uint4*>(ph + kt * 32);
    *reinterpret_cast<uint4*>(&Hs[srow * LDK + scol + 8]) = *reinterpret_cast<const uint4*>(ph + kt * 32 + 8);
    *reinterpret_cast<uint4*>(&Ls[srow * LDK + scol]) = *reinterpret_cast<const uint4*>(pl + kt * 32);
    *reinterpret_cast<uint4*>(&Ls[srow * LDK + scol + 8]) = *reinterpret_cast<const uint4*>(pl + kt * 32 + 8);
    __syncthreads();
    short8 ah[4], al[4], bh[4], bl[4];
#pragma unroll
    for (int tr = 0; tr < 4; ++tr) {
      ah[tr] = *reinterpret_cast<const short8*>(&Hs[(arow0 + tr * 16 + fr) * LDK + kb]);
      al[tr] = *reinterpret_cast<const short8*>(&Ls[(arow0 + tr * 16 + fr) * LDK + kb]);
    }
#pragma unroll
    for (int tc = 0; tc < 4; ++tc) {
      bh[tc] = *reinterpret_cast<const short8*>(&Hs[(brow0 + tc * 16 + fr) * LDK + kb]);
      bl[tc] = *reinterpret_cast<const short8*>(&Ls[(brow0 + tc * 16 + fr) * LDK + kb]);
    }
#pragma unroll
    for (int tr = 0; tr < 4; ++tr)
#pragma unroll
      for (int tc = 0; tc < 4; ++tc) {
        acc[tr][tc] = __builtin_amdgcn_mfma_f32_16x16x32_bf16(ah[tr], bh[tc], acc[tr][tc], 0, 0, 0);
        acc[tr][tc] = __builtin_amdgcn_mfma_f32_16x16x32_bf16(ah[tr], bl[tc], acc[tr][tc], 0, 0, 0);
        acc[tr][tc] = __builtin_amdgcn_mfma_f32_16x16x32_bf16(al[tr], bh[tc], acc[tr][tc], 0, 0, 0);
      }
  }
  const int rq = (lane >> 4) << 2;
#pragma unroll
  for (int tc = 0; tc < 4; ++tc) {
    const int gc = brow0 + tc * 16 + fr;
#pragma unroll
    for (int tr = 0; tr < 4; ++tr) {
      const int gr = arow0 + tr * 16 + rq;
#pragma unroll
      for (int q = 0; q < 4; ++q)
        Gp[(((size_t)c * 8 + ks) * 128 + gr + q) * 128 + gc] = acc[tr][tc][q];
    }
  }
}

// -------------------- ttree --------------------
__global__ __launch_bounds__(256) void ttree_kernel(
    const float* __restrict__ Gp, const float* __restrict__ T8all,
    unsigned short* __restrict__ Thi, unsigned short* __restrict__ Tlo) {
  __shared__ float Ts[128 * 128];
  __shared__ float Gb[64 * 64];
  __shared__ float Xb[64 * 64];
  const int c = blockIdx.x, tid = threadIdx.x;
  for (int i = tid; i < 128 * 128; i += 256) Ts[i] = 0.f;
  __syncthreads();
  for (int i = tid; i < 1024; i += 256) {
    const int sb = i >> 6, ij = i & 63, r = ij >> 3, col = ij & 7;
    const int t8i = (c < 8) ? (16 * c + sb) : (128 + 16 * (c - 8) + sb);
    Ts[(8 * sb + r) * 128 + 8 * sb + col] = T8all[(size_t)t8i * 64 + ij];
  }
  __syncthreads();
  for (int b = 8; b <= 64; b <<= 1) {
    const int nm = 128 / (2 * b);
    for (int m = 0; m < nm; ++m) {
      const int a0 = 2 * b * m;
      for (int i = tid; i < b * b; i += 256) {
        const int r = i / b, cl = i % b;
        float s = 0.f;
#pragma unroll
        for (int sl = 0; sl < 8; ++sl)
          s += Gp[(((size_t)c * 8 + sl) * 128 + a0 + r) * 128 + a0 + b + cl];
        Gb[i] = s;
      }
      __syncthreads();
      for (int i = tid; i < b * b; i += 256) {
        const int r = i / b, cl = i % b;
        float s = 0.f;
        for (int k = 0; k <= cl; ++k)
          s += Gb[r * b + k] * Ts[(a0 + b + k) * 128 + a0 + b + cl];
        Xb[i] = s;
      }
      __syncthreads();
      for (int i = tid; i < b * b; i += 256) {
        const int r = i / b, cl = i % b;
        float s = 0.f;
        for (int k = r; k < b; ++k)
          s -= Ts[(a0 + r) * 128 + a0 + k] * Xb[k * b + cl];
        Ts[(a0 + r) * 128 + a0 + b + cl] = s;
      }
      __syncthreads();
    }
  }
  for (int i = tid; i < 128 * 128; i += 256) {
    unsigned short h, l;
    split_bf16(Ts[i], h, l);
    Thi[(size_t)c * 128 * 128 + i] = h;
    Tlo[(size_t)c * 128 * 128 + i] = l;
  }
}

// -------------------- zw --------------------
__global__ __launch_bounds__(256) void zw_kernel(
    const unsigned short* __restrict__ Thi, const unsigned short* __restrict__ Tlo,
    const unsigned short* __restrict__ YThi, const unsigned short* __restrict__ YTlo,
    unsigned short* __restrict__ WThi, unsigned short* __restrict__ WTlo) {
  __shared__ unsigned short Xh[128 * LDK], Xl[128 * LDK];
  __shared__ unsigned short Wh[128 * LDK], Wl[128 * LDK];
  const int tid = threadIdx.x;
  const int lane = tid & 63, wave = tid >> 6;
  const int c = blockIdx.x >> 3, bn = blockIdx.x & 7;
  const int n0 = bn * 128;
  const int wm = wave & 1, wn = wave >> 1;
  const int srow = tid >> 1, scol = (tid & 1) << 4;
  const unsigned short* pxh = Thi + ((size_t)c * 128 + srow) * 128 + scol;
  const unsigned short* pxl = Tlo + ((size_t)c * 128 + srow) * 128 + scol;
  const unsigned short* pwh = YThi + ((size_t)c * 1024 + n0 + srow) * 128 + scol;
  const unsigned short* pwl = YTlo + ((size_t)c * 1024 + n0 + srow) * 128 + scol;

  f32x4 acc[4][4];
#pragma unroll
  for (int a = 0; a < 4; ++a)
#pragma unroll
    for (int b = 0; b < 4; ++b) acc[a][b] = 0.f;

  const int arow0 = wm * 64, brow0 = wn * 64;
  const int fr = lane & 15, kb = (lane >> 4) << 3;

#pragma unroll 1
  for (int kt = 0; kt < 4; ++kt) {
    __syncthreads();
    *reinterpret_cast<uint4*>(&Xh[srow * LDK + scol]) = *reinterpret_cast<const uint4*>(pxh + kt * 32);
    *reinterpret_cast<uint4*>(&Xh[srow * LDK + scol + 8]) = *reinterpret_cast<const uint4*>(pxh + kt * 32 + 8);
    *reinterpret_cast<uint4*>(&Xl[srow * LDK + scol]) = *reinterpret_cast<const uint4*>(pxl + kt * 32);
    *reinterpret_cast<uint4*>(&Xl[srow * LDK + scol + 8]) = *reinterpret_cast<const uint4*>(pxl + kt * 32 + 8);
    *reinterpret_cast<uint4*>(&Wh[srow * LDK + scol]) = *reinterpret_cast<const uint4*>(pwh + kt * 32);
    *reinterpret_cast<uint4*>(&Wh[srow * LDK + scol + 8]) = *reinterpret_cast<const uint4*>(pwh + kt * 32 + 8);
    *reinterpret_cast<uint4*>(&Wl[srow * LDK + scol]) = *reinterpret_cast<const uint4*>(pwl + kt * 32);
    *reinterpret_cast<uint4*>(&Wl[srow * LDK + scol + 8]) = *reinterpret_cast<const uint4*>(pwl + kt * 32 + 8);
    __syncthreads();
    short8 ah[4], al[4], bh[4], bl[4];
#pragma unroll
    for (int tr = 0; tr < 4; ++tr) {
      ah[tr] = *reinterpret_cast<const short8*>(&Xh[(arow0 + tr * 16 + fr) * LDK + kb]);
      al[tr] = *reinterpret_cast<const short8*>(&Xl[(arow0 + tr * 16 + fr) * LDK + kb]);
    }
#pragma unroll
    for (int tc = 0; tc < 4; ++tc) {
      bh[tc] = *reinterpret_cast<const short8*>(&Wh[(brow0 + tc * 16 + fr) * LDK + kb]);
      bl[tc] = *reinterpret_cast<const short8*>(&Wl[(brow0 + tc * 16 + fr) * LDK + kb]);
    }
#pragma unroll
    for (int tr = 0; tr < 4; ++tr)
#pragma unroll
      for (int tc = 0; tc < 4; ++tc) {
        acc[tr][tc] = __builtin_amdgcn_mfma_f32_16x16x32_bf16(ah[tr], bh[tc], acc[tr][tc], 0, 0, 0);
        acc[tr][tc] = __builtin_amdgcn_mfma_f32_16x16x32_bf16(ah[tr], bl[tc], acc[tr][tc], 0, 0, 0);
        acc[tr][tc] = __builtin_amdgcn_mfma_f32_16x16x32_bf16(al[tr], bh[tc], acc[tr][tc], 0, 0, 0);
      }
  }
  const int rq = (lane >> 4) << 2;
#pragma unroll
  for (int tc = 0; tc < 4; ++tc) {
    const int gc = brow0 + tc * 16 + fr;
#pragma unroll
    for (int tr = 0; tr < 4; ++tr) {
      const int gr = arow0 + tr * 16 + rq;
      ushort4 h4, l4;
      split_bf16(acc[tr][tc][0], h4.x, l4.x);
      split_bf16(acc[tr][tc][1], h4.y, l4.y);
      split_bf16(acc[tr][tc][2], h4.z, l4.z);
      split_bf16(acc[tr][tc][3], h4.w, l4.w);
      const size_t off = ((size_t)c * 1024 + n0 + gc) * 128 + gr;
      *reinterpret_cast<ushort4*>(&WThi[off]) = h4;
      *reinterpret_cast<ushort4*>(&WTlo[off]) = l4;
    }
  }
}

// -------------------- chainC --------------------
__global__ __launch_bounds__(256) void chainc_kernel(
    const unsigned short* __restrict__ YThi, const unsigned short* __restrict__ YTlo,
    const unsigned short* __restrict__ WThi, const unsigned short* __restrict__ WTlo,
    unsigned short* __restrict__ chains) {
  __shared__ unsigned short Xh[128 * LDK], Xl[128 * LDK];
  __shared__ unsigned short Wh[128 * LDK], Wl[128 * LDK];
  const int tid = threadIdx.x;
  const int lane = tid & 63, wave = tid >> 6;
  const int c = blockIdx.x >> 6, b6 = blockIdx.x & 63;
  const int bm = b6 & 7, bn = b6 >> 3;
  const int m0 = bm * 128, n0 = bn * 128;
  const int wm = wave & 1, wn = wave >> 1;
  const int srow = tid >> 1, scol = (tid & 1) << 4;
  const unsigned short* pxh = YThi + ((size_t)c * 1024 + m0 + srow) * 128 + scol;
  const unsigned short* pxl = YTlo + ((size_t)c * 1024 + m0 + srow) * 128 + scol;
  const unsigned short* pwh = WThi + ((size_t)c * 1024 + n0 + srow) * 128 + scol;
  const unsigned short* pwl = WTlo + ((size_t)c * 1024 + n0 + srow) * 128 + scol;

  f32x4 acc[4][4];
#pragma unroll
  for (int a = 0; a < 4; ++a)
#pragma unroll
    for (int b = 0; b < 4; ++b) acc[a][b] = 0.f;

  const int arow0 = wm * 64, brow0 = wn * 64;
  const int fr = lane & 15, kb = (lane >> 4) << 3;

#pragma unroll 1
  for (int kt = 0; kt < 4; ++kt) {
    __syncthreads();
    *reinterpret_cast<uint4*>(&Xh[srow * LDK + scol]) = *reinterpret_cast<const uint4*>(pxh + kt * 32);
    *reinterpret_cast<uint4*>(&Xh[srow * LDK + scol + 8]) = *reinterpret_cast<const uint4*>(pxh + kt * 32 + 8);
    *reinterpret_cast<uint4*>(&Xl[srow * LDK + scol]) = *reinterpret_cast<const uint4*>(pxl + kt * 32);
    *reinterpret_cast<uint4*>(&Xl[srow * LDK + scol + 8]) = *reinterpret_cast<const uint4*>(pxl + kt * 32 + 8);
    *reinterpret_cast<uint4*>(&Wh[srow * LDK + scol]) = *reinterpret_cast<const uint4*>(pwh + kt * 32);
    *reinterpret_cast<uint4*>(&Wh[srow * LDK + scol + 8]) = *reinterpret_cast<const uint4*>(pwh + kt * 32 + 8);
    *reinterpret_cast<uint4*>(&Wl[srow * LDK + scol]) = *reinterpret_cast<const uint4*>(pwl + kt * 32);
    *reinterpret_cast<uint4*>(&Wl[srow * LDK + scol + 8]) = *reinterpret_cast<const uint4*>(pwl + kt * 32 + 8);
    __syncthreads();
    short8 ah[4], al[4], bh[4], bl[4];
#pragma unroll
    for (int tr = 0; tr < 4; ++tr) {
      ah[tr] = *reinterpret_cast<const short8*>(&Xh[(arow0 + tr * 16 + fr) * LDK + kb]);
      al[tr] = *reinterpret_cast<const short8*>(&Xl[(arow0 + tr * 16 + fr) * LDK + kb]);
    }
#pragma unroll
    for (int tc = 0; tc < 4; ++tc) {
      bh[tc] = *reinterpret_cast<const short8*>(&Wh[(brow0 + tc * 16 + fr) * LDK + kb]);
      bl[tc] = *reinterpret_cast<const short8*>(&Wl[(brow0 + tc * 16 + fr) * LDK + kb]);
    }
#pragma unroll
    for (int tr = 0; tr < 4; ++tr)
#pragma unroll
      for (int tc = 0; tc < 4; ++tc) {
        acc[tr][tc] = __builtin_amdgcn_mfma_f32_16x16x32_bf16(ah[tr], bh[tc], acc[tr][tc], 0, 0, 0);
        acc[tr][tc] = __builtin_amdgcn_mfma_f32_16x16x32_bf16(ah[tr], bl[tc], acc[tr][tc], 0, 0, 0);
        acc[tr][tc] = __builtin_amdgcn_mfma_f32_16x16x32_bf16(al[tr], bh[tc], acc[tr][tc], 0, 0, 0);
      }
  }
  unsigned short* dst = chains + (size_t)c * ME;
  const int rq = (lane >> 4) << 2;
  if ((c & 1) == 0) {
#pragma unroll
    for (int tc = 0; tc < 4; ++tc) {
      const int gcg = n0 + brow0 + tc * 16 + fr;
#pragma unroll
      for (int tr = 0; tr < 4; ++tr) {
        const int grg = m0 + arow0 + tr * 16 + rq;
#pragma unroll
        for (int q = 0; q < 4; ++q) {
          const float val = ((grg + q) == gcg ? 1.0f : 0.0f) - acc[tr][tc][q];
          dst[(size_t)(grg + q) * NN + gcg] = f32_to_bf16_rne(val);
        }
      }
    }
  } else {
#pragma unroll
    for (int tc = 0; tc < 4; ++tc) {
      const int gcg = n0 + brow0 + tc * 16 + fr;
#pragma unroll
      for (int tr = 0; tr < 4; ++tr) {
        const int grg = m0 + arow0 + tr * 16 + rq;
        ushort4 pk;
        pk.x = f32_to_bf16_rne(((grg + 0) == gcg ? 1.0f : 0.0f) - acc[tr][tc][0]);
        pk.y = f32_to_bf16_rne(((grg + 1) == gcg ? 1.0f : 0.0f) - acc[tr][tc][1]);
        pk.z = f32_to_bf16_rne(((grg + 2) == gcg ? 1.0f : 0.0f) - acc[tr][tc][2]);
        pk.w = f32_to_bf16_rne(((grg + 3) == gcg ? 1.0f : 0.0f) - acc[tr][tc][3]);
        *reinterpret_cast<ushort4*>(&dst[(size_t)gcg * NN + grg]) = pk;
      }
    }
  }
}

// -------------------- 1024^3 bf16 compose: 3-buf rotation, counted vmcnt ----
// Per iter kt: [vmcnt(4): own stage(kt) landed] -> [s_barrier: ALL stage(kt)
// visible; also all threads done reading buf[kt%3] from prev iter's compute]
// -> [issue stage(kt+2) -> buf[(kt+2)%3], disjoint from kt%3 and (kt+1)%3]
// -> [compute(kt)]. 4 loads/stage/thread stay in flight across barriers.
__device__ __forceinline__ void cb_stage(
    const unsigned short* __restrict__ agbase, const unsigned short* __restrict__ bgbase,
    unsigned short* __restrict__ la, unsigned short* __restrict__ lb, int tid, int kt) {
#pragma unroll
  for (int i = 0; i < 2; ++i) {
    const int slot = tid + 256 * i;
    const int row = slot >> 2, s = slot & 3;
    __builtin_amdgcn_global_load_lds(
        AS1(agbase + (size_t)row * NN + kt * 32 + s * 8), AS3(la + row * 32 + s * 8), 16, 0, 0);
  }
#pragma unroll
  for (int i = 0; i < 2; ++i) {
    const int slot = tid + 256 * i;
    const int row = slot >> 2, s = slot & 3;
    __builtin_amdgcn_global_load_lds(
        AS1(bgbase + (size_t)row * NN + kt * 32 + s * 8), AS3(lb + row * 32 + s * 8), 16, 0, 0);
  }
}

__device__ __forceinline__ void cb_compute(
    const unsigned short* __restrict__ As, const unsigned short* __restrict__ Bs,
    f32x4 acc[4][4], int arow0, int brow0, int fr, int kb) {
  short8 af[4], bf[4];
#pragma unroll
  for (int tr = 0; tr < 4; ++tr)
    af[tr] = *reinterpret_cast<const short8*>(&As[(arow0 + tr * 16 + fr) * 32 + kb]);
#pragma unroll
  for (int tc = 0; tc < 4; ++tc)
    bf[tc] = *reinterpret_cast<const short8*>(&Bs[(brow0 + tc * 16 + fr) * 32 + kb]);
#pragma unroll
  for (int tr = 0; tr < 4; ++tr)
#pragma unroll
    for (int tc = 0; tc < 4; ++tc)
      acc[tr][tc] = __builtin_amdgcn_mfma_f32_16x16x32_bf16(af[tr], bf[tc], acc[tr][tc], 0, 0, 0);
}

__device__ __forceinline__ void compose_body(
    const unsigned short* __restrict__ Xb, const unsigned short* __restrict__ Wb,
    unsigned short* __restrict__ Op, const float* __restrict__ sig, int b, bool tstore) {
  __shared__ unsigned short As[3][BM * 32];
  __shared__ unsigned short Bs[3][BN * 32];
  const int tid = threadIdx.x;
  const int lane = tid & 63, wave = tid >> 6;
  const int bm = b & 7, bn = b >> 3;
  const int m0 = bm * BM, n0 = bn * BN;
  const int wm = wave & 1, wn = wave >> 1;
  const int arow0 = wm * 64, brow0 = wn * 64;
  const int fr = lane & 15, kb = (lane >> 4) << 3;

  f32x4 acc[4][4];
#pragma unroll
  for (int a = 0; a < 4; ++a)
#pragma unroll
    for (int bb = 0; bb < 4; ++bb) acc[a][bb] = 0.f;

  const unsigned short* agbase = Xb + (size_t)m0 * NN;
  const unsigned short* bgbase = Wb + (size_t)n0 * NN;

  cb_stage(agbase, bgbase, &As[0][0], &Bs[0][0], tid, 0);
  cb_stage(agbase, bgbase, &As[1][0], &Bs[1][0], tid, 1);
#pragma unroll 1
  for (int kt = 0; kt < 31; ++kt) {
    asm volatile("s_waitcnt vmcnt(4)" ::: "memory");
    __builtin_amdgcn_s_barrier();
    __builtin_amdgcn_sched_barrier(0);
    if (kt + 2 < 32) {
      const int nb = (kt + 2) % 3;
      cb_stage(agbase, bgbase, &As[nb][0], &Bs[nb][0], tid, kt + 2);
    }
    cb_compute(&As[kt % 3][0], &Bs[kt % 3][0], acc, arow0, brow0, fr, kb);
  }
  asm volatile("s_waitcnt vmcnt(0)" ::: "memory");
  __builtin_amdgcn_s_barrier();
  __builtin_amdgcn_sched_barrier(0);
  cb_compute(&As[1][0], &Bs[1][0], acc, arow0, brow0, fr, kb);  // 31%3 == 1

  const int rq = (lane >> 4) << 2;
  if (!tstore) {
#pragma unroll
    for (int tc = 0; tc < 4; ++tc) {
      const int gc = n0 + brow0 + tc * 16 + fr;
      const float s = sig ? sig[gc] : 1.0f;
#pragma unroll
      for (int tr = 0; tr < 4; ++tr) {
        const int gr = m0 + arow0 + tr * 16 + rq;
#pragma unroll
        for (int q = 0; q < 4; ++q) {
          Op[(size_t)(gr + q) * NN + gc] = f32_to_bf16_rne(acc[tr][tc][q] * s);
        }
      }
    }
  } else {
#pragma unroll
    for (int tc = 0; tc < 4; ++tc) {
      const int gc = n0 + brow0 + tc * 16 + fr;
#pragma unroll
      for (int tr = 0; tr < 4; ++tr) {
        const int gr = m0 + arow0 + tr * 16 + rq;
        ushort4 pk;
        pk.x = f32_to_bf16_rne(acc[tr][tc][0]);
        pk.y = f32_to_bf16_rne(acc[tr][tc][1]);
        pk.z = f32_to_bf16_rne(acc[tr][tc][2]);
        pk.w = f32_to_bf16_rne(acc[tr][tc][3]);
        *reinterpret_cast<ushort4*>(&Op[(size_t)gc * NN + gr]) = pk;  // gr % 4 == 0
      }
    }
  }
}

__global__ __launch_bounds__(256) void composeL1_kernel(
    const unsigned short* __restrict__ ch, unsigned short* __restrict__ P) {
  const int sub = blockIdx.x >> 6, b = blockIdx.x & 63;
  const int i = sub & 3;
  const unsigned short* x = ch + (size_t)((sub < 4 ? 0 : 8) + 2 * i) * ME;
  compose_body(x, x + ME, P + (size_t)sub * ME, nullptr, b, (i & 1) != 0);
}

__global__ __launch_bounds__(256) void composeL2_kernel(
    const unsigned short* __restrict__ P, unsigned short* __restrict__ Q) {
  const int sub = blockIdx.x >> 6, b = blockIdx.x & 63;
  compose_body(P + (size_t)(2 * sub) * ME, P + (size_t)(2 * sub + 1) * ME,
               Q + (size_t)sub * ME, nullptr, b, (sub & 1) != 0);
}

__global__ __launch_bounds__(256) void composeL3_kernel(
    const unsigned short* __restrict__ Q, const float* __restrict__ sigmas,
    unsigned short* __restrict__ F) {
  const int sub = blockIdx.x >> 6, b = blockIdx.x & 63;
  if (sub == 0) compose_body(Q, Q + ME, F, sigmas, b, false);
  else compose_body(Q + 2 * ME, Q + 3 * ME, F + ME, nullptr, b, true);
}

__global__ __launch_bounds__(256) void composeL4_kernel(
    const unsigned short* __restrict__ F, unsigned short* __restrict__ Mt) {
  compose_body(F + ME, F, Mt, nullptr, blockIdx.x, false);
}

// -------------------- gemm256: out = Xb @ M + bias, 256x128 tile, 3-buf counted vmcnt ----
// 512 blocks = exactly 2/CU resident; 512 threads (8 waves, 4x2). 3 loads/stage.
__global__ __launch_bounds__(512) void gemm256_kernel(
    const unsigned short* __restrict__ Xb, const unsigned short* __restrict__ Mt,
    const float* __restrict__ bias, float* __restrict__ Out) {
  __shared__ unsigned short As[3][256 * 32];  // 16 KB each
  __shared__ unsigned short Bs[3][128 * 32];  // 8 KB each
  const int tid = threadIdx.x;
  const int lane = tid & 63, wave = tid >> 6;
  const int bm = blockIdx.x & 63, bn = blockIdx.x >> 6;
  const int m0 = bm * 256, n0 = bn * 128;
  const int wm = wave & 3, wn = wave >> 2;
  const int arow0 = wm * 64, brow0 = wn * 64;
  const int fr = lane & 15, kb = (lane >> 4) << 3;

  f32x4 acc[4][4];
#pragma unroll
  for (int a = 0; a < 4; ++a)
#pragma unroll
    for (int b = 0; b < 4; ++b) acc[a][b] = 0.f;

  const unsigned short* agbase = Xb + (size_t)m0 * NN;
  const unsigned short* bgbase = Mt + (size_t)n0 * NN;

#define G256_STAGE(B, KT)                                                        \
  {                                                                              \
    _Pragma("unroll")                                                            \
    for (int i = 0; i < 2; ++i) {                                                \
      const int slot = tid + 512 * i;                                            \
      const int row = slot >> 2, s = slot & 3;                                   \
      __builtin_amdgcn_global_load_lds(                                          \
          AS1(agbase + (size_t)row * NN + (KT) * 32 + s * 8),                    \
          AS3(&As[B][row * 32 + s * 8]), 16, 0, 0);                              \
    }                                                                            \
    {                                                                            \
      const int row = tid >> 2, s = tid & 3;                                     \
      __builtin_amdgcn_global_load_lds(                                          \
          AS1(bgbase + (size_t)row * NN + (KT) * 32 + s * 8),                    \
          AS3(&Bs[B][row * 32 + s * 8]), 16, 0, 0);                              \
    }                                                                            \
  }

#define G256_CMP(B)                                                              \
  {                                                                              \
    short8 af[4], bf4[4];                                                        \
    _Pragma("unroll")                                                            \
    for (int tr = 0; tr < 4; ++tr)                                               \
      af[tr] = *reinterpret_cast<const short8*>(&As[B][(arow0 + tr * 16 + fr) * 32 + kb]); \
    _Pragma("unroll")                                                            \
    for (int tc = 0; tc < 4; ++tc)                                               \
      bf4[tc] = *reinterpret_cast<const short8*>(&Bs[B][(brow0 + tc * 16 + fr) * 32 + kb]); \
    _Pragma("unroll")                                                            \
    for (int tr = 0; tr < 4; ++tr)                                               \
      _Pragma("unroll")                                                          \
      for (int tc = 0; tc < 4; ++tc)                                             \
        acc[tr][tc] = __builtin_amdgcn_mfma_f32_16x16x32_bf16(af[tr], bf4[tc], acc[tr][tc], 0, 0, 0); \
  }

  G256_STAGE(0, 0)
  G256_STAGE(1, 1)
#pragma unroll 1
  for (int kt = 0; kt < 31; ++kt) {
    asm volatile("s_waitcnt vmcnt(3)" ::: "memory");
    __builtin_amdgcn_s_barrier();
    __builtin_amdgcn_sched_barrier(0);
    if (kt + 2 < 32) {
      const int nb = (kt + 2) % 3;
      G256_STAGE(nb, kt + 2)
    }
    G256_CMP(kt % 3)
  }
  asm volatile("s_waitcnt vmcnt(0)" ::: "memory");
  __builtin_amdgcn_s_barrier();
  __builtin_amdgcn_sched_barrier(0);
  G256_CMP(1)  // 31 % 3 == 1
#undef G256_STAGE
#undef G256_CMP

  const int rq = (lane >> 4) << 2;
#pragma unroll
  for (int tc = 0; tc < 4; ++tc) {
    const int gc = n0 + brow0 + tc * 16 + fr;
    const float bv = bias[gc];
#pragma unroll
    for (int tr = 0; tr < 4; ++tr) {
      const int gr = m0 + arow0 + tr * 16 + rq;
#pragma unroll
      for (int q = 0; q < 4; ++q) {
        Out[(size_t)(gr + q) * NN + gc] = acc[tr][tc][q] + bv;
      }
    }
  }
}

// -------------------- fallback gemm (R13 verbatim; used when ws too small) ----
__global__ __launch_bounds__(256) void gemm_fb_kernel(
    const float* __restrict__ X, const unsigned short* __restrict__ Mt,
    const float* __restrict__ bias, float* __restrict__ Out) {
  __shared__ float Af[2][BM * 32];
  __shared__ unsigned short Bsl[2][BN * 32];
  const int tid = threadIdx.x;
  const int lane = tid & 63, wave = tid >> 6;
  const int bm = blockIdx.x & 127;
  const int bn = blockIdx.x >> 7;
  const int m0 = bm * BM, n0 = bn * BN;
  const int wm = wave & 1, wn = wave >> 1;
  const int arow0 = wm * 64, brow0 = wn * 64;
  const int fr = lane & 15, kb = (lane >> 4) << 3;

  f32x4 acc[4][4];
#pragma unroll
  for (int a = 0; a < 4; ++a)
#pragma unroll
    for (int b = 0; b < 4; ++b) acc[a][b] = 0.f;

  const float* agbase = X + (size_t)m0 * NN;
  const unsigned short* bgbase = Mt + (size_t)n0 * NN;

#define FB_STAGE(PB, KT)                                                        \
  {                                                                             \
    _Pragma("unroll")                                                           \
    for (int i = 0; i < 4; ++i) {                                               \
      const int slot = tid + 256 * i;                                           \
      const int row = slot >> 3, s = slot & 7;                                  \
      __builtin_amdgcn_global_load_lds(                                         \
          AS1(agbase + (size_t)row * NN + (KT) * 32 + s * 4),                   \
          AS3(&Af[PB][row * 32 + s * 4]), 16, 0, 0);                            \
    }                                                                           \
    _Pragma("unroll")                                                           \
    for (int i = 0; i < 2; ++i) {                                               \
      const int slot = tid + 256 * i;                                           \
      const int row = slot >> 2, s = slot & 3;                                  \
      __builtin_amdgcn_global_load_lds(                                         \
          AS1(bgbase + (size_t)row * NN + (KT) * 32 + s * 8),                   \
          AS3(&Bsl[PB][row * 32 + s * 8]), 16, 0, 0);                           \
    }                                                                           \
  }

  FB_STAGE(0, 0)
  int pb = 0;
#pragma unroll 1
  for (int kt = 0; kt < 32; ++kt) {
    __syncthreads();
    if (kt + 1 < 32) FB_STAGE(pb ^ 1, kt + 1)
    {
      short8 af[4], bf[4];
      const int c0 = kb >> 2;
#pragma unroll
      for (int tr = 0; tr < 4; ++tr) {
        const int row = arow0 + tr * 16 + fr;
        const f32x4 a0 = *reinterpret_cast<const f32x4*>(&Af[pb][row * 32 + c0 * 4]);
        const f32x4 a1 = *reinterpret_cast<const f32x4*>(&Af[pb][row * 32 + (c0 + 1) * 4]);
        uint4 w;
        w.x = pack2bf(a0[0], a0[1]); w.y = pack2bf(a0[2], a0[3]);
        w.z = pack2bf(a1[0], a1[1]); w.w = pack2bf(a1[2], a1[3]);
        af[tr] = *reinterpret_cast<const short8*>(&w);
      }
#pragma unroll
      for (int tc = 0; tc < 4; ++tc) {
        const int row = brow0 + tc * 16 + fr;
        bf[tc] = *reinterpret_cast<const short8*>(&Bsl[pb][row * 32 + kb]);
      }
#pragma unroll
      for (int tr = 0; tr < 4; ++tr)
#pragma unroll
        for (int tc = 0; tc < 4; ++tc)
          acc[tr][tc] = __builtin_amdgcn_mfma_f32_16x16x32_bf16(af[tr], bf[tc], acc[tr][tc], 0, 0, 0);
    }
    pb ^= 1;
  }
#undef FB_STAGE

  const int rq = (lane >> 4) << 2;
#pragma unroll
  for (int tc = 0; tc < 4; ++tc) {
    const int gc = n0 + brow0 + tc * 16 + fr;
    const float bv = bias[gc];
#pragma unroll
    for (int tr = 0; tr < 4; ++tr) {
      const int gr = m0 + arow0 + tr * 16 + rq;
#pragma unroll
      for (int q = 0; q < 4; ++q) {
        Out[(size_t)(gr + q) * NN + gc] = acc[tr][tc][q] + bv;
      }
    }
  }
}

extern "C" void kernel_launch(void* const* d_in, const int* in_sizes, int n_in,
                              void* d_out, int out_size, void* d_ws, size_t ws_size,
                              hipStream_t stream) {
  const float* x = (const float*)d_in[0];
  const float* U = (const float*)d_in[1];
  const float* V = (const float*)d_in[2];
  const float* p = (const float*)d_in[3];
  const float* bias = (const float*)d_in[4];
  float* out = (float*)d_out;

  char* ws = (char*)d_ws;
  float* tau_u = (float*)(ws);
  float* tau_v = (float*)(ws + 4096);
  float* sigmas = (float*)(ws + 8192);
  float* T8all = (float*)(ws + 16384);                 // 64 KB
  unsigned short* Mt = (unsigned short*)(ws + 81920);  // 2 MB

  const size_t XB_OFF = 4u * 1024 * 1024;
  const size_t XB_BYTES = (size_t)NBATCH * NN * 2;     // 32 MB
  const bool fast = ws_size >= XB_OFF + XB_BYTES;
  unsigned short* Xb = (unsigned short*)(ws + XB_OFF);

  unsigned short* sc = (unsigned short*)d_out;
  unsigned short* chains = sc;
  unsigned short* P = sc + 16 * ME;
  unsigned short* Q = sc + 24 * ME;
  unsigned short* F = sc + 28 * ME;
  unsigned short* YThi = sc + 16 * ME;
  unsigned short* YTlo = sc + 18 * ME;
  unsigned short* WThi = sc + 20 * ME;
  unsigned short* WTlo = sc + 22 * ME;
  unsigned short* Yhi = sc + 24 * ME;
  unsigned short* Ylo = sc + 26 * ME;
  float* Gp = (float*)(sc + 28 * ME);
  unsigned short* Thi = sc + 24 * ME;
  unsigned short* Tlo = Thi + 262144;

  prep_kernel<<<516, 256, 0, stream>>>(U, V, p, tau_u, tau_v, sigmas);
  if (fast) castx_kernel<<<2048, 256, 0, stream>>>(x, Xb);
  gram_t8_kernel<<<256, 64, 0, stream>>>(U, V, tau_u, tau_v, T8all);
  splity_kernel<<<128, 256, 0, stream>>>(U, V, Yhi, Ylo, YThi, YTlo);
  gramt_kernel<<<128, 256, 0, stream>>>(Yhi, Ylo, Gp);
  ttree_kernel<<<16, 256, 0, stream>>>(Gp, T8all, Thi, Tlo);
  zw_kernel<<<128, 256, 0, stream>>>(Thi, Tlo, YThi, YTlo, WThi, WTlo);
  chainc_kernel<<<1024, 256, 0, stream>>>(YThi, YTlo, WThi, WTlo, chains);
  composeL1_kernel<<<512, 256, 0, stream>>>(chains, P);
  composeL2_kernel<<<256, 256, 0, stream>>>(P, Q);
  composeL3_kernel<<<128, 256, 0, stream>>>(Q, sigmas, F);
  composeL4_kernel<<<64, 256, 0, stream>>>(F, Mt);
  if (fast) gemm256_kernel<<<512, 512, 0, stream>>>(Xb, Mt, bias, out);
  else gemm_fb_kernel<<<1024, 256, 0, stream>>>(x, Mt, bias, out);
}

// Round 15
// 325.174 us; speedup vs baseline: 1.0674x; 1.0316x over previous
//
#include <hip/hip_runtime.h>
#include <stdint.h>

typedef __attribute__((ext_vector_type(8))) short short8;
typedef __attribute__((ext_vector_type(4))) float f32x4;

#define NN 1024
#define NBATCH 16384
#define ME ((size_t)NN * NN)
#define AS1 (const __attribute__((address_space(1))) void*)
#define AS3 (__attribute__((address_space(3))) void*)

__device__ __forceinline__ unsigned short f32_to_bf16_rne(float f) {
  unsigned int u = __float_as_uint(f);
  unsigned int r = (u + 0x7fffu + ((u >> 16) & 1u)) >> 16;
  return (unsigned short)r;
}

__device__ __forceinline__ unsigned int pack2bf(float lo, float hi) {
  return (unsigned int)f32_to_bf16_rne(lo) | ((unsigned int)f32_to_bf16_rne(hi) << 16);
}

__device__ __forceinline__ void split_bf16(float x, unsigned short& h, unsigned short& l) {
  h = f32_to_bf16_rne(x);
  float hf = __uint_as_float((unsigned int)h << 16);
  l = f32_to_bf16_rne(x - hf);
}

__device__ __forceinline__ float allsum64(float x) {
  x += __int_as_float(__builtin_amdgcn_update_dpp(0, __float_as_int(x), 0xB1, 0xF, 0xF, true));
  x += __int_as_float(__builtin_amdgcn_update_dpp(0, __float_as_int(x), 0x4E, 0xF, 0xF, true));
  x += __int_as_float(__builtin_amdgcn_update_dpp(0, __float_as_int(x), 0x141, 0xF, 0xF, true));
  x += __int_as_float(__builtin_amdgcn_update_dpp(0, __float_as_int(x), 0x140, 0xF, 0xF, true));
#if __has_builtin(__builtin_amdgcn_permlane16_swap) && __has_builtin(__builtin_amdgcn_permlane32_swap)
  {
    auto r16 = __builtin_amdgcn_permlane16_swap(__float_as_uint(x), __float_as_uint(x), false, false);
    x = __uint_as_float(r16[0]) + __uint_as_float(r16[1]);
    auto r32 = __builtin_amdgcn_permlane32_swap(__float_as_uint(x), __float_as_uint(x), false, false);
    x = __uint_as_float(r32[0]) + __uint_as_float(r32[1]);
  }
#else
  x += __int_as_float(__builtin_amdgcn_ds_swizzle(__float_as_int(x), 0x401F));
  x += __shfl_xor(x, 32);
#endif
  return x;
}

// -------------------- prep --------------------
__global__ __launch_bounds__(256) void prep_kernel(
    const float* __restrict__ U, const float* __restrict__ V,
    const float* __restrict__ p, float* __restrict__ tau_u,
    float* __restrict__ tau_v, float* __restrict__ sigmas) {
  int wave = threadIdx.x >> 6, lane = threadIdx.x & 63;
  int row = blockIdx.x * 4 + wave;
  if (row < 2048) {
    const float* u = (row < NN) ? (U + (size_t)row * NN) : (V + (size_t)(row - NN) * NN);
    float s = 0.f;
#pragma unroll
    for (int t = 0; t < 16; ++t) { float a = u[lane + (t << 6)]; s += a * a; }
    s = allsum64(s);
    if (lane == 0) {
      float tau = 2.0f / s;
      if (row < NN) tau_u[row] = tau;
      else tau_v[row - NN] = tau;
    }
  } else if (row < 2064) {
    int j = ((row - 2048) << 6) + lane;
    float pj = p[j];
    float sg = 1.0f / (1.0f + expf(-pj));
    sigmas[j] = 0.9f * (sg - 0.5f) + 0.55f;
  }
}

// -------------------- castx: X f32 -> bf16 --------------------
__global__ __launch_bounds__(256) void castx_kernel(
    const float* __restrict__ X, unsigned short* __restrict__ Xb) {
  const size_t n4 = (size_t)NBATCH * NN / 4;
  for (size_t i = (size_t)blockIdx.x * 256 + threadIdx.x; i < n4; i += (size_t)gridDim.x * 256) {
    float4 v = reinterpret_cast<const float4*>(X)[i];
    uint2 o;
    o.x = pack2bf(v.x, v.y);
    o.y = pack2bf(v.z, v.w);
    reinterpret_cast<uint2*>(Xb)[i] = o;
  }
}

// -------------------- gram + T8 --------------------
__global__ __launch_bounds__(64) void gram_t8_kernel(
    const float* __restrict__ U, const float* __restrict__ V,
    const float* __restrict__ tau_u, const float* __restrict__ tau_v,
    float* __restrict__ T8all) {
  __shared__ float G[64];
  const int blk = blockIdx.x;
  const int lane = threadIdx.x;
  const float* bank;
  int rbase, rsign, st;
  if (blk < 128) { bank = U; rbase = 8 * blk; rsign = 1; st = 8 * blk; }
  else { int s = blk - 128; bank = V; rbase = 1023 - 8 * s; rsign = -1; st = 1016 - 8 * s; }

  if (lane < 28) {
    int j = 1, k = 0, t = lane;
    for (int jj = 1; jj < 8; ++jj) {
      int lo = jj * (jj - 1) / 2, hi = jj * (jj + 1) / 2;
      if (t >= lo && t < hi) { j = jj; k = t - lo; }
    }
    const float* rk = bank + (size_t)(rbase + rsign * k) * NN;
    const float* rj = bank + (size_t)(rbase + rsign * j) * NN;
    float acc = 0.f;
    for (int i = st >> 2; i < 256; ++i) {
      float4 a = *reinterpret_cast<const float4*>(rk + 4 * i);
      float4 b = *reinterpret_cast<const float4*>(rj + 4 * i);
      acc += a.x * b.x + a.y * b.y + a.z * b.z + a.w * b.w;
    }
    G[k * 8 + j] = acc;
  }
  __syncthreads();

  if (lane < 8) {
    float Tr[8];
#pragma unroll
    for (int j = 0; j < 8; ++j) Tr[j] = 0.f;
#pragma unroll
    for (int j = 0; j < 8; ++j) {
      int grow = rbase + rsign * j;
      float tj = (blk < 128) ? tau_u[grow] : tau_v[grow];
      float a = 0.f;
#pragma unroll
      for (int k = 0; k < 8; ++k) {
        if (k < j) a += Tr[k] * G[k * 8 + j];
      }
      Tr[j] = (lane == j) ? tj : (-tj * a);
    }
#pragma unroll
    for (int j = 0; j < 8; ++j) T8all[(size_t)blk * 64 + lane * 8 + j] = Tr[j];
  }
}

// -------------------- splitY --------------------
__global__ __launch_bounds__(256) void splity_kernel(
    const float* __restrict__ U, const float* __restrict__ V,
    unsigned short* __restrict__ Yhi, unsigned short* __restrict__ Ylo,
    unsigned short* __restrict__ YThi, unsigned short* __restrict__ YTlo) {
  __shared__ float ys[128][129];
  const int tid = threadIdx.x;
  const int c = blockIdx.x >> 3, et = blockIdx.x & 7;
  const int half = tid & 1;
  const int slot = tid >> 1;
  const int e0 = et << 7;
  const int grow = (c < 8) ? ((c << 7) + slot) : (1023 - ((c - 8) << 7) - slot);
  const float* src = ((c < 8) ? U : V) + (size_t)grow * NN + e0 + (half << 6);
#pragma unroll
  for (int i = 0; i < 16; ++i) {
    float4 v4 = *reinterpret_cast<const float4*>(src + (i << 2));
    const int kk = (half << 6) + (i << 2);
    ys[slot][kk + 0] = v4.x; ys[slot][kk + 1] = v4.y;
    ys[slot][kk + 2] = v4.z; ys[slot][kk + 3] = v4.w;
  }
  __syncthreads();
  {
    const size_t rbase = ((size_t)(c * 128 + slot)) * NN + e0 + (half << 6);
#pragma unroll
    for (int i = 0; i < 16; ++i) {
      const int kk = (half << 6) + (i << 2);
      ushort4 h4, l4;
      split_bf16(ys[slot][kk + 0], h4.x, l4.x);
      split_bf16(ys[slot][kk + 1], h4.y, l4.y);
      split_bf16(ys[slot][kk + 2], h4.z, l4.z);
      split_bf16(ys[slot][kk + 3], h4.w, l4.w);
      *reinterpret_cast<ushort4*>(&Yhi[rbase + (i << 2)]) = h4;
      *reinterpret_cast<ushort4*>(&Ylo[rbase + (i << 2)]) = l4;
    }
  }
  {
    const int e = slot;
    const size_t tbase = ((size_t)c * 1024 + e0 + e) * 128 + (half << 6);
#pragma unroll
    for (int i = 0; i < 16; ++i) {
      const int k0 = (half << 6) + (i << 2);
      ushort4 h4, l4;
      split_bf16(ys[k0 + 0][e], h4.x, l4.x);
      split_bf16(ys[k0 + 1][e], h4.y, l4.y);
      split_bf16(ys[k0 + 2][e], h4.z, l4.z);
      split_bf16(ys[k0 + 3][e], h4.w, l4.w);
      *reinterpret_cast<ushort4*>(&YThi[tbase + (i << 2)]) = h4;
      *reinterpret_cast<ushort4*>(&YTlo[tbase + (i << 2)]) = l4;
    }
  }
}

#define LDK 40
#define BM 128
#define BN 128
#define BK 32

// -------------------- gramT (K-split 8x) --------------------
__global__ __launch_bounds__(256) void gramt_kernel(
    const unsigned short* __restrict__ Yhi, const unsigned short* __restrict__ Ylo,
    float* __restrict__ Gp) {
  __shared__ unsigned short Hs[128 * LDK];
  __shared__ unsigned short Ls[128 * LDK];
  const int tid = threadIdx.x;
  const int lane = tid & 63, wave = tid >> 6;
  const int c = blockIdx.x >> 3, ks = blockIdx.x & 7;
  const int wm = wave & 1, wn = wave >> 1;
  const int srow = tid >> 1, scol = (tid & 1) << 4;
  const unsigned short* ph = Yhi + ((size_t)(c * 128 + srow)) * NN + ks * 128 + scol;
  const unsigned short* pl = Ylo + ((size_t)(c * 128 + srow)) * NN + ks * 128 + scol;

  f32x4 acc[4][4];
#pragma unroll
  for (int a = 0; a < 4; ++a)
#pragma unroll
    for (int b = 0; b < 4; ++b) acc[a][b] = 0.f;

  const int arow0 = wm * 64, brow0 = wn * 64;
  const int fr = lane & 15, kb = (lane >> 4) << 3;

#pragma unroll 1
  for (int kt = 0; kt < 4; ++kt) {
    __syncthreads();
    *reinterpret_cast<uint4*>(&Hs[srow * LDK + scol]) = *reinterpret_cast<const uint4*>(ph + kt * 32);
    *reinterpret_cast<uint4*>(&Hs[srow * LDK + scol + 8]) = *reinterpret_cast<const uint4*>(ph + kt * 32 + 8);
    *reinterpret_cast<uint4*>(&Ls[srow * LDK + scol]) = *reinterpret_cast<const uint4*>(pl + kt * 32);
    *reinterpret_cast<uint4*>(&Ls[srow * LDK + scol + 8]) = *reinterpret_cast<const uint4*>(pl + kt * 32 + 8);
    __syncthreads();
    short8 ah[4], al[4], bh[4], bl[4];
#pragma unroll
    for (int tr = 0; tr < 4; ++tr) {
      ah[tr] = *reinterpret_cast<const short8*>(&Hs[(arow0 + tr * 16 + fr) * LDK + kb]);
      al[tr] = *reinterpret_cast<const short8*>(&Ls[(arow0 + tr * 16 + fr) * LDK + kb]);
    }
#pragma unroll
    for (int tc = 0; tc < 4; ++tc) {
      bh[tc] = *reinterpret_cast<const short8*>(&Hs[(brow0 + tc * 16 + fr) * LDK + kb]);
      bl[tc] = *reinterpret_cast<const short8*>(&Ls[(brow0 + tc * 16 + fr) * LDK + kb]);
    }
#pragma unroll
    for (int tr = 0; tr < 4; ++tr)
#pragma unroll
      for (int tc = 0; tc < 4; ++tc) {
        acc[tr][tc] = __builtin_amdgcn_mfma_f32_16x16x32_bf16(ah[tr], bh[tc], acc[tr][tc], 0, 0, 0);
        acc[tr][tc] = __builtin_amdgcn_mfma_f32_16x16x32_bf16(ah[tr], bl[tc], acc[tr][tc], 0, 0, 0);
        acc[tr][tc] = __builtin_amdgcn_mfma_f32_16x16x32_bf16(al[tr], bh[tc], acc[tr][tc], 0, 0, 0);
      }
  }
  const int rq = (lane >> 4) << 2;
#pragma unroll
  for (int tc = 0; tc < 4; ++tc) {
    const int gc = brow0 + tc * 16 + fr;
#pragma unroll
    for (int tr = 0; tr < 4; ++tr) {
      const int gr = arow0 + tr * 16 + rq;
#pragma unroll
      for (int q = 0; q < 4; ++q)
        Gp[(((size_t)c * 8 + ks) * 128 + gr + q) * 128 + gc] = acc[tr][tc][q];
    }
  }
}

// -------------------- gsum + Tg init (replaces ttree's in-loop work) ----
// blocks 0..1023: G[c][r][cl] = sum_8 Gp slices (same order as old ttree).
// blocks 1024..1087: Tg init = zeros + diagonal T8 blocks.
__global__ __launch_bounds__(256) void gsum_tinit_kernel(
    const float* __restrict__ Gp, const float* __restrict__ T8all,
    float* __restrict__ G, float* __restrict__ Tg) {
  const int bid = blockIdx.x;
  if (bid < 1024) {
    const size_t i = (size_t)bid * 256 + threadIdx.x;  // 16*128*128 = 262144
    const size_t c = i >> 14, rc = i & 16383;
    float s = 0.f;
#pragma unroll
    for (int sl = 0; sl < 8; ++sl)
      s += Gp[(c * 8 + sl) * 16384 + rc];
    G[i] = s;
  } else {
    const size_t base = ((size_t)(bid - 1024) * 256 + threadIdx.x) * 16;
#pragma unroll 1
    for (int e = 0; e < 16; ++e) {
      const size_t i = base + e;
      const int c = (int)(i >> 14), rc = (int)(i & 16383);
      const int r = rc >> 7, cl = rc & 127;
      float v = 0.f;
      if ((r >> 3) == (cl >> 3)) {
        const int sb = r >> 3;
        const int t8i = (c < 8) ? (16 * c + sb) : (128 + 16 * (c - 8) + sb);
        v = T8all[(size_t)t8i * 64 + (r & 7) * 8 + (cl & 7)];
      }
      Tg[i] = v;
    }
  }
}

// -------------------- tmerge<B>: one WY merge per block ----
// T12 = -T1 * (G12 * T2); write off-diag block of Tg. Grid = 16 * (64/B).
// Identical arithmetic to old ttree (bit-exact).
template <int B>
__global__ __launch_bounds__(256) void tmerge_kernel(
    const float* __restrict__ G, float* __restrict__ Tg) {
  __shared__ float T1s[B * B], T2s[B * B], Gs[B * B], Xs[B * B];
  const int nm = 128 / (2 * B);
  const int c = blockIdx.x / nm, m = blockIdx.x % nm;
  const int a0 = 2 * B * m;
  const int tid = threadIdx.x;
  float* Tc = Tg + (size_t)c * 16384;
  for (int i = tid; i < B * B; i += 256) {
    const int r = i / B, cl = i % B;
    T1s[i] = Tc[(a0 + r) * 128 + a0 + cl];
    T2s[i] = Tc[(a0 + B + r) * 128 + a0 + B + cl];
    Gs[i] = G[((size_t)c * 128 + a0 + r) * 128 + a0 + B + cl];
  }
  __syncthreads();
  for (int i = tid; i < B * B; i += 256) {
    const int r = i / B, cl = i % B;
    float s = 0.f;
    for (int k = 0; k <= cl; ++k) s += Gs[r * B + k] * T2s[k * B + cl];
    Xs[i] = s;
  }
  __syncthreads();
  for (int i = tid; i < B * B; i += 256) {
    const int r = i / B, cl = i % B;
    float s = 0.f;
    for (int k = r; k < B; ++k) s -= T1s[r * B + k] * Xs[k * B + cl];
    Tc[(a0 + r) * 128 + a0 + B + cl] = s;
  }
}

// -------------------- tsplit: Tg f32 -> Thi/Tlo bf16 ----
__global__ __launch_bounds__(256) void tsplit_kernel(
    const float* __restrict__ Tg, unsigned short* __restrict__ Thi,
    unsigned short* __restrict__ Tlo) {
  const size_t i0 = ((size_t)blockIdx.x * 256 + threadIdx.x) * 16;  // 64 blocks
#pragma unroll
  for (int v = 0; v < 4; ++v) {
    float4 t = *reinterpret_cast<const float4*>(Tg + i0 + 4 * v);
    ushort4 h4, l4;
    split_bf16(t.x, h4.x, l4.x);
    split_bf16(t.y, h4.y, l4.y);
    split_bf16(t.z, h4.z, l4.z);
    split_bf16(t.w, h4.w, l4.w);
    *reinterpret_cast<ushort4*>(&Thi[i0 + 4 * v]) = h4;
    *reinterpret_cast<ushort4*>(&Tlo[i0 + 4 * v]) = l4;
  }
}

// -------------------- zw --------------------
__global__ __launch_bounds__(256) void zw_kernel(
    const unsigned short* __restrict__ Thi, const unsigned short* __restrict__ Tlo,
    const unsigned short* __restrict__ YThi, const unsigned short* __restrict__ YTlo,
    unsigned short* __restrict__ WThi, unsigned short* __restrict__ WTlo) {
  __shared__ unsigned short Xh[128 * LDK], Xl[128 * LDK];
  __shared__ unsigned short Wh[128 * LDK], Wl[128 * LDK];
  const int tid = threadIdx.x;
  const int lane = tid & 63, wave = tid >> 6;
  const int c = blockIdx.x >> 3, bn = blockIdx.x & 7;
  const int n0 = bn * 128;
  const int wm = wave & 1, wn = wave >> 1;
  const int srow = tid >> 1, scol = (tid & 1) << 4;
  const unsigned short* pxh = Thi + ((size_t)c * 128 + srow) * 128 + scol;
  const unsigned short* pxl = Tlo + ((size_t)c * 128 + srow) * 128 + scol;
  const unsigned short* pwh = YThi + ((size_t)c * 1024 + n0 + srow) * 128 + scol;
  const unsigned short* pwl = YTlo + ((size_t)c * 1024 + n0 + srow) * 128 + scol;

  f32x4 acc[4][4];
#pragma unroll
  for (int a = 0; a < 4; ++a)
#pragma unroll
    for (int b = 0; b < 4; ++b) acc[a][b] = 0.f;

  const int arow0 = wm * 64, brow0 = wn * 64;
  const int fr = lane & 15, kb = (lane >> 4) << 3;

#pragma unroll 1
  for (int kt = 0; kt < 4; ++kt) {
    __syncthreads();
    *reinterpret_cast<uint4*>(&Xh[srow * LDK + scol]) = *reinterpret_cast<const uint4*>(pxh + kt * 32);
    *reinterpret_cast<uint4*>(&Xh[srow * LDK + scol + 8]) = *reinterpret_cast<const uint4*>(pxh + kt * 32 + 8);
    *reinterpret_cast<uint4*>(&Xl[srow * LDK + scol]) = *reinterpret_cast<const uint4*>(pxl + kt * 32);
    *reinterpret_cast<uint4*>(&Xl[srow * LDK + scol + 8]) = *reinterpret_cast<const uint4*>(pxl + kt * 32 + 8);
    *reinterpret_cast<uint4*>(&Wh[srow * LDK + scol]) = *reinterpret_cast<const uint4*>(pwh + kt * 32);
    *reinterpret_cast<uint4*>(&Wh[srow * LDK + scol + 8]) = *reinterpret_cast<const uint4*>(pwh + kt * 32 + 8);
    *reinterpret_cast<uint4*>(&Wl[srow * LDK + scol]) = *reinterpret_cast<const uint4*>(pwl + kt * 32);
    *reinterpret_cast<uint4*>(&Wl[srow * LDK + scol + 8]) = *reinterpret_cast<const uint4*>(pwl + kt * 32 + 8);
    __syncthreads();
    short8 ah[4], al[4], bh[4], bl[4];
#pragma unroll
    for (int tr = 0; tr < 4; ++tr) {
      ah[tr] = *reinterpret_cast<const short8*>(&Xh[(arow0 + tr * 16 + fr) * LDK + kb]);
      al[tr] = *reinterpret_cast<const short8*>(&Xl[(arow0 + tr * 16 + fr) * LDK + kb]);
    }
#pragma unroll
    for (int tc = 0; tc < 4; ++tc) {
      bh[tc] = *reinterpret_cast<const short8*>(&Wh[(brow0 + tc * 16 + fr) * LDK + kb]);
      bl[tc] = *reinterpret_cast<const short8*>(&Wl[(brow0 + tc * 16 + fr) * LDK + kb]);
    }
#pragma unroll
    for (int tr = 0; tr < 4; ++tr)
#pragma unroll
      for (int tc = 0; tc < 4; ++tc) {
        acc[tr][tc] = __builtin_amdgcn_mfma_f32_16x16x32_bf16(ah[tr], bh[tc], acc[tr][tc], 0, 0, 0);
        acc[tr][tc] = __builtin_amdgcn_mfma_f32_16x16x32_bf16(ah[tr], bl[tc], acc[tr][tc], 0, 0, 0);
        acc[tr][tc] = __builtin_amdgcn_mfma_f32_16x16x32_bf16(al[tr], bh[tc], acc[tr][tc], 0, 0, 0);
      }
  }
  const int rq = (lane >> 4) << 2;
#pragma unroll
  for (int tc = 0; tc < 4; ++tc) {
    const int gc = brow0 + tc * 16 + fr;
#pragma unroll
    for (int tr = 0; tr < 4; ++tr) {
      const int gr = arow0 + tr * 16 + rq;
      ushort4 h4, l4;
      split_bf16(acc[tr][tc][0], h4.x, l4.x);
      split_bf16(acc[tr][tc][1], h4.y, l4.y);
      split_bf16(acc[tr][tc][2], h4.z, l4.z);
      split_bf16(acc[tr][tc][3], h4.w, l4.w);
      const size_t off = ((size_t)c * 1024 + n0 + gc) * 128 + gr;
      *reinterpret_cast<ushort4*>(&WThi[off]) = h4;
      *reinterpret_cast<ushort4*>(&WTlo[off]) = l4;
    }
  }
}

// -------------------- chainC --------------------
__global__ __launch_bounds__(256) void chainc_kernel(
    const unsigned short* __restrict__ YThi, const unsigned short* __restrict__ YTlo,
    const unsigned short* __restrict__ WThi, const unsigned short* __restrict__ WTlo,
    unsigned short* __restrict__ chains) {
  __shared__ unsigned short Xh[128 * LDK], Xl[128 * LDK];
  __shared__ unsigned short Wh[128 * LDK], Wl[128 * LDK];
  const int tid = threadIdx.x;
  const int lane = tid & 63, wave = tid >> 6;
  const int c = blockIdx.x >> 6, b6 = blockIdx.x & 63;
  const int bm = b6 & 7, bn = b6 >> 3;
  const int m0 = bm * 128, n0 = bn * 128;
  const int wm = wave & 1, wn = wave >> 1;
  const int srow = tid >> 1, scol = (tid & 1) << 4;
  const unsigned short* pxh = YThi + ((size_t)c * 1024 + m0 + srow) * 128 + scol;
  const unsigned short* pxl = YTlo + ((size_t)c * 1024 + m0 + srow) * 128 + scol;
  const unsigned short* pwh = WThi + ((size_t)c * 1024 + n0 + srow) * 128 + scol;
  const unsigned short* pwl = WTlo + ((size_t)c * 1024 + n0 + srow) * 128 + scol;

  f32x4 acc[4][4];
#pragma unroll
  for (int a = 0; a < 4; ++a)
#pragma unroll
    for (int b = 0; b < 4; ++b) acc[a][b] = 0.f;

  const int arow0 = wm * 64, brow0 = wn * 64;
  const int fr = lane & 15, kb = (lane >> 4) << 3;

#pragma unroll 1
  for (int kt = 0; kt < 4; ++kt) {
    __syncthreads();
    *reinterpret_cast<uint4*>(&Xh[srow * LDK + scol]) = *reinterpret_cast<const uint4*>(pxh + kt * 32);
    *reinterpret_cast<uint4*>(&Xh[srow * LDK + scol + 8]) = *reinterpret_cast<const uint4*>(pxh + kt * 32 + 8);
    *reinterpret_cast<uint4*>(&Xl[srow * LDK + scol]) = *reinterpret_cast<const uint4*>(pxl + kt * 32);
    *reinterpret_cast<uint4*>(&Xl[srow * LDK + scol + 8]) = *reinterpret_cast<const uint4*>(pxl + kt * 32 + 8);
    *reinterpret_cast<uint4*>(&Wh[srow * LDK + scol]) = *reinterpret_cast<const uint4*>(pwh + kt * 32);
    *reinterpret_cast<uint4*>(&Wh[srow * LDK + scol + 8]) = *reinterpret_cast<const uint4*>(pwh + kt * 32 + 8);
    *reinterpret_cast<uint4*>(&Wl[srow * LDK + scol]) = *reinterpret_cast<const uint4*>(pwl + kt * 32);
    *reinterpret_cast<uint4*>(&Wl[srow * LDK + scol + 8]) = *reinterpret_cast<const uint4*>(pwl + kt * 32 + 8);
    __syncthreads();
    short8 ah[4], al[4], bh[4], bl[4];
#pragma unroll
    for (int tr = 0; tr < 4; ++tr) {
      ah[tr] = *reinterpret_cast<const short8*>(&Xh[(arow0 + tr * 16 + fr) * LDK + kb]);
      al[tr] = *reinterpret_cast<const short8*>(&Xl[(arow0 + tr * 16 + fr) * LDK + kb]);
    }
#pragma unroll
    for (int tc = 0; tc < 4; ++tc) {
      bh[tc] = *reinterpret_cast<const short8*>(&Wh[(brow0 + tc * 16 + fr) * LDK + kb]);
      bl[tc] = *reinterpret_cast<const short8*>(&Wl[(brow0 + tc * 16 + fr) * LDK + kb]);
    }
#pragma unroll
    for (int tr = 0; tr < 4; ++tr)
#pragma unroll
      for (int tc = 0; tc < 4; ++tc) {
        acc[tr][tc] = __builtin_amdgcn_mfma_f32_16x16x32_bf16(ah[tr], bh[tc], acc[tr][tc], 0, 0, 0);
        acc[tr][tc] = __builtin_amdgcn_mfma_f32_16x16x32_bf16(ah[tr], bl[tc], acc[tr][tc], 0, 0, 0);
        acc[tr][tc] = __builtin_amdgcn_mfma_f32_16x16x32_bf16(al[tr], bh[tc], acc[tr][tc], 0, 0, 0);
      }
  }
  unsigned short* dst = chains + (size_t)c * ME;
  const int rq = (lane >> 4) << 2;
  if ((c & 1) == 0) {
#pragma unroll
    for (int tc = 0; tc < 4; ++tc) {
      const int gcg = n0 + brow0 + tc * 16 + fr;
#pragma unroll
      for (int tr = 0; tr < 4; ++tr) {
        const int grg = m0 + arow0 + tr * 16 + rq;
#pragma unroll
        for (int q = 0; q < 4; ++q) {
          const float val = ((grg + q) == gcg ? 1.0f : 0.0f) - acc[tr][tc][q];
          dst[(size_t)(grg + q) * NN + gcg] = f32_to_bf16_rne(val);
        }
      }
    }
  } else {
#pragma unroll
    for (int tc = 0; tc < 4; ++tc) {
      const int gcg = n0 + brow0 + tc * 16 + fr;
#pragma unroll
      for (int tr = 0; tr < 4; ++tr) {
        const int grg = m0 + arow0 + tr * 16 + rq;
        ushort4 pk;
        pk.x = f32_to_bf16_rne(((grg + 0) == gcg ? 1.0f : 0.0f) - acc[tr][tc][0]);
        pk.y = f32_to_bf16_rne(((grg + 1) == gcg ? 1.0f : 0.0f) - acc[tr][tc][1]);
        pk.z = f32_to_bf16_rne(((grg + 2) == gcg ? 1.0f : 0.0f) - acc[tr][tc][2]);
        pk.w = f32_to_bf16_rne(((grg + 3) == gcg ? 1.0f : 0.0f) - acc[tr][tc][3]);
        *reinterpret_cast<ushort4*>(&dst[(size_t)gcg * NN + grg]) = pk;
      }
    }
  }
}

// -------------------- 1024^3 bf16 compose: 3-buf rotation, counted vmcnt ----
__device__ __forceinline__ void cb_stage(
    const unsigned short* __restrict__ agbase, const unsigned short* __restrict__ bgbase,
    unsigned short* __restrict__ la, unsigned short* __restrict__ lb, int tid, int kt) {
#pragma unroll
  for (int i = 0; i < 2; ++i) {
    const int slot = tid + 256 * i;
    const int row = slot >> 2, s = slot & 3;
    __builtin_amdgcn_global_load_lds(
        AS1(agbase + (size_t)row * NN + kt * 32 + s * 8), AS3(la + row * 32 + s * 8), 16, 0, 0);
  }
#pragma unroll
  for (int i = 0; i < 2; ++i) {
    const int slot = tid + 256 * i;
    const int row = slot >> 2, s = slot & 3;
    __builtin_amdgcn_global_load_lds(
        AS1(bgbase + (size_t)row * NN + kt * 32 + s * 8), AS3(lb + row * 32 + s * 8), 16, 0, 0);
  }
}

__device__ __forceinline__ void cb_compute(
    const unsigned short* __restrict__ As, const unsigned short* __restrict__ Bs,
    f32x4 acc[4][4], int arow0, int brow0, int fr, int kb) {
  short8 af[4], bf[4];
#pragma unroll
  for (int tr = 0; tr < 4; ++tr)
    af[tr] = *reinterpret_cast<const short8*>(&As[(arow0 + tr * 16 + fr) * 32 + kb]);
#pragma unroll
  for (int tc = 0; tc < 4; ++tc)
    bf[tc] = *reinterpret_cast<const short8*>(&Bs[(brow0 + tc * 16 + fr) * 32 + kb]);
#pragma unroll
  for (int tr = 0; tr < 4; ++tr)
#pragma unroll
    for (int tc = 0; tc < 4; ++tc)
      acc[tr][tc] = __builtin_amdgcn_mfma_f32_16x16x32_bf16(af[tr], bf[tc], acc[tr][tc], 0, 0, 0);
}

__device__ __forceinline__ void compose_body(
    const unsigned short* __restrict__ Xb, const unsigned short* __restrict__ Wb,
    unsigned short* __restrict__ Op, const float* __restrict__ sig, int b, bool tstore) {
  __shared__ unsigned short As[3][BM * 32];
  __shared__ unsigned short Bs[3][BN * 32];
  const int tid = threadIdx.x;
  const int lane = tid & 63, wave = tid >> 6;
  const int bm = b & 7, bn = b >> 3;
  const int m0 = bm * BM, n0 = bn * BN;
  const int wm = wave & 1, wn = wave >> 1;
  const int arow0 = wm * 64, brow0 = wn * 64;
  const int fr = lane & 15, kb = (lane >> 4) << 3;

  f32x4 acc[4][4];
#pragma unroll
  for (int a = 0; a < 4; ++a)
#pragma unroll
    for (int bb = 0; bb < 4; ++bb) acc[a][bb] = 0.f;

  const unsigned short* agbase = Xb + (size_t)m0 * NN;
  const unsigned short* bgbase = Wb + (size_t)n0 * NN;

  cb_stage(agbase, bgbase, &As[0][0], &Bs[0][0], tid, 0);
  cb_stage(agbase, bgbase, &As[1][0], &Bs[1][0], tid, 1);
#pragma unroll 1
  for (int kt = 0; kt < 31; ++kt) {
    asm volatile("s_waitcnt vmcnt(4)" ::: "memory");
    __builtin_amdgcn_s_barrier();
    __builtin_amdgcn_sched_barrier(0);
    if (kt + 2 < 32) {
      const int nb = (kt + 2) % 3;
      cb_stage(agbase, bgbase, &As[nb][0], &Bs[nb][0], tid, kt + 2);
    }
    cb_compute(&As[kt % 3][0], &Bs[kt % 3][0], acc, arow0, brow0, fr, kb);
  }
  asm volatile("s_waitcnt vmcnt(0)" ::: "memory");
  __builtin_amdgcn_s_barrier();
  __builtin_amdgcn_sched_barrier(0);
  cb_compute(&As[1][0], &Bs[1][0], acc, arow0, brow0, fr, kb);  // 31%3 == 1

  const int rq = (lane >> 4) << 2;
  if (!tstore) {
#pragma unroll
    for (int tc = 0; tc < 4; ++tc) {
      const int gc = n0 + brow0 + tc * 16 + fr;
      const float s = sig ? sig[gc] : 1.0f;
#pragma unroll
      for (int tr = 0; tr < 4; ++tr) {
        const int gr = m0 + arow0 + tr * 16 + rq;
#pragma unroll
        for (int q = 0; q < 4; ++q) {
          Op[(size_t)(gr + q) * NN + gc] = f32_to_bf16_rne(acc[tr][tc][q] * s);
        }
      }
    }
  } else {
#pragma unroll
    for (int tc = 0; tc < 4; ++tc) {
      const int gc = n0 + brow0 + tc * 16 + fr;
#pragma unroll
      for (int tr = 0; tr < 4; ++tr) {
        const int gr = m0 + arow0 + tr * 16 + rq;
        ushort4 pk;
        pk.x = f32_to_bf16_rne(acc[tr][tc][0]);
        pk.y = f32_to_bf16_rne(acc[tr][tc][1]);
        pk.z = f32_to_bf16_rne(acc[tr][tc][2]);
        pk.w = f32_to_bf16_rne(acc[tr][tc][3]);
        *reinterpret_cast<ushort4*>(&Op[(size_t)gc * NN + gr]) = pk;  // gr % 4 == 0
      }
    }
  }
}

__global__ __launch_bounds__(256) void composeL1_kernel(
    const unsigned short* __restrict__ ch, unsigned short* __restrict__ P) {
  const int sub = blockIdx.x >> 6, b = blockIdx.x & 63;
  const int i = sub & 3;
  const unsigned short* x = ch + (size_t)((sub < 4 ? 0 : 8) + 2 * i) * ME;
  compose_body(x, x + ME, P + (size_t)sub * ME, nullptr, b, (i & 1) != 0);
}

__global__ __launch_bounds__(256) void composeL2_kernel(
    const unsigned short* __restrict__ P, unsigned short* __restrict__ Q) {
  const int sub = blockIdx.x >> 6, b = blockIdx.x & 63;
  compose_body(P + (size_t)(2 * sub) * ME, P + (size_t)(2 * sub + 1) * ME,
               Q + (size_t)sub * ME, nullptr, b, (sub & 1) != 0);
}

__global__ __launch_bounds__(256) void composeL3_kernel(
    const unsigned short* __restrict__ Q, const float* __restrict__ sigmas,
    unsigned short* __restrict__ F) {
  const int sub = blockIdx.x >> 6, b = blockIdx.x & 63;
  if (sub == 0) compose_body(Q, Q + ME, F, sigmas, b, false);
  else compose_body(Q + 2 * ME, Q + 3 * ME, F + ME, nullptr, b, true);
}

__global__ __launch_bounds__(256) void composeL4_kernel(
    const unsigned short* __restrict__ F, unsigned short* __restrict__ Mt) {
  compose_body(F + ME, F, Mt, nullptr, blockIdx.x, false);
}

// -------------------- gemm256 --------------------
__global__ __launch_bounds__(512) void gemm256_kernel(
    const unsigned short* __restrict__ Xb, const unsigned short* __restrict__ Mt,
    const float* __restrict__ bias, float* __restrict__ Out) {
  __shared__ unsigned short As[3][256 * 32];
  __shared__ unsigned short Bs[3][128 * 32];
  const int tid = threadIdx.x;
  const int lane = tid & 63, wave = tid >> 6;
  const int bm = blockIdx.x & 63, bn = blockIdx.x >> 6;
  const int m0 = bm * 256, n0 = bn * 128;
  const int wm = wave & 3, wn = wave >> 2;
  const int arow0 = wm * 64, brow0 = wn * 64;
  const int fr = lane & 15, kb = (lane >> 4) << 3;

  f32x4 acc[4][4];
#pragma unroll
  for (int a = 0; a < 4; ++a)
#pragma unroll
    for (int b = 0; b < 4; ++b) acc[a][b] = 0.f;

  const unsigned short* agbase = Xb + (size_t)m0 * NN;
  const unsigned short* bgbase = Mt + (size_t)n0 * NN;

#define G256_STAGE(B, KT)                                                        \
  {                                                                              \
    _Pragma("unroll")                                                            \
    for (int i = 0; i < 2; ++i) {                                                \
      const int slot = tid + 512 * i;                                            \
      const int row = slot >> 2, s = slot & 3;                                   \
      __builtin_amdgcn_global_load_lds(                                          \
          AS1(agbase + (size_t)row * NN + (KT) * 32 + s * 8),                    \
          AS3(&As[B][row * 32 + s * 8]), 16, 0, 0);                              \
    }                                                                            \
    {                                                                            \
      const int row = tid >> 2, s = tid & 3;                                     \
      __builtin_amdgcn_global_load_lds(                                          \
          AS1(bgbase + (size_t)row * NN + (KT) * 32 + s * 8),                    \
          AS3(&Bs[B][row * 32 + s * 8]), 16, 0, 0);                              \
    }                                                                            \
  }

#define G256_CMP(B)                                                              \
  {                                                                              \
    short8 af[4], bf4[4];                                                        \
    _Pragma("unroll")                                                            \
    for (int tr = 0; tr < 4; ++tr)                                               \
      af[tr] = *reinterpret_cast<const short8*>(&As[B][(arow0 + tr * 16 + fr) * 32 + kb]); \
    _Pragma("unroll")                                                            \
    for (int tc = 0; tc < 4; ++tc)                                               \
      bf4[tc] = *reinterpret_cast<const short8*>(&Bs[B][(brow0 + tc * 16 + fr) * 32 + kb]); \
    _Pragma("unroll")                                                            \
    for (int tr = 0; tr < 4; ++tr)                                               \
      _Pragma("unroll")                                                          \
      for (int tc = 0; tc < 4; ++tc)                                             \
        acc[tr][tc] = __builtin_amdgcn_mfma_f32_16x16x32_bf16(af[tr], bf4[tc], acc[tr][tc], 0, 0, 0); \
  }

  G256_STAGE(0, 0)
  G256_STAGE(1, 1)
#pragma unroll 1
  for (int kt = 0; kt < 31; ++kt) {
    asm volatile("s_waitcnt vmcnt(3)" ::: "memory");
    __builtin_amdgcn_s_barrier();
    __builtin_amdgcn_sched_barrier(0);
    if (kt + 2 < 32) {
      const int nb = (kt + 2) % 3;
      G256_STAGE(nb, kt + 2)
    }
    G256_CMP(kt % 3)
  }
  asm volatile("s_waitcnt vmcnt(0)" ::: "memory");
  __builtin_amdgcn_s_barrier();
  __builtin_amdgcn_sched_barrier(0);
  G256_CMP(1)
#undef G256_STAGE
#undef G256_CMP

  const int rq = (lane >> 4) << 2;
#pragma unroll
  for (int tc = 0; tc < 4; ++tc) {
    const int gc = n0 + brow0 + tc * 16 + fr;
    const float bv = bias[gc];
#pragma unroll
    for (int tr = 0; tr < 4; ++tr) {
      const int gr = m0 + arow0 + tr * 16 + rq;
#pragma unroll
      for (int q = 0; q < 4; ++q) {
        Out[(size_t)(gr + q) * NN + gc] = acc[tr][tc][q] + bv;
      }
    }
  }
}

// -------------------- fallback gemm --------------------
__global__ __launch_bounds__(256) void gemm_fb_kernel(
    const float* __restrict__ X, const unsigned short* __restrict__ Mt,
    const float* __restrict__ bias, float* __restrict__ Out) {
  __shared__ float Af[2][BM * 32];
  __shared__ unsigned short Bsl[2][BN * 32];
  const int tid = threadIdx.x;
  const int lane = tid & 63, wave = tid >> 6;
  const int bm = blockIdx.x & 127;
  const int bn = blockIdx.x >> 7;
  const int m0 = bm * BM, n0 = bn * BN;
  const int wm = wave & 1, wn = wave >> 1;
  const int arow0 = wm * 64, brow0 = wn * 64;
  const int fr = lane & 15, kb = (lane >> 4) << 3;

  f32x4 acc[4][4];
#pragma unroll
  for (int a = 0; a < 4; ++a)
#pragma unroll
    for (int b = 0; b < 4; ++b) acc[a][b] = 0.f;

  const float* agbase = X + (size_t)m0 * NN;
  const unsigned short* bgbase = Mt + (size_t)n0 * NN;

#define FB_STAGE(PB, KT)                                                        \
  {                                                                             \
    _Pragma("unroll")                                                           \
    for (int i = 0; i < 4; ++i) {                                               \
      const int slot = tid + 256 * i;                                           \
      const int row = slot >> 3, s = slot & 7;                                  \
      __builtin_amdgcn_global_load_lds(                                         \
          AS1(agbase + (size_t)row * NN + (KT) * 32 + s * 4),                   \
          AS3(&Af[PB][row * 32 + s * 4]), 16, 0, 0);                            \
    }                                                                           \
    _Pragma("unroll")                                                           \
    for (int i = 0; i < 2; ++i) {                                               \
      const int slot = tid + 256 * i;                                           \
      const int row = slot >> 2, s = slot & 3;                                  \
      __builtin_amdgcn_global_load_lds(                                         \
          AS1(bgbase + (size_t)row * NN + (KT) * 32 + s * 8),                   \
          AS3(&Bsl[PB][row * 32 + s * 8]), 16, 0, 0);                           \
    }                                                                           \
  }

  FB_STAGE(0, 0)
  int pb = 0;
#pragma unroll 1
  for (int kt = 0; kt < 32; ++kt) {
    __syncthreads();
    if (kt + 1 < 32) FB_STAGE(pb ^ 1, kt + 1)
    {
      short8 af[4], bf[4];
      const int c0 = kb >> 2;
#pragma unroll
      for (int tr = 0; tr < 4; ++tr) {
        const int row = arow0 + tr * 16 + fr;
        const f32x4 a0 = *reinterpret_cast<const f32x4*>(&Af[pb][row * 32 + c0 * 4]);
        const f32x4 a1 = *reinterpret_cast<const f32x4*>(&Af[pb][row * 32 + (c0 + 1) * 4]);
        uint4 w;
        w.x = pack2bf(a0[0], a0[1]); w.y = pack2bf(a0[2], a0[3]);
        w.z = pack2bf(a1[0], a1[1]); w.w = pack2bf(a1[2], a1[3]);
        af[tr] = *reinterpret_cast<const short8*>(&w);
      }
#pragma unroll
      for (int tc = 0; tc < 4; ++tc) {
        const int row = brow0 + tc * 16 + fr;
        bf[tc] = *reinterpret_cast<const short8*>(&Bsl[pb][row * 32 + kb]);
      }
#pragma unroll
      for (int tr = 0; tr < 4; ++tr)
#pragma unroll
        for (int tc = 0; tc < 4; ++tc)
          acc[tr][tc] = __builtin_amdgcn_mfma_f32_16x16x32_bf16(af[tr], bf[tc], acc[tr][tc], 0, 0, 0);
    }
    pb ^= 1;
  }
#undef FB_STAGE

  const int rq = (lane >> 4) << 2;
#pragma unroll
  for (int tc = 0; tc < 4; ++tc) {
    const int gc = n0 + brow0 + tc * 16 + fr;
    const float bv = bias[gc];
#pragma unroll
    for (int tr = 0; tr < 4; ++tr) {
      const int gr = m0 + arow0 + tr * 16 + rq;
#pragma unroll
      for (int q = 0; q < 4; ++q) {
        Out[(size_t)(gr + q) * NN + gc] = acc[tr][tc][q] + bv;
      }
    }
  }
}

extern "C" void kernel_launch(void* const* d_in, const int* in_sizes, int n_in,
                              void* d_out, int out_size, void* d_ws, size_t ws_size,
                              hipStream_t stream) {
  const float* x = (const float*)d_in[0];
  const float* U = (const float*)d_in[1];
  const float* V = (const float*)d_in[2];
  const float* p = (const float*)d_in[3];
  const float* bias = (const float*)d_in[4];
  float* out = (float*)d_out;

  char* ws = (char*)d_ws;
  float* tau_u = (float*)(ws);
  float* tau_v = (float*)(ws + 4096);
  float* sigmas = (float*)(ws + 8192);
  float* T8all = (float*)(ws + 16384);                 // 64 KB
  unsigned short* Mt = (unsigned short*)(ws + 81920);  // 2 MB

  const size_t XB_OFF = 4u * 1024 * 1024;
  const size_t XB_BYTES = (size_t)NBATCH * NN * 2;     // 32 MB
  const bool fast = ws_size >= XB_OFF + XB_BYTES;
  unsigned short* Xb = (unsigned short*)(ws + XB_OFF);

  // d_out (64 MB = 32 ME-units) scratch, lifetime-overlapped:
  //  [0,16)  G f32 (1MB @0) + Tg f32 (1MB @2MB) during T-phase; then chains
  //  [16,24) YT/WT (splity/zw -> chainc), then P (L1 -> L2)
  //  [24,28) Yhi/Ylo (splity -> gramt), then Thi/Tlo (tsplit -> zw), then Q
  //  [28,32) Gp 8MB f32 (gramt -> gsum), then F at [28,30) (L3 -> L4)
  unsigned short* sc = (unsigned short*)d_out;
  unsigned short* chains = sc;
  unsigned short* P = sc + 16 * ME;
  unsigned short* Q = sc + 24 * ME;
  unsigned short* F = sc + 28 * ME;
  unsigned short* YThi = sc + 16 * ME;
  unsigned short* YTlo = sc + 18 * ME;
  unsigned short* WThi = sc + 20 * ME;
  unsigned short* WTlo = sc + 22 * ME;
  unsigned short* Yhi = sc + 24 * ME;
  unsigned short* Ylo = sc + 26 * ME;
  float* Gp = (float*)(sc + 28 * ME);
  float* G = (float*)sc;                               // 1 MB (chains region, dead until chainc)
  float* Tg = (float*)(sc + ME);                       // 1 MB
  unsigned short* Thi = sc + 24 * ME;                  // dead Yhi region
  unsigned short* Tlo = Thi + 262144;

  prep_kernel<<<516, 256, 0, stream>>>(U, V, p, tau_u, tau_v, sigmas);
  if (fast) castx_kernel<<<2048, 256, 0, stream>>>(x, Xb);
  gram_t8_kernel<<<256, 64, 0, stream>>>(U, V, tau_u, tau_v, T8all);
  splity_kernel<<<128, 256, 0, stream>>>(U, V, Yhi, Ylo, YThi, YTlo);
  gramt_kernel<<<128, 256, 0, stream>>>(Yhi, Ylo, Gp);
  gsum_tinit_kernel<<<1088, 256, 0, stream>>>(Gp, T8all, G, Tg);
  tmerge_kernel<8><<<128, 256, 0, stream>>>(G, Tg);
  tmerge_kernel<16><<<64, 256, 0, stream>>>(G, Tg);
  tmerge_kernel<32><<<32, 256, 0, stream>>>(G, Tg);
  tmerge_kernel<64><<<16, 256, 0, stream>>>(G, Tg);
  tsplit_kernel<<<64, 256, 0, stream>>>(Tg, Thi, Tlo);
  zw_kernel<<<128, 256, 0, stream>>>(Thi, Tlo, YThi, YTlo, WThi, WTlo);
  chainc_kernel<<<1024, 256, 0, stream>>>(YThi, YTlo, WThi, WTlo, chains);
  composeL1_kernel<<<512, 256, 0, stream>>>(chains, P);
  composeL2_kernel<<<256, 256, 0, stream>>>(P, Q);
  composeL3_kernel<<<128, 256, 0, stream>>>(Q, sigmas, F);
  composeL4_kernel<<<64, 256, 0, stream>>>(F, Mt);
  if (fast) gemm256_kernel<<<512, 512, 0, stream>>>(Xb, Mt, bias, out);
  else gemm_fb_kernel<<<1024, 256, 0, stream>>>(x, Mt, bias, out);
}

// Round 16
// 318.123 us; speedup vs baseline: 1.0911x; 1.0222x over previous
//
#include <hip/hip_runtime.h>
#include <stdint.h>

typedef __attribute__((ext_vector_type(8))) short short8;
typedef __attribute__((ext_vector_type(4))) float f32x4;

#define NN 1024
#define NBATCH 16384
#define ME ((size_t)NN * NN)
#define AS1 (const __attribute__((address_space(1))) void*)
#define AS3 (__attribute__((address_space(3))) void*)

__device__ __forceinline__ unsigned short f32_to_bf16_rne(float f) {
  unsigned int u = __float_as_uint(f);
  unsigned int r = (u + 0x7fffu + ((u >> 16) & 1u)) >> 16;
  return (unsigned short)r;
}

__device__ __forceinline__ unsigned int pack2bf(float lo, float hi) {
  return (unsigned int)f32_to_bf16_rne(lo) | ((unsigned int)f32_to_bf16_rne(hi) << 16);
}

__device__ __forceinline__ void split_bf16(float x, unsigned short& h, unsigned short& l) {
  h = f32_to_bf16_rne(x);
  float hf = __uint_as_float((unsigned int)h << 16);
  l = f32_to_bf16_rne(x - hf);
}

__device__ __forceinline__ float allsum64(float x) {
  x += __int_as_float(__builtin_amdgcn_update_dpp(0, __float_as_int(x), 0xB1, 0xF, 0xF, true));
  x += __int_as_float(__builtin_amdgcn_update_dpp(0, __float_as_int(x), 0x4E, 0xF, 0xF, true));
  x += __int_as_float(__builtin_amdgcn_update_dpp(0, __float_as_int(x), 0x141, 0xF, 0xF, true));
  x += __int_as_float(__builtin_amdgcn_update_dpp(0, __float_as_int(x), 0x140, 0xF, 0xF, true));
#if __has_builtin(__builtin_amdgcn_permlane16_swap) && __has_builtin(__builtin_amdgcn_permlane32_swap)
  {
    auto r16 = __builtin_amdgcn_permlane16_swap(__float_as_uint(x), __float_as_uint(x), false, false);
    x = __uint_as_float(r16[0]) + __uint_as_float(r16[1]);
    auto r32 = __builtin_amdgcn_permlane32_swap(__float_as_uint(x), __float_as_uint(x), false, false);
    x = __uint_as_float(r32[0]) + __uint_as_float(r32[1]);
  }
#else
  x += __int_as_float(__builtin_amdgcn_ds_swizzle(__float_as_int(x), 0x401F));
  x += __shfl_xor(x, 32);
#endif
  return x;
}

// -------------------- prep --------------------
__global__ __launch_bounds__(256) void prep_kernel(
    const float* __restrict__ U, const float* __restrict__ V,
    const float* __restrict__ p, float* __restrict__ tau_u,
    float* __restrict__ tau_v, float* __restrict__ sigmas) {
  int wave = threadIdx.x >> 6, lane = threadIdx.x & 63;
  int row = blockIdx.x * 4 + wave;
  if (row < 2048) {
    const float* u = (row < NN) ? (U + (size_t)row * NN) : (V + (size_t)(row - NN) * NN);
    float s = 0.f;
#pragma unroll
    for (int t = 0; t < 16; ++t) { float a = u[lane + (t << 6)]; s += a * a; }
    s = allsum64(s);
    if (lane == 0) {
      float tau = 2.0f / s;
      if (row < NN) tau_u[row] = tau;
      else tau_v[row - NN] = tau;
    }
  } else if (row < 2064) {
    int j = ((row - 2048) << 6) + lane;
    float pj = p[j];
    float sg = 1.0f / (1.0f + expf(-pj));
    sigmas[j] = 0.9f * (sg - 0.5f) + 0.55f;
  }
}

// -------------------- castx: X f32 -> bf16 --------------------
__global__ __launch_bounds__(256) void castx_kernel(
    const float* __restrict__ X, unsigned short* __restrict__ Xb) {
  const size_t n4 = (size_t)NBATCH * NN / 4;
  for (size_t i = (size_t)blockIdx.x * 256 + threadIdx.x; i < n4; i += (size_t)gridDim.x * 256) {
    float4 v = reinterpret_cast<const float4*>(X)[i];
    uint2 o;
    o.x = pack2bf(v.x, v.y);
    o.y = pack2bf(v.z, v.w);
    reinterpret_cast<uint2*>(Xb)[i] = o;
  }
}

// -------------------- gram + T8 --------------------
__global__ __launch_bounds__(64) void gram_t8_kernel(
    const float* __restrict__ U, const float* __restrict__ V,
    const float* __restrict__ tau_u, const float* __restrict__ tau_v,
    float* __restrict__ T8all) {
  __shared__ float G[64];
  const int blk = blockIdx.x;
  const int lane = threadIdx.x;
  const float* bank;
  int rbase, rsign, st;
  if (blk < 128) { bank = U; rbase = 8 * blk; rsign = 1; st = 8 * blk; }
  else { int s = blk - 128; bank = V; rbase = 1023 - 8 * s; rsign = -1; st = 1016 - 8 * s; }

  if (lane < 28) {
    int j = 1, k = 0, t = lane;
    for (int jj = 1; jj < 8; ++jj) {
      int lo = jj * (jj - 1) / 2, hi = jj * (jj + 1) / 2;
      if (t >= lo && t < hi) { j = jj; k = t - lo; }
    }
    const float* rk = bank + (size_t)(rbase + rsign * k) * NN;
    const float* rj = bank + (size_t)(rbase + rsign * j) * NN;
    float acc = 0.f;
    for (int i = st >> 2; i < 256; ++i) {
      float4 a = *reinterpret_cast<const float4*>(rk + 4 * i);
      float4 b = *reinterpret_cast<const float4*>(rj + 4 * i);
      acc += a.x * b.x + a.y * b.y + a.z * b.z + a.w * b.w;
    }
    G[k * 8 + j] = acc;
  }
  __syncthreads();

  if (lane < 8) {
    float Tr[8];
#pragma unroll
    for (int j = 0; j < 8; ++j) Tr[j] = 0.f;
#pragma unroll
    for (int j = 0; j < 8; ++j) {
      int grow = rbase + rsign * j;
      float tj = (blk < 128) ? tau_u[grow] : tau_v[grow];
      float a = 0.f;
#pragma unroll
      for (int k = 0; k < 8; ++k) {
        if (k < j) a += Tr[k] * G[k * 8 + j];
      }
      Tr[j] = (lane == j) ? tj : (-tj * a);
    }
#pragma unroll
    for (int j = 0; j < 8; ++j) T8all[(size_t)blk * 64 + lane * 8 + j] = Tr[j];
  }
}

// -------------------- splitY --------------------
__global__ __launch_bounds__(256) void splity_kernel(
    const float* __restrict__ U, const float* __restrict__ V,
    unsigned short* __restrict__ Yhi, unsigned short* __restrict__ Ylo,
    unsigned short* __restrict__ YThi, unsigned short* __restrict__ YTlo) {
  __shared__ float ys[128][129];
  const int tid = threadIdx.x;
  const int c = blockIdx.x >> 3, et = blockIdx.x & 7;
  const int half = tid & 1;
  const int slot = tid >> 1;
  const int e0 = et << 7;
  const int grow = (c < 8) ? ((c << 7) + slot) : (1023 - ((c - 8) << 7) - slot);
  const float* src = ((c < 8) ? U : V) + (size_t)grow * NN + e0 + (half << 6);
#pragma unroll
  for (int i = 0; i < 16; ++i) {
    float4 v4 = *reinterpret_cast<const float4*>(src + (i << 2));
    const int kk = (half << 6) + (i << 2);
    ys[slot][kk + 0] = v4.x; ys[slot][kk + 1] = v4.y;
    ys[slot][kk + 2] = v4.z; ys[slot][kk + 3] = v4.w;
  }
  __syncthreads();
  {
    const size_t rbase = ((size_t)(c * 128 + slot)) * NN + e0 + (half << 6);
#pragma unroll
    for (int i = 0; i < 16; ++i) {
      const int kk = (half << 6) + (i << 2);
      ushort4 h4, l4;
      split_bf16(ys[slot][kk + 0], h4.x, l4.x);
      split_bf16(ys[slot][kk + 1], h4.y, l4.y);
      split_bf16(ys[slot][kk + 2], h4.z, l4.z);
      split_bf16(ys[slot][kk + 3], h4.w, l4.w);
      *reinterpret_cast<ushort4*>(&Yhi[rbase + (i << 2)]) = h4;
      *reinterpret_cast<ushort4*>(&Ylo[rbase + (i << 2)]) = l4;
    }
  }
  {
    const int e = slot;
    const size_t tbase = ((size_t)c * 1024 + e0 + e) * 128 + (half << 6);
#pragma unroll
    for (int i = 0; i < 16; ++i) {
      const int k0 = (half << 6) + (i << 2);
      ushort4 h4, l4;
      split_bf16(ys[k0 + 0][e], h4.x, l4.x);
      split_bf16(ys[k0 + 1][e], h4.y, l4.y);
      split_bf16(ys[k0 + 2][e], h4.z, l4.z);
      split_bf16(ys[k0 + 3][e], h4.w, l4.w);
      *reinterpret_cast<ushort4*>(&YThi[tbase + (i << 2)]) = h4;
      *reinterpret_cast<ushort4*>(&YTlo[tbase + (i << 2)]) = l4;
    }
  }
}

#define LDK 40
#define BM 128
#define BN 128
#define BK 32

// -------------------- gramT (K-split 8x) with triangular skip ----
// Block (c,ks): Y rows of chain c are all-zero over e in [128ks,128ks+128) when
// U: ks < c, V: ks < 7-cc -> whole G slice exactly zero (triu support).
__global__ __launch_bounds__(256) void gramt_kernel(
    const unsigned short* __restrict__ Yhi, const unsigned short* __restrict__ Ylo,
    float* __restrict__ Gp) {
  const int tid = threadIdx.x;
  const int c = blockIdx.x >> 3, ks = blockIdx.x & 7;
  const bool productive = (c < 8) ? (ks >= c) : (ks >= 7 - (c - 8));
  if (!productive) {
    float4 z = {0.f, 0.f, 0.f, 0.f};
    float4* dst = reinterpret_cast<float4*>(Gp + (((size_t)c * 8 + ks) << 14));
    for (int i = tid; i < 4096; i += 256) dst[i] = z;
    return;
  }
  __shared__ unsigned short Hs[128 * LDK];
  __shared__ unsigned short Ls[128 * LDK];
  const int lane = tid & 63, wave = tid >> 6;
  const int wm = wave & 1, wn = wave >> 1;
  const int srow = tid >> 1, scol = (tid & 1) << 4;
  const unsigned short* ph = Yhi + ((size_t)(c * 128 + srow)) * NN + ks * 128 + scol;
  const unsigned short* pl = Ylo + ((size_t)(c * 128 + srow)) * NN + ks * 128 + scol;

  f32x4 acc[4][4];
#pragma unroll
  for (int a = 0; a < 4; ++a)
#pragma unroll
    for (int b = 0; b < 4; ++b) acc[a][b] = 0.f;

  const int arow0 = wm * 64, brow0 = wn * 64;
  const int fr = lane & 15, kb = (lane >> 4) << 3;

#pragma unroll 1
  for (int kt = 0; kt < 4; ++kt) {
    __syncthreads();
    *reinterpret_cast<uint4*>(&Hs[srow * LDK + scol]) = *reinterpret_cast<const uint4*>(ph + kt * 32);
    *reinterpret_cast<uint4*>(&Hs[srow * LDK + scol + 8]) = *reinterpret_cast<const uint4*>(ph + kt * 32 + 8);
    *reinterpret_cast<uint4*>(&Ls[srow * LDK + scol]) = *reinterpret_cast<const uint4*>(pl + kt * 32);
    *reinterpret_cast<uint4*>(&Ls[srow * LDK + scol + 8]) = *reinterpret_cast<const uint4*>(pl + kt * 32 + 8);
    __syncthreads();
    short8 ah[4], al[4], bh[4], bl[4];
#pragma unroll
    for (int tr = 0; tr < 4; ++tr) {
      ah[tr] = *reinterpret_cast<const short8*>(&Hs[(arow0 + tr * 16 + fr) * LDK + kb]);
      al[tr] = *reinterpret_cast<const short8*>(&Ls[(arow0 + tr * 16 + fr) * LDK + kb]);
    }
#pragma unroll
    for (int tc = 0; tc < 4; ++tc) {
      bh[tc] = *reinterpret_cast<const short8*>(&Hs[(brow0 + tc * 16 + fr) * LDK + kb]);
      bl[tc] = *reinterpret_cast<const short8*>(&Ls[(brow0 + tc * 16 + fr) * LDK + kb]);
    }
#pragma unroll
    for (int tr = 0; tr < 4; ++tr)
#pragma unroll
      for (int tc = 0; tc < 4; ++tc) {
        acc[tr][tc] = __builtin_amdgcn_mfma_f32_16x16x32_bf16(ah[tr], bh[tc], acc[tr][tc], 0, 0, 0);
        acc[tr][tc] = __builtin_amdgcn_mfma_f32_16x16x32_bf16(ah[tr], bl[tc], acc[tr][tc], 0, 0, 0);
        acc[tr][tc] = __builtin_amdgcn_mfma_f32_16x16x32_bf16(al[tr], bh[tc], acc[tr][tc], 0, 0, 0);
      }
  }
  const int rq = (lane >> 4) << 2;
#pragma unroll
  for (int tc = 0; tc < 4; ++tc) {
    const int gc = brow0 + tc * 16 + fr;
#pragma unroll
    for (int tr = 0; tr < 4; ++tr) {
      const int gr = arow0 + tr * 16 + rq;
#pragma unroll
      for (int q = 0; q < 4; ++q)
        Gp[(((size_t)c * 8 + ks) * 128 + gr + q) * 128 + gc] = acc[tr][tc][q];
    }
  }
}

// -------------------- gsum + Tg init --------------------
__global__ __launch_bounds__(256) void gsum_tinit_kernel(
    const float* __restrict__ Gp, const float* __restrict__ T8all,
    float* __restrict__ G, float* __restrict__ Tg) {
  const int bid = blockIdx.x;
  if (bid < 1024) {
    const size_t i = (size_t)bid * 256 + threadIdx.x;
    const size_t c = i >> 14, rc = i & 16383;
    float s = 0.f;
#pragma unroll
    for (int sl = 0; sl < 8; ++sl)
      s += Gp[(c * 8 + sl) * 16384 + rc];
    G[i] = s;
  } else {
    const size_t base = ((size_t)(bid - 1024) * 256 + threadIdx.x) * 16;
#pragma unroll 1
    for (int e = 0; e < 16; ++e) {
      const size_t i = base + e;
      const int c = (int)(i >> 14), rc = (int)(i & 16383);
      const int r = rc >> 7, cl = rc & 127;
      float v = 0.f;
      if ((r >> 3) == (cl >> 3)) {
        const int sb = r >> 3;
        const int t8i = (c < 8) ? (16 * c + sb) : (128 + 16 * (c - 8) + sb);
        v = T8all[(size_t)t8i * 64 + (r & 7) * 8 + (cl & 7)];
      }
      Tg[i] = v;
    }
  }
}

// -------------------- tmerge<B> --------------------
template <int B>
__global__ __launch_bounds__(256) void tmerge_kernel(
    const float* __restrict__ G, float* __restrict__ Tg) {
  __shared__ float T1s[B * B], T2s[B * B], Gs[B * B], Xs[B * B];
  const int nm = 128 / (2 * B);
  const int c = blockIdx.x / nm, m = blockIdx.x % nm;
  const int a0 = 2 * B * m;
  const int tid = threadIdx.x;
  float* Tc = Tg + (size_t)c * 16384;
  for (int i = tid; i < B * B; i += 256) {
    const int r = i / B, cl = i % B;
    T1s[i] = Tc[(a0 + r) * 128 + a0 + cl];
    T2s[i] = Tc[(a0 + B + r) * 128 + a0 + B + cl];
    Gs[i] = G[((size_t)c * 128 + a0 + r) * 128 + a0 + B + cl];
  }
  __syncthreads();
  for (int i = tid; i < B * B; i += 256) {
    const int r = i / B, cl = i % B;
    float s = 0.f;
    for (int k = 0; k <= cl; ++k) s += Gs[r * B + k] * T2s[k * B + cl];
    Xs[i] = s;
  }
  __syncthreads();
  for (int i = tid; i < B * B; i += 256) {
    const int r = i / B, cl = i % B;
    float s = 0.f;
    for (int k = r; k < B; ++k) s -= T1s[r * B + k] * Xs[k * B + cl];
    Tc[(a0 + r) * 128 + a0 + B + cl] = s;
  }
}

// -------------------- tsplit --------------------
__global__ __launch_bounds__(256) void tsplit_kernel(
    const float* __restrict__ Tg, unsigned short* __restrict__ Thi,
    unsigned short* __restrict__ Tlo) {
  const size_t i0 = ((size_t)blockIdx.x * 256 + threadIdx.x) * 16;
#pragma unroll
  for (int v = 0; v < 4; ++v) {
    float4 t = *reinterpret_cast<const float4*>(Tg + i0 + 4 * v);
    ushort4 h4, l4;
    split_bf16(t.x, h4.x, l4.x);
    split_bf16(t.y, h4.y, l4.y);
    split_bf16(t.z, h4.z, l4.z);
    split_bf16(t.w, h4.w, l4.w);
    *reinterpret_cast<ushort4*>(&Thi[i0 + 4 * v]) = h4;
    *reinterpret_cast<ushort4*>(&Tlo[i0 + 4 * v]) = l4;
  }
}

// -------------------- zw --------------------
__global__ __launch_bounds__(256) void zw_kernel(
    const unsigned short* __restrict__ Thi, const unsigned short* __restrict__ Tlo,
    const unsigned short* __restrict__ YThi, const unsigned short* __restrict__ YTlo,
    unsigned short* __restrict__ WThi, unsigned short* __restrict__ WTlo) {
  __shared__ unsigned short Xh[128 * LDK], Xl[128 * LDK];
  __shared__ unsigned short Wh[128 * LDK], Wl[128 * LDK];
  const int tid = threadIdx.x;
  const int lane = tid & 63, wave = tid >> 6;
  const int c = blockIdx.x >> 3, bn = blockIdx.x & 7;
  const int n0 = bn * 128;
  const int wm = wave & 1, wn = wave >> 1;
  const int srow = tid >> 1, scol = (tid & 1) << 4;
  const unsigned short* pxh = Thi + ((size_t)c * 128 + srow) * 128 + scol;
  const unsigned short* pxl = Tlo + ((size_t)c * 128 + srow) * 128 + scol;
  const unsigned short* pwh = YThi + ((size_t)c * 1024 + n0 + srow) * 128 + scol;
  const unsigned short* pwl = YTlo + ((size_t)c * 1024 + n0 + srow) * 128 + scol;

  f32x4 acc[4][4];
#pragma unroll
  for (int a = 0; a < 4; ++a)
#pragma unroll
    for (int b = 0; b < 4; ++b) acc[a][b] = 0.f;

  const int arow0 = wm * 64, brow0 = wn * 64;
  const int fr = lane & 15, kb = (lane >> 4) << 3;

#pragma unroll 1
  for (int kt = 0; kt < 4; ++kt) {
    __syncthreads();
    *reinterpret_cast<uint4*>(&Xh[srow * LDK + scol]) = *reinterpret_cast<const uint4*>(pxh + kt * 32);
    *reinterpret_cast<uint4*>(&Xh[srow * LDK + scol + 8]) = *reinterpret_cast<const uint4*>(pxh + kt * 32 + 8);
    *reinterpret_cast<uint4*>(&Xl[srow * LDK + scol]) = *reinterpret_cast<const uint4*>(pxl + kt * 32);
    *reinterpret_cast<uint4*>(&Xl[srow * LDK + scol + 8]) = *reinterpret_cast<const uint4*>(pxl + kt * 32 + 8);
    *reinterpret_cast<uint4*>(&Wh[srow * LDK + scol]) = *reinterpret_cast<const uint4*>(pwh + kt * 32);
    *reinterpret_cast<uint4*>(&Wh[srow * LDK + scol + 8]) = *reinterpret_cast<const uint4*>(pwh + kt * 32 + 8);
    *reinterpret_cast<uint4*>(&Wl[srow * LDK + scol]) = *reinterpret_cast<const uint4*>(pwl + kt * 32);
    *reinterpret_cast<uint4*>(&Wl[srow * LDK + scol + 8]) = *reinterpret_cast<const uint4*>(pwl + kt * 32 + 8);
    __syncthreads();
    short8 ah[4], al[4], bh[4], bl[4];
#pragma unroll
    for (int tr = 0; tr < 4; ++tr) {
      ah[tr] = *reinterpret_cast<const short8*>(&Xh[(arow0 + tr * 16 + fr) * LDK + kb]);
      al[tr] = *reinterpret_cast<const short8*>(&Xl[(arow0 + tr * 16 + fr) * LDK + kb]);
    }
#pragma unroll
    for (int tc = 0; tc < 4; ++tc) {
      bh[tc] = *reinterpret_cast<const short8*>(&Wh[(brow0 + tc * 16 + fr) * LDK + kb]);
      bl[tc] = *reinterpret_cast<const short8*>(&Wl[(brow0 + tc * 16 + fr) * LDK + kb]);
    }
#pragma unroll
    for (int tr = 0; tr < 4; ++tr)
#pragma unroll
      for (int tc = 0; tc < 4; ++tc) {
        acc[tr][tc] = __builtin_amdgcn_mfma_f32_16x16x32_bf16(ah[tr], bh[tc], acc[tr][tc], 0, 0, 0);
        acc[tr][tc] = __builtin_amdgcn_mfma_f32_16x16x32_bf16(ah[tr], bl[tc], acc[tr][tc], 0, 0, 0);
        acc[tr][tc] = __builtin_amdgcn_mfma_f32_16x16x32_bf16(al[tr], bh[tc], acc[tr][tc], 0, 0, 0);
      }
  }
  const int rq = (lane >> 4) << 2;
#pragma unroll
  for (int tc = 0; tc < 4; ++tc) {
    const int gc = brow0 + tc * 16 + fr;
#pragma unroll
    for (int tr = 0; tr < 4; ++tr) {
      const int gr = arow0 + tr * 16 + rq;
      ushort4 h4, l4;
      split_bf16(acc[tr][tc][0], h4.x, l4.x);
      split_bf16(acc[tr][tc][1], h4.y, l4.y);
      split_bf16(acc[tr][tc][2], h4.z, l4.z);
      split_bf16(acc[tr][tc][3], h4.w, l4.w);
      const size_t off = ((size_t)c * 1024 + n0 + gc) * 128 + gr;
      *reinterpret_cast<ushort4*>(&WThi[off]) = h4;
      *reinterpret_cast<ushort4*>(&WTlo[off]) = l4;
    }
  }
}

// -------------------- chainC with triangular skip ----
// Chain c deviates from I only in [z0:N)^2, z0 = (c<8)?128c : 896-128(c-8)
// (exact triu-support algebra; stored values outside are exact bf16 0/1).
__global__ __launch_bounds__(256) void chainc_kernel(
    const unsigned short* __restrict__ YThi, const unsigned short* __restrict__ YTlo,
    const unsigned short* __restrict__ WThi, const unsigned short* __restrict__ WTlo,
    unsigned short* __restrict__ chains) {
  const int tid = threadIdx.x;
  const int lane = tid & 63, wave = tid >> 6;
  const int c = blockIdx.x >> 6, b6 = blockIdx.x & 63;
  const int bm = b6 & 7, bn = b6 >> 3;
  const int m0 = bm * 128, n0 = bn * 128;
  const int wm = wave & 1, wn = wave >> 1;
  const int arow0 = wm * 64, brow0 = wn * 64;
  const int fr = lane & 15, kb = (lane >> 4) << 3;
  const int rq = (lane >> 4) << 2;
  unsigned short* dst = chains + (size_t)c * ME;

  const int z0 = (c < 8) ? (128 * c) : (896 - 128 * (c - 8));
  if (m0 < z0 || n0 < z0) {
    // identity tile
    if ((c & 1) == 0) {
#pragma unroll
      for (int tc = 0; tc < 4; ++tc) {
        const int gcg = n0 + brow0 + tc * 16 + fr;
#pragma unroll
        for (int tr = 0; tr < 4; ++tr) {
          const int grg = m0 + arow0 + tr * 16 + rq;
#pragma unroll
          for (int q = 0; q < 4; ++q)
            dst[(size_t)(grg + q) * NN + gcg] = f32_to_bf16_rne((grg + q) == gcg ? 1.0f : 0.0f);
        }
      }
    } else {
#pragma unroll
      for (int tc = 0; tc < 4; ++tc) {
        const int gcg = n0 + brow0 + tc * 16 + fr;
#pragma unroll
        for (int tr = 0; tr < 4; ++tr) {
          const int grg = m0 + arow0 + tr * 16 + rq;
          ushort4 pk;
          pk.x = f32_to_bf16_rne((grg + 0) == gcg ? 1.0f : 0.0f);
          pk.y = f32_to_bf16_rne((grg + 1) == gcg ? 1.0f : 0.0f);
          pk.z = f32_to_bf16_rne((grg + 2) == gcg ? 1.0f : 0.0f);
          pk.w = f32_to_bf16_rne((grg + 3) == gcg ? 1.0f : 0.0f);
          *reinterpret_cast<ushort4*>(&dst[(size_t)gcg * NN + grg]) = pk;
        }
      }
    }
    return;
  }

  __shared__ unsigned short Xh[128 * LDK], Xl[128 * LDK];
  __shared__ unsigned short Wh[128 * LDK], Wl[128 * LDK];
  const int srow = tid >> 1, scol = (tid & 1) << 4;
  const unsigned short* pxh = YThi + ((size_t)c * 1024 + m0 + srow) * 128 + scol;
  const unsigned short* pxl = YTlo + ((size_t)c * 1024 + m0 + srow) * 128 + scol;
  const unsigned short* pwh = WThi + ((size_t)c * 1024 + n0 + srow) * 128 + scol;
  const unsigned short* pwl = WTlo + ((size_t)c * 1024 + n0 + srow) * 128 + scol;

  f32x4 acc[4][4];
#pragma unroll
  for (int a = 0; a < 4; ++a)
#pragma unroll
    for (int b = 0; b < 4; ++b) acc[a][b] = 0.f;

#pragma unroll 1
  for (int kt = 0; kt < 4; ++kt) {
    __syncthreads();
    *reinterpret_cast<uint4*>(&Xh[srow * LDK + scol]) = *reinterpret_cast<const uint4*>(pxh + kt * 32);
    *reinterpret_cast<uint4*>(&Xh[srow * LDK + scol + 8]) = *reinterpret_cast<const uint4*>(pxh + kt * 32 + 8);
    *reinterpret_cast<uint4*>(&Xl[srow * LDK + scol]) = *reinterpret_cast<const uint4*>(pxl + kt * 32);
    *reinterpret_cast<uint4*>(&Xl[srow * LDK + scol + 8]) = *reinterpret_cast<const uint4*>(pxl + kt * 32 + 8);
    *reinterpret_cast<uint4*>(&Wh[srow * LDK + scol]) = *reinterpret_cast<const uint4*>(pwh + kt * 32);
    *reinterpret_cast<uint4*>(&Wh[srow * LDK + scol + 8]) = *reinterpret_cast<const uint4*>(pwh + kt * 32 + 8);
    *reinterpret_cast<uint4*>(&Wl[srow * LDK + scol]) = *reinterpret_cast<const uint4*>(pwl + kt * 32);
    *reinterpret_cast<uint4*>(&Wl[srow * LDK + scol + 8]) = *reinterpret_cast<const uint4*>(pwl + kt * 32 + 8);
    __syncthreads();
    short8 ah[4], al[4], bh[4], bl[4];
#pragma unroll
    for (int tr = 0; tr < 4; ++tr) {
      ah[tr] = *reinterpret_cast<const short8*>(&Xh[(arow0 + tr * 16 + fr) * LDK + kb]);
      al[tr] = *reinterpret_cast<const short8*>(&Xl[(arow0 + tr * 16 + fr) * LDK + kb]);
    }
#pragma unroll
    for (int tc = 0; tc < 4; ++tc) {
      bh[tc] = *reinterpret_cast<const short8*>(&Wh[(brow0 + tc * 16 + fr) * LDK + kb]);
      bl[tc] = *reinterpret_cast<const short8*>(&Wl[(brow0 + tc * 16 + fr) * LDK + kb]);
    }
#pragma unroll
    for (int tr = 0; tr < 4; ++tr)
#pragma unroll
      for (int tc = 0; tc < 4; ++tc) {
        acc[tr][tc] = __builtin_amdgcn_mfma_f32_16x16x32_bf16(ah[tr], bh[tc], acc[tr][tc], 0, 0, 0);
        acc[tr][tc] = __builtin_amdgcn_mfma_f32_16x16x32_bf16(ah[tr], bl[tc], acc[tr][tc], 0, 0, 0);
        acc[tr][tc] = __builtin_amdgcn_mfma_f32_16x16x32_bf16(al[tr], bh[tc], acc[tr][tc], 0, 0, 0);
      }
  }
  if ((c & 1) == 0) {
#pragma unroll
    for (int tc = 0; tc < 4; ++tc) {
      const int gcg = n0 + brow0 + tc * 16 + fr;
#pragma unroll
      for (int tr = 0; tr < 4; ++tr) {
        const int grg = m0 + arow0 + tr * 16 + rq;
#pragma unroll
        for (int q = 0; q < 4; ++q) {
          const float val = ((grg + q) == gcg ? 1.0f : 0.0f) - acc[tr][tc][q];
          dst[(size_t)(grg + q) * NN + gcg] = f32_to_bf16_rne(val);
        }
      }
    }
  } else {
#pragma unroll
    for (int tc = 0; tc < 4; ++tc) {
      const int gcg = n0 + brow0 + tc * 16 + fr;
#pragma unroll
      for (int tr = 0; tr < 4; ++tr) {
        const int grg = m0 + arow0 + tr * 16 + rq;
        ushort4 pk;
        pk.x = f32_to_bf16_rne(((grg + 0) == gcg ? 1.0f : 0.0f) - acc[tr][tc][0]);
        pk.y = f32_to_bf16_rne(((grg + 1) == gcg ? 1.0f : 0.0f) - acc[tr][tc][1]);
        pk.z = f32_to_bf16_rne(((grg + 2) == gcg ? 1.0f : 0.0f) - acc[tr][tc][2]);
        pk.w = f32_to_bf16_rne(((grg + 3) == gcg ? 1.0f : 0.0f) - acc[tr][tc][3]);
        *reinterpret_cast<ushort4*>(&dst[(size_t)gcg * NN + grg]) = pk;
      }
    }
  }
}

// -------------------- 1024^3 bf16 compose: 3-buf counted vmcnt + XOR swizzle + skip ----
// Both-sides swizzle (rule #21): linear LDS dest, inverse-swizzled global
// source chunk cs = s ^ ((row>>1)&3), same XOR on the ds_read slot.
__device__ __forceinline__ void cb_stage(
    const unsigned short* __restrict__ agbase, const unsigned short* __restrict__ bgbase,
    unsigned short* __restrict__ la, unsigned short* __restrict__ lb, int tid, int kt) {
#pragma unroll
  for (int i = 0; i < 2; ++i) {
    const int slot = tid + 256 * i;
    const int row = slot >> 2, s = slot & 3;
    const int cs = s ^ ((row >> 1) & 3);
    __builtin_amdgcn_global_load_lds(
        AS1(agbase + (size_t)row * NN + kt * 32 + cs * 8), AS3(la + row * 32 + s * 8), 16, 0, 0);
  }
#pragma unroll
  for (int i = 0; i < 2; ++i) {
    const int slot = tid + 256 * i;
    const int row = slot >> 2, s = slot & 3;
    const int cs = s ^ ((row >> 1) & 3);
    __builtin_amdgcn_global_load_lds(
        AS1(bgbase + (size_t)row * NN + kt * 32 + cs * 8), AS3(lb + row * 32 + s * 8), 16, 0, 0);
  }
}

__device__ __forceinline__ void cb_compute(
    const unsigned short* __restrict__ As, const unsigned short* __restrict__ Bs,
    f32x4 acc[4][4], int arow0, int brow0, int fr, int kb) {
  short8 af[4], bf[4];
  const int ck = kb >> 3;
#pragma unroll
  for (int tr = 0; tr < 4; ++tr) {
    const int row = arow0 + tr * 16 + fr;
    const int sl = ck ^ ((row >> 1) & 3);
    af[tr] = *reinterpret_cast<const short8*>(&As[row * 32 + sl * 8]);
  }
#pragma unroll
  for (int tc = 0; tc < 4; ++tc) {
    const int row = brow0 + tc * 16 + fr;
    const int sl = ck ^ ((row >> 1) & 3);
    bf[tc] = *reinterpret_cast<const short8*>(&Bs[row * 32 + sl * 8]);
  }
#pragma unroll
  for (int tr = 0; tr < 4; ++tr)
#pragma unroll
    for (int tc = 0; tc < 4; ++tc)
      acc[tr][tc] = __builtin_amdgcn_mfma_f32_16x16x32_bf16(af[tr], bf[tc], acc[tr][tc], 0, 0, 0);
}

__device__ __forceinline__ void compose_body(
    const unsigned short* __restrict__ Xb, const unsigned short* __restrict__ Wb,
    unsigned short* __restrict__ Op, const float* __restrict__ sig, int b, bool tstore,
    int z0) {
  const int tid = threadIdx.x;
  const int lane = tid & 63, wave = tid >> 6;
  const int bm = b & 7, bn = b >> 3;
  const int m0 = bm * BM, n0 = bn * BN;
  const int wm = wave & 1, wn = wave >> 1;
  const int arow0 = wm * 64, brow0 = wn * 64;
  const int fr = lane & 15, kb = (lane >> 4) << 3;
  const int rq = (lane >> 4) << 2;

  if (m0 < z0 || n0 < z0) {
    // D = I on this tile (deviation support is [z0:N)^2); exact.
    if (!tstore) {
#pragma unroll
      for (int tc = 0; tc < 4; ++tc) {
        const int gc = n0 + brow0 + tc * 16 + fr;
        const float s = sig ? sig[gc] : 1.0f;
#pragma unroll
        for (int tr = 0; tr < 4; ++tr) {
          const int gr = m0 + arow0 + tr * 16 + rq;
#pragma unroll
          for (int q = 0; q < 4; ++q)
            Op[(size_t)(gr + q) * NN + gc] = f32_to_bf16_rne((gr + q == gc) ? s : 0.0f);
        }
      }
    } else {
#pragma unroll
      for (int tc = 0; tc < 4; ++tc) {
        const int gc = n0 + brow0 + tc * 16 + fr;
#pragma unroll
        for (int tr = 0; tr < 4; ++tr) {
          const int gr = m0 + arow0 + tr * 16 + rq;
          ushort4 pk;
          pk.x = f32_to_bf16_rne((gr + 0 == gc) ? 1.0f : 0.0f);
          pk.y = f32_to_bf16_rne((gr + 1 == gc) ? 1.0f : 0.0f);
          pk.z = f32_to_bf16_rne((gr + 2 == gc) ? 1.0f : 0.0f);
          pk.w = f32_to_bf16_rne((gr + 3 == gc) ? 1.0f : 0.0f);
          *reinterpret_cast<ushort4*>(&Op[(size_t)gc * NN + gr]) = pk;
        }
      }
    }
    return;
  }

  __shared__ unsigned short As[3][BM * 32];
  __shared__ unsigned short Bs[3][BN * 32];
  f32x4 acc[4][4];
#pragma unroll
  for (int a = 0; a < 4; ++a)
#pragma unroll
    for (int bb = 0; bb < 4; ++bb) acc[a][bb] = 0.f;

  const unsigned short* agbase = Xb + (size_t)m0 * NN;
  const unsigned short* bgbase = Wb + (size_t)n0 * NN;

  cb_stage(agbase, bgbase, &As[0][0], &Bs[0][0], tid, 0);
  cb_stage(agbase, bgbase, &As[1][0], &Bs[1][0], tid, 1);
#pragma unroll 1
  for (int kt = 0; kt < 31; ++kt) {
    asm volatile("s_waitcnt vmcnt(4)" ::: "memory");
    __builtin_amdgcn_s_barrier();
    __builtin_amdgcn_sched_barrier(0);
    if (kt + 2 < 32) {
      const int nb = (kt + 2) % 3;
      cb_stage(agbase, bgbase, &As[nb][0], &Bs[nb][0], tid, kt + 2);
    }
    cb_compute(&As[kt % 3][0], &Bs[kt % 3][0], acc, arow0, brow0, fr, kb);
  }
  asm volatile("s_waitcnt vmcnt(0)" ::: "memory");
  __builtin_amdgcn_s_barrier();
  __builtin_amdgcn_sched_barrier(0);
  cb_compute(&As[1][0], &Bs[1][0], acc, arow0, brow0, fr, kb);  // 31%3 == 1

  if (!tstore) {
#pragma unroll
    for (int tc = 0; tc < 4; ++tc) {
      const int gc = n0 + brow0 + tc * 16 + fr;
      const float s = sig ? sig[gc] : 1.0f;
#pragma unroll
      for (int tr = 0; tr < 4; ++tr) {
        const int gr = m0 + arow0 + tr * 16 + rq;
#pragma unroll
        for (int q = 0; q < 4; ++q) {
          Op[(size_t)(gr + q) * NN + gc] = f32_to_bf16_rne(acc[tr][tc][q] * s);
        }
      }
    }
  } else {
#pragma unroll
    for (int tc = 0; tc < 4; ++tc) {
      const int gc = n0 + brow0 + tc * 16 + fr;
#pragma unroll
      for (int tr = 0; tr < 4; ++tr) {
        const int gr = m0 + arow0 + tr * 16 + rq;
        ushort4 pk;
        pk.x = f32_to_bf16_rne(acc[tr][tc][0]);
        pk.y = f32_to_bf16_rne(acc[tr][tc][1]);
        pk.z = f32_to_bf16_rne(acc[tr][tc][2]);
        pk.w = f32_to_bf16_rne(acc[tr][tc][3]);
        *reinterpret_cast<ushort4*>(&Op[(size_t)gc * NN + gr]) = pk;
      }
    }
  }
}

// L1: U pairs dev [256i:N)^2, V pairs dev [768-256i:N)^2.
__global__ __launch_bounds__(256) void composeL1_kernel(
    const unsigned short* __restrict__ ch, unsigned short* __restrict__ P) {
  const int sub = blockIdx.x >> 6, b = blockIdx.x & 63;
  const int i = sub & 3;
  const unsigned short* x = ch + (size_t)((sub < 4 ? 0 : 8) + 2 * i) * ME;
  const int z0 = (sub < 4) ? (256 * i) : (768 - 256 * i);
  compose_body(x, x + ME, P + (size_t)sub * ME, nullptr, b, (i & 1) != 0, z0);
}

// L2: z0 = {0, 512, 512, 0}.
__global__ __launch_bounds__(256) void composeL2_kernel(
    const unsigned short* __restrict__ P, unsigned short* __restrict__ Q) {
  const int sub = blockIdx.x >> 6, b = blockIdx.x & 63;
  const int z0 = (sub == 1 || sub == 2) ? 512 : 0;
  compose_body(P + (size_t)(2 * sub) * ME, P + (size_t)(2 * sub + 1) * ME,
               Q + (size_t)sub * ME, nullptr, b, (sub & 1) != 0, z0);
}

__global__ __launch_bounds__(256) void composeL3_kernel(
    const unsigned short* __restrict__ Q, const float* __restrict__ sigmas,
    unsigned short* __restrict__ F) {
  const int sub = blockIdx.x >> 6, b = blockIdx.x & 63;
  if (sub == 0) compose_body(Q, Q + ME, F, sigmas, b, false, 0);
  else compose_body(Q + 2 * ME, Q + 3 * ME, F + ME, nullptr, b, true, 0);
}

__global__ __launch_bounds__(256) void composeL4_kernel(
    const unsigned short* __restrict__ F, unsigned short* __restrict__ Mt) {
  compose_body(F + ME, F, Mt, nullptr, blockIdx.x, false, 0);
}

// -------------------- gemm256: 256x128 tile, 3-buf counted vmcnt + swizzle ----
__global__ __launch_bounds__(512) void gemm256_kernel(
    const unsigned short* __restrict__ Xb, const unsigned short* __restrict__ Mt,
    const float* __restrict__ bias, float* __restrict__ Out) {
  __shared__ unsigned short As[3][256 * 32];
  __shared__ unsigned short Bs[3][128 * 32];
  const int tid = threadIdx.x;
  const int lane = tid & 63, wave = tid >> 6;
  const int bm = blockIdx.x & 63, bn = blockIdx.x >> 6;
  const int m0 = bm * 256, n0 = bn * 128;
  const int wm = wave & 3, wn = wave >> 2;
  const int arow0 = wm * 64, brow0 = wn * 64;
  const int fr = lane & 15, kb = (lane >> 4) << 3;

  f32x4 acc[4][4];
#pragma unroll
  for (int a = 0; a < 4; ++a)
#pragma unroll
    for (int b = 0; b < 4; ++b) acc[a][b] = 0.f;

  const unsigned short* agbase = Xb + (size_t)m0 * NN;
  const unsigned short* bgbase = Mt + (size_t)n0 * NN;

#define G256_STAGE(B, KT)                                                        \
  {                                                                              \
    _Pragma("unroll")                                                            \
    for (int i = 0; i < 2; ++i) {                                                \
      const int slot = tid + 512 * i;                                            \
      const int row = slot >> 2, s = slot & 3;                                   \
      const int cs = s ^ ((row >> 1) & 3);                                       \
      __builtin_amdgcn_global_load_lds(                                          \
          AS1(agbase + (size_t)row * NN + (KT) * 32 + cs * 8),                   \
          AS3(&As[B][row * 32 + s * 8]), 16, 0, 0);                              \
    }                                                                            \
    {                                                                            \
      const int row = tid >> 2, s = tid & 3;                                     \
      const int cs = s ^ ((row >> 1) & 3);                                       \
      __builtin_amdgcn_global_load_lds(                                          \
          AS1(bgbase + (size_t)row * NN + (KT) * 32 + cs * 8),                   \
          AS3(&Bs[B][row * 32 + s * 8]), 16, 0, 0);                              \
    }                                                                            \
  }

#define G256_CMP(B)                                                              \
  {                                                                              \
    short8 af[4], bf4[4];                                                        \
    const int ck = kb >> 3;                                                      \
    _Pragma("unroll")                                                            \
    for (int tr = 0; tr < 4; ++tr) {                                             \
      const int row = arow0 + tr * 16 + fr;                                      \
      const int sl = ck ^ ((row >> 1) & 3);                                      \
      af[tr] = *reinterpret_cast<const short8*>(&As[B][row * 32 + sl * 8]);      \
    }                                                                            \
    _Pragma("unroll")                                                            \
    for (int tc = 0; tc < 4; ++tc) {                                             \
      const int row = brow0 + tc * 16 + fr;                                      \
      const int sl = ck ^ ((row >> 1) & 3);                                      \
      bf4[tc] = *reinterpret_cast<const short8*>(&Bs[B][row * 32 + sl * 8]);     \
    }                                                                            \
    _Pragma("unroll")                                                            \
    for (int tr = 0; tr < 4; ++tr)                                               \
      _Pragma("unroll")                                                          \
      for (int tc = 0; tc < 4; ++tc)                                             \
        acc[tr][tc] = __builtin_amdgcn_mfma_f32_16x16x32_bf16(af[tr], bf4[tc], acc[tr][tc], 0, 0, 0); \
  }

  G256_STAGE(0, 0)
  G256_STAGE(1, 1)
#pragma unroll 1
  for (int kt = 0; kt < 31; ++kt) {
    asm volatile("s_waitcnt vmcnt(3)" ::: "memory");
    __builtin_amdgcn_s_barrier();
    __builtin_amdgcn_sched_barrier(0);
    if (kt + 2 < 32) {
      const int nb = (kt + 2) % 3;
      G256_STAGE(nb, kt + 2)
    }
    G256_CMP(kt % 3)
  }
  asm volatile("s_waitcnt vmcnt(0)" ::: "memory");
  __builtin_amdgcn_s_barrier();
  __builtin_amdgcn_sched_barrier(0);
  G256_CMP(1)
#undef G256_STAGE
#undef G256_CMP

  const int rq = (lane >> 4) << 2;
#pragma unroll
  for (int tc = 0; tc < 4; ++tc) {
    const int gc = n0 + brow0 + tc * 16 + fr;
    const float bv = bias[gc];
#pragma unroll
    for (int tr = 0; tr < 4; ++tr) {
      const int gr = m0 + arow0 + tr * 16 + rq;
#pragma unroll
      for (int q = 0; q < 4; ++q) {
        Out[(size_t)(gr + q) * NN + gc] = acc[tr][tc][q] + bv;
      }
    }
  }
}

// -------------------- fallback gemm --------------------
__global__ __launch_bounds__(256) void gemm_fb_kernel(
    const float* __restrict__ X, const unsigned short* __restrict__ Mt,
    const float* __restrict__ bias, float* __restrict__ Out) {
  __shared__ float Af[2][BM * 32];
  __shared__ unsigned short Bsl[2][BN * 32];
  const int tid = threadIdx.x;
  const int lane = tid & 63, wave = tid >> 6;
  const int bm = blockIdx.x & 127;
  const int bn = blockIdx.x >> 7;
  const int m0 = bm * BM, n0 = bn * BN;
  const int wm = wave & 1, wn = wave >> 1;
  const int arow0 = wm * 64, brow0 = wn * 64;
  const int fr = lane & 15, kb = (lane >> 4) << 3;

  f32x4 acc[4][4];
#pragma unroll
  for (int a = 0; a < 4; ++a)
#pragma unroll
    for (int b = 0; b < 4; ++b) acc[a][b] = 0.f;

  const float* agbase = X + (size_t)m0 * NN;
  const unsigned short* bgbase = Mt + (size_t)n0 * NN;

#define FB_STAGE(PB, KT)                                                        \
  {                                                                             \
    _Pragma("unroll")                                                           \
    for (int i = 0; i < 4; ++i) {                                               \
      const int slot = tid + 256 * i;                                           \
      const int row = slot >> 3, s = slot & 7;                                  \
      __builtin_amdgcn_global_load_lds(                                         \
          AS1(agbase + (size_t)row * NN + (KT) * 32 + s * 4),                   \
          AS3(&Af[PB][row * 32 + s * 4]), 16, 0, 0);                            \
    }                                                                           \
    _Pragma("unroll")                                                           \
    for (int i = 0; i < 2; ++i) {                                               \
      const int slot = tid + 256 * i;                                           \
      const int row = slot >> 2, s = slot & 3;                                  \
      __builtin_amdgcn_global_load_lds(                                         \
          AS1(bgbase + (size_t)row * NN + (KT) * 32 + s * 8),                   \
          AS3(&Bsl[PB][row * 32 + s * 8]), 16, 0, 0);                           \
    }                                                                           \
  }

  FB_STAGE(0, 0)
  int pb = 0;
#pragma unroll 1
  for (int kt = 0; kt < 32; ++kt) {
    __syncthreads();
    if (kt + 1 < 32) FB_STAGE(pb ^ 1, kt + 1)
    {
      short8 af[4], bf[4];
      const int c0 = kb >> 2;
#pragma unroll
      for (int tr = 0; tr < 4; ++tr) {
        const int row = arow0 + tr * 16 + fr;
        const f32x4 a0 = *reinterpret_cast<const f32x4*>(&Af[pb][row * 32 + c0 * 4]);
        const f32x4 a1 = *reinterpret_cast<const f32x4*>(&Af[pb][row * 32 + (c0 + 1) * 4]);
        uint4 w;
        w.x = pack2bf(a0[0], a0[1]); w.y = pack2bf(a0[2], a0[3]);
        w.z = pack2bf(a1[0], a1[1]); w.w = pack2bf(a1[2], a1[3]);
        af[tr] = *reinterpret_cast<const short8*>(&w);
      }
#pragma unroll
      for (int tc = 0; tc < 4; ++tc) {
        const int row = brow0 + tc * 16 + fr;
        bf[tc] = *reinterpret_cast<const short8*>(&Bsl[pb][row * 32 + kb]);
      }
#pragma unroll
      for (int tr = 0; tr < 4; ++tr)
#pragma unroll
        for (int tc = 0; tc < 4; ++tc)
          acc[tr][tc] = __builtin_amdgcn_mfma_f32_16x16x32_bf16(af[tr], bf[tc], acc[tr][tc], 0, 0, 0);
    }
    pb ^= 1;
  }
#undef FB_STAGE

  const int rq = (lane >> 4) << 2;
#pragma unroll
  for (int tc = 0; tc < 4; ++tc) {
    const int gc = n0 + brow0 + tc * 16 + fr;
    const float bv = bias[gc];
#pragma unroll
    for (int tr = 0; tr < 4; ++tr) {
      const int gr = m0 + arow0 + tr * 16 + rq;
#pragma unroll
      for (int q = 0; q < 4; ++q) {
        Out[(size_t)(gr + q) * NN + gc] = acc[tr][tc][q] + bv;
      }
    }
  }
}

extern "C" void kernel_launch(void* const* d_in, const int* in_sizes, int n_in,
                              void* d_out, int out_size, void* d_ws, size_t ws_size,
                              hipStream_t stream) {
  const float* x = (const float*)d_in[0];
  const float* U = (const float*)d_in[1];
  const float* V = (const float*)d_in[2];
  const float* p = (const float*)d_in[3];
  const float* bias = (const float*)d_in[4];
  float* out = (float*)d_out;

  char* ws = (char*)d_ws;
  float* tau_u = (float*)(ws);
  float* tau_v = (float*)(ws + 4096);
  float* sigmas = (float*)(ws + 8192);
  float* T8all = (float*)(ws + 16384);                 // 64 KB
  unsigned short* Mt = (unsigned short*)(ws + 81920);  // 2 MB

  const size_t XB_OFF = 4u * 1024 * 1024;
  const size_t XB_BYTES = (size_t)NBATCH * NN * 2;     // 32 MB
  const bool fast = ws_size >= XB_OFF + XB_BYTES;
  unsigned short* Xb = (unsigned short*)(ws + XB_OFF);

  unsigned short* sc = (unsigned short*)d_out;
  unsigned short* chains = sc;
  unsigned short* P = sc + 16 * ME;
  unsigned short* Q = sc + 24 * ME;
  unsigned short* F = sc + 28 * ME;
  unsigned short* YThi = sc + 16 * ME;
  unsigned short* YTlo = sc + 18 * ME;
  unsigned short* WThi = sc + 20 * ME;
  unsigned short* WTlo = sc + 22 * ME;
  unsigned short* Yhi = sc + 24 * ME;
  unsigned short* Ylo = sc + 26 * ME;
  float* Gp = (float*)(sc + 28 * ME);
  float* G = (float*)sc;                               // chains region, dead until chainc
  float* Tg = (float*)(sc + ME);
  unsigned short* Thi = sc + 24 * ME;                  // dead Yhi region
  unsigned short* Tlo = Thi + 262144;

  prep_kernel<<<516, 256, 0, stream>>>(U, V, p, tau_u, tau_v, sigmas);
  if (fast) castx_kernel<<<2048, 256, 0, stream>>>(x, Xb);
  gram_t8_kernel<<<256, 64, 0, stream>>>(U, V, tau_u, tau_v, T8all);
  splity_kernel<<<128, 256, 0, stream>>>(U, V, Yhi, Ylo, YThi, YTlo);
  gramt_kernel<<<128, 256, 0, stream>>>(Yhi, Ylo, Gp);
  gsum_tinit_kernel<<<1088, 256, 0, stream>>>(Gp, T8all, G, Tg);
  tmerge_kernel<8><<<128, 256, 0, stream>>>(G, Tg);
  tmerge_kernel<16><<<64, 256, 0, stream>>>(G, Tg);
  tmerge_kernel<32><<<32, 256, 0, stream>>>(G, Tg);
  tmerge_kernel<64><<<16, 256, 0, stream>>>(G, Tg);
  tsplit_kernel<<<64, 256, 0, stream>>>(Tg, Thi, Tlo);
  zw_kernel<<<128, 256, 0, stream>>>(Thi, Tlo, YThi, YTlo, WThi, WTlo);
  chainc_kernel<<<1024, 256, 0, stream>>>(YThi, YTlo, WThi, WTlo, chains);
  composeL1_kernel<<<512, 256, 0, stream>>>(chains, P);
  composeL2_kernel<<<256, 256, 0, stream>>>(P, Q);
  composeL3_kernel<<<128, 256, 0, stream>>>(Q, sigmas, F);
  composeL4_kernel<<<64, 256, 0, stream>>>(F, Mt);
  if (fast) gemm256_kernel<<<512, 512, 0, stream>>>(Xb, Mt, bias, out);
  else gemm_fb_kernel<<<1024, 256, 0, stream>>>(x, Mt, bias, out);
}

// Round 17
// 302.587 us; speedup vs baseline: 1.1471x; 1.0513x over previous
//
#include <hip/hip_runtime.h>
#include <stdint.h>

typedef __attribute__((ext_vector_type(8))) short short8;
typedef __attribute__((ext_vector_type(4))) float f32x4;

#define NN 1024
#define NBATCH 16384
#define ME ((size_t)NN * NN)
#define AS1 (const __attribute__((address_space(1))) void*)
#define AS3 (__attribute__((address_space(3))) void*)

__device__ __forceinline__ unsigned short f32_to_bf16_rne(float f) {
  unsigned int u = __float_as_uint(f);
  unsigned int r = (u + 0x7fffu + ((u >> 16) & 1u)) >> 16;
  return (unsigned short)r;
}

__device__ __forceinline__ unsigned int pack2bf(float lo, float hi) {
  return (unsigned int)f32_to_bf16_rne(lo) | ((unsigned int)f32_to_bf16_rne(hi) << 16);
}

__device__ __forceinline__ void split_bf16(float x, unsigned short& h, unsigned short& l) {
  h = f32_to_bf16_rne(x);
  float hf = __uint_as_float((unsigned int)h << 16);
  l = f32_to_bf16_rne(x - hf);
}

__device__ __forceinline__ float allsum64(float x) {
  x += __int_as_float(__builtin_amdgcn_update_dpp(0, __float_as_int(x), 0xB1, 0xF, 0xF, true));
  x += __int_as_float(__builtin_amdgcn_update_dpp(0, __float_as_int(x), 0x4E, 0xF, 0xF, true));
  x += __int_as_float(__builtin_amdgcn_update_dpp(0, __float_as_int(x), 0x141, 0xF, 0xF, true));
  x += __int_as_float(__builtin_amdgcn_update_dpp(0, __float_as_int(x), 0x140, 0xF, 0xF, true));
#if __has_builtin(__builtin_amdgcn_permlane16_swap) && __has_builtin(__builtin_amdgcn_permlane32_swap)
  {
    auto r16 = __builtin_amdgcn_permlane16_swap(__float_as_uint(x), __float_as_uint(x), false, false);
    x = __uint_as_float(r16[0]) + __uint_as_float(r16[1]);
    auto r32 = __builtin_amdgcn_permlane32_swap(__float_as_uint(x), __float_as_uint(x), false, false);
    x = __uint_as_float(r32[0]) + __uint_as_float(r32[1]);
  }
#else
  x += __int_as_float(__builtin_amdgcn_ds_swizzle(__float_as_int(x), 0x401F));
  x += __shfl_xor(x, 32);
#endif
  return x;
}

// -------------------- prep --------------------
__global__ __launch_bounds__(256) void prep_kernel(
    const float* __restrict__ U, const float* __restrict__ V,
    const float* __restrict__ p, float* __restrict__ tau_u,
    float* __restrict__ tau_v, float* __restrict__ sigmas) {
  int wave = threadIdx.x >> 6, lane = threadIdx.x & 63;
  int row = blockIdx.x * 4 + wave;
  if (row < 2048) {
    const float* u = (row < NN) ? (U + (size_t)row * NN) : (V + (size_t)(row - NN) * NN);
    float s = 0.f;
#pragma unroll
    for (int t = 0; t < 16; ++t) { float a = u[lane + (t << 6)]; s += a * a; }
    s = allsum64(s);
    if (lane == 0) {
      float tau = 2.0f / s;
      if (row < NN) tau_u[row] = tau;
      else tau_v[row - NN] = tau;
    }
  } else if (row < 2064) {
    int j = ((row - 2048) << 6) + lane;
    float pj = p[j];
    float sg = 1.0f / (1.0f + expf(-pj));
    sigmas[j] = 0.9f * (sg - 0.5f) + 0.55f;
  }
}

// -------------------- castx --------------------
__global__ __launch_bounds__(256) void castx_kernel(
    const float* __restrict__ X, unsigned short* __restrict__ Xb) {
  const size_t n4 = (size_t)NBATCH * NN / 4;
  for (size_t i = (size_t)blockIdx.x * 256 + threadIdx.x; i < n4; i += (size_t)gridDim.x * 256) {
    float4 v = reinterpret_cast<const float4*>(X)[i];
    uint2 o;
    o.x = pack2bf(v.x, v.y);
    o.y = pack2bf(v.z, v.w);
    reinterpret_cast<uint2*>(Xb)[i] = o;
  }
}

// -------------------- gram + T8 --------------------
__global__ __launch_bounds__(64) void gram_t8_kernel(
    const float* __restrict__ U, const float* __restrict__ V,
    const float* __restrict__ tau_u, const float* __restrict__ tau_v,
    float* __restrict__ T8all) {
  __shared__ float G[64];
  const int blk = blockIdx.x;
  const int lane = threadIdx.x;
  const float* bank;
  int rbase, rsign, st;
  if (blk < 128) { bank = U; rbase = 8 * blk; rsign = 1; st = 8 * blk; }
  else { int s = blk - 128; bank = V; rbase = 1023 - 8 * s; rsign = -1; st = 1016 - 8 * s; }

  if (lane < 28) {
    int j = 1, k = 0, t = lane;
    for (int jj = 1; jj < 8; ++jj) {
      int lo = jj * (jj - 1) / 2, hi = jj * (jj + 1) / 2;
      if (t >= lo && t < hi) { j = jj; k = t - lo; }
    }
    const float* rk = bank + (size_t)(rbase + rsign * k) * NN;
    const float* rj = bank + (size_t)(rbase + rsign * j) * NN;
    float acc = 0.f;
    for (int i = st >> 2; i < 256; ++i) {
      float4 a = *reinterpret_cast<const float4*>(rk + 4 * i);
      float4 b = *reinterpret_cast<const float4*>(rj + 4 * i);
      acc += a.x * b.x + a.y * b.y + a.z * b.z + a.w * b.w;
    }
    G[k * 8 + j] = acc;
  }
  __syncthreads();

  if (lane < 8) {
    float Tr[8];
#pragma unroll
    for (int j = 0; j < 8; ++j) Tr[j] = 0.f;
#pragma unroll
    for (int j = 0; j < 8; ++j) {
      int grow = rbase + rsign * j;
      float tj = (blk < 128) ? tau_u[grow] : tau_v[grow];
      float a = 0.f;
#pragma unroll
      for (int k = 0; k < 8; ++k) {
        if (k < j) a += Tr[k] * G[k * 8 + j];
      }
      Tr[j] = (lane == j) ? tj : (-tj * a);
    }
#pragma unroll
    for (int j = 0; j < 8; ++j) T8all[(size_t)blk * 64 + lane * 8 + j] = Tr[j];
  }
}

// -------------------- splitY --------------------
__global__ __launch_bounds__(256) void splity_kernel(
    const float* __restrict__ U, const float* __restrict__ V,
    unsigned short* __restrict__ Yhi, unsigned short* __restrict__ Ylo,
    unsigned short* __restrict__ YThi, unsigned short* __restrict__ YTlo) {
  __shared__ float ys[128][129];
  const int tid = threadIdx.x;
  const int c = blockIdx.x >> 3, et = blockIdx.x & 7;
  const int half = tid & 1;
  const int slot = tid >> 1;
  const int e0 = et << 7;
  const int grow = (c < 8) ? ((c << 7) + slot) : (1023 - ((c - 8) << 7) - slot);
  const float* src = ((c < 8) ? U : V) + (size_t)grow * NN + e0 + (half << 6);
#pragma unroll
  for (int i = 0; i < 16; ++i) {
    float4 v4 = *reinterpret_cast<const float4*>(src + (i << 2));
    const int kk = (half << 6) + (i << 2);
    ys[slot][kk + 0] = v4.x; ys[slot][kk + 1] = v4.y;
    ys[slot][kk + 2] = v4.z; ys[slot][kk + 3] = v4.w;
  }
  __syncthreads();
  {
    const size_t rbase = ((size_t)(c * 128 + slot)) * NN + e0 + (half << 6);
#pragma unroll
    for (int i = 0; i < 16; ++i) {
      const int kk = (half << 6) + (i << 2);
      ushort4 h4, l4;
      split_bf16(ys[slot][kk + 0], h4.x, l4.x);
      split_bf16(ys[slot][kk + 1], h4.y, l4.y);
      split_bf16(ys[slot][kk + 2], h4.z, l4.z);
      split_bf16(ys[slot][kk + 3], h4.w, l4.w);
      *reinterpret_cast<ushort4*>(&Yhi[rbase + (i << 2)]) = h4;
      *reinterpret_cast<ushort4*>(&Ylo[rbase + (i << 2)]) = l4;
    }
  }
  {
    const int e = slot;
    const size_t tbase = ((size_t)c * 1024 + e0 + e) * 128 + (half << 6);
#pragma unroll
    for (int i = 0; i < 16; ++i) {
      const int k0 = (half << 6) + (i << 2);
      ushort4 h4, l4;
      split_bf16(ys[k0 + 0][e], h4.x, l4.x);
      split_bf16(ys[k0 + 1][e], h4.y, l4.y);
      split_bf16(ys[k0 + 2][e], h4.z, l4.z);
      split_bf16(ys[k0 + 3][e], h4.w, l4.w);
      *reinterpret_cast<ushort4*>(&YThi[tbase + (i << 2)]) = h4;
      *reinterpret_cast<ushort4*>(&YTlo[tbase + (i << 2)]) = l4;
    }
  }
}

#define LDK 40
#define BM 128
#define BN 128
#define BK 32

// -------------------- gramT (K-split 8x) with triangular skip ----
__global__ __launch_bounds__(256) void gramt_kernel(
    const unsigned short* __restrict__ Yhi, const unsigned short* __restrict__ Ylo,
    float* __restrict__ Gp) {
  const int tid = threadIdx.x;
  const int c = blockIdx.x >> 3, ks = blockIdx.x & 7;
  const bool productive = (c < 8) ? (ks >= c) : (ks >= 7 - (c - 8));
  if (!productive) {
    float4 z = {0.f, 0.f, 0.f, 0.f};
    float4* dst = reinterpret_cast<float4*>(Gp + (((size_t)c * 8 + ks) << 14));
    for (int i = tid; i < 4096; i += 256) dst[i] = z;
    return;
  }
  __shared__ unsigned short Hs[128 * LDK];
  __shared__ unsigned short Ls[128 * LDK];
  const int lane = tid & 63, wave = tid >> 6;
  const int wm = wave & 1, wn = wave >> 1;
  const int srow = tid >> 1, scol = (tid & 1) << 4;
  const unsigned short* ph = Yhi + ((size_t)(c * 128 + srow)) * NN + ks * 128 + scol;
  const unsigned short* pl = Ylo + ((size_t)(c * 128 + srow)) * NN + ks * 128 + scol;

  f32x4 acc[4][4];
#pragma unroll
  for (int a = 0; a < 4; ++a)
#pragma unroll
    for (int b = 0; b < 4; ++b) acc[a][b] = 0.f;

  const int arow0 = wm * 64, brow0 = wn * 64;
  const int fr = lane & 15, kb = (lane >> 4) << 3;

#pragma unroll 1
  for (int kt = 0; kt < 4; ++kt) {
    __syncthreads();
    *reinterpret_cast<uint4*>(&Hs[srow * LDK + scol]) = *reinterpret_cast<const uint4*>(ph + kt * 32);
    *reinterpret_cast<uint4*>(&Hs[srow * LDK + scol + 8]) = *reinterpret_cast<const uint4*>(ph + kt * 32 + 8);
    *reinterpret_cast<uint4*>(&Ls[srow * LDK + scol]) = *reinterpret_cast<const uint4*>(pl + kt * 32);
    *reinterpret_cast<uint4*>(&Ls[srow * LDK + scol + 8]) = *reinterpret_cast<const uint4*>(pl + kt * 32 + 8);
    __syncthreads();
    short8 ah[4], al[4], bh[4], bl[4];
#pragma unroll
    for (int tr = 0; tr < 4; ++tr) {
      ah[tr] = *reinterpret_cast<const short8*>(&Hs[(arow0 + tr * 16 + fr) * LDK + kb]);
      al[tr] = *reinterpret_cast<const short8*>(&Ls[(arow0 + tr * 16 + fr) * LDK + kb]);
    }
#pragma unroll
    for (int tc = 0; tc < 4; ++tc) {
      bh[tc] = *reinterpret_cast<const short8*>(&Hs[(brow0 + tc * 16 + fr) * LDK + kb]);
      bl[tc] = *reinterpret_cast<const short8*>(&Ls[(brow0 + tc * 16 + fr) * LDK + kb]);
    }
#pragma unroll
    for (int tr = 0; tr < 4; ++tr)
#pragma unroll
      for (int tc = 0; tc < 4; ++tc) {
        acc[tr][tc] = __builtin_amdgcn_mfma_f32_16x16x32_bf16(ah[tr], bh[tc], acc[tr][tc], 0, 0, 0);
        acc[tr][tc] = __builtin_amdgcn_mfma_f32_16x16x32_bf16(ah[tr], bl[tc], acc[tr][tc], 0, 0, 0);
        acc[tr][tc] = __builtin_amdgcn_mfma_f32_16x16x32_bf16(al[tr], bh[tc], acc[tr][tc], 0, 0, 0);
      }
  }
  const int rq = (lane >> 4) << 2;
#pragma unroll
  for (int tc = 0; tc < 4; ++tc) {
    const int gc = brow0 + tc * 16 + fr;
#pragma unroll
    for (int tr = 0; tr < 4; ++tr) {
      const int gr = arow0 + tr * 16 + rq;
#pragma unroll
      for (int q = 0; q < 4; ++q)
        Gp[(((size_t)c * 8 + ks) * 128 + gr + q) * 128 + gc] = acc[tr][tc][q];
    }
  }
}

// -------------------- gsum + Tg init --------------------
__global__ __launch_bounds__(256) void gsum_tinit_kernel(
    const float* __restrict__ Gp, const float* __restrict__ T8all,
    float* __restrict__ G, float* __restrict__ Tg) {
  const int bid = blockIdx.x;
  if (bid < 1024) {
    const size_t i = (size_t)bid * 256 + threadIdx.x;
    const size_t c = i >> 14, rc = i & 16383;
    float s = 0.f;
#pragma unroll
    for (int sl = 0; sl < 8; ++sl)
      s += Gp[(c * 8 + sl) * 16384 + rc];
    G[i] = s;
  } else {
    const size_t base = ((size_t)(bid - 1024) * 256 + threadIdx.x) * 16;
#pragma unroll 1
    for (int e = 0; e < 16; ++e) {
      const size_t i = base + e;
      const int c = (int)(i >> 14), rc = (int)(i & 16383);
      const int r = rc >> 7, cl = rc & 127;
      float v = 0.f;
      if ((r >> 3) == (cl >> 3)) {
        const int sb = r >> 3;
        const int t8i = (c < 8) ? (16 * c + sb) : (128 + 16 * (c - 8) + sb);
        v = T8all[(size_t)t8i * 64 + (r & 7) * 8 + (cl & 7)];
      }
      Tg[i] = v;
    }
  }
}

// -------------------- tmerge<B> --------------------
template <int B>
__global__ __launch_bounds__(256) void tmerge_kernel(
    const float* __restrict__ G, float* __restrict__ Tg) {
  __shared__ float T1s[B * B], T2s[B * B], Gs[B * B], Xs[B * B];
  const int nm = 128 / (2 * B);
  const int c = blockIdx.x / nm, m = blockIdx.x % nm;
  const int a0 = 2 * B * m;
  const int tid = threadIdx.x;
  float* Tc = Tg + (size_t)c * 16384;
  for (int i = tid; i < B * B; i += 256) {
    const int r = i / B, cl = i % B;
    T1s[i] = Tc[(a0 + r) * 128 + a0 + cl];
    T2s[i] = Tc[(a0 + B + r) * 128 + a0 + B + cl];
    Gs[i] = G[((size_t)c * 128 + a0 + r) * 128 + a0 + B + cl];
  }
  __syncthreads();
  for (int i = tid; i < B * B; i += 256) {
    const int r = i / B, cl = i % B;
    float s = 0.f;
    for (int k = 0; k <= cl; ++k) s += Gs[r * B + k] * T2s[k * B + cl];
    Xs[i] = s;
  }
  __syncthreads();
  for (int i = tid; i < B * B; i += 256) {
    const int r = i / B, cl = i % B;
    float s = 0.f;
    for (int k = r; k < B; ++k) s -= T1s[r * B + k] * Xs[k * B + cl];
    Tc[(a0 + r) * 128 + a0 + B + cl] = s;
  }
}

// -------------------- tsplit --------------------
__global__ __launch_bounds__(256) void tsplit_kernel(
    const float* __restrict__ Tg, unsigned short* __restrict__ Thi,
    unsigned short* __restrict__ Tlo) {
  const size_t i0 = ((size_t)blockIdx.x * 256 + threadIdx.x) * 16;
#pragma unroll
  for (int v = 0; v < 4; ++v) {
    float4 t = *reinterpret_cast<const float4*>(Tg + i0 + 4 * v);
    ushort4 h4, l4;
    split_bf16(t.x, h4.x, l4.x);
    split_bf16(t.y, h4.y, l4.y);
    split_bf16(t.z, h4.z, l4.z);
    split_bf16(t.w, h4.w, l4.w);
    *reinterpret_cast<ushort4*>(&Thi[i0 + 4 * v]) = h4;
    *reinterpret_cast<ushort4*>(&Tlo[i0 + 4 * v]) = l4;
  }
}

// -------------------- zw --------------------
__global__ __launch_bounds__(256) void zw_kernel(
    const unsigned short* __restrict__ Thi, const unsigned short* __restrict__ Tlo,
    const unsigned short* __restrict__ YThi, const unsigned short* __restrict__ YTlo,
    unsigned short* __restrict__ WThi, unsigned short* __restrict__ WTlo) {
  __shared__ unsigned short Xh[128 * LDK], Xl[128 * LDK];
  __shared__ unsigned short Wh[128 * LDK], Wl[128 * LDK];
  const int tid = threadIdx.x;
  const int lane = tid & 63, wave = tid >> 6;
  const int c = blockIdx.x >> 3, bn = blockIdx.x & 7;
  const int n0 = bn * 128;
  const int wm = wave & 1, wn = wave >> 1;
  const int srow = tid >> 1, scol = (tid & 1) << 4;
  const unsigned short* pxh = Thi + ((size_t)c * 128 + srow) * 128 + scol;
  const unsigned short* pxl = Tlo + ((size_t)c * 128 + srow) * 128 + scol;
  const unsigned short* pwh = YThi + ((size_t)c * 1024 + n0 + srow) * 128 + scol;
  const unsigned short* pwl = YTlo + ((size_t)c * 1024 + n0 + srow) * 128 + scol;

  f32x4 acc[4][4];
#pragma unroll
  for (int a = 0; a < 4; ++a)
#pragma unroll
    for (int b = 0; b < 4; ++b) acc[a][b] = 0.f;

  const int arow0 = wm * 64, brow0 = wn * 64;
  const int fr = lane & 15, kb = (lane >> 4) << 3;

#pragma unroll 1
  for (int kt = 0; kt < 4; ++kt) {
    __syncthreads();
    *reinterpret_cast<uint4*>(&Xh[srow * LDK + scol]) = *reinterpret_cast<const uint4*>(pxh + kt * 32);
    *reinterpret_cast<uint4*>(&Xh[srow * LDK + scol + 8]) = *reinterpret_cast<const uint4*>(pxh + kt * 32 + 8);
    *reinterpret_cast<uint4*>(&Xl[srow * LDK + scol]) = *reinterpret_cast<const uint4*>(pxl + kt * 32);
    *reinterpret_cast<uint4*>(&Xl[srow * LDK + scol + 8]) = *reinterpret_cast<const uint4*>(pxl + kt * 32 + 8);
    *reinterpret_cast<uint4*>(&Wh[srow * LDK + scol]) = *reinterpret_cast<const uint4*>(pwh + kt * 32);
    *reinterpret_cast<uint4*>(&Wh[srow * LDK + scol + 8]) = *reinterpret_cast<const uint4*>(pwh + kt * 32 + 8);
    *reinterpret_cast<uint4*>(&Wl[srow * LDK + scol]) = *reinterpret_cast<const uint4*>(pwl + kt * 32);
    *reinterpret_cast<uint4*>(&Wl[srow * LDK + scol + 8]) = *reinterpret_cast<const uint4*>(pwl + kt * 32 + 8);
    __syncthreads();
    short8 ah[4], al[4], bh[4], bl[4];
#pragma unroll
    for (int tr = 0; tr < 4; ++tr) {
      ah[tr] = *reinterpret_cast<const short8*>(&Xh[(arow0 + tr * 16 + fr) * LDK + kb]);
      al[tr] = *reinterpret_cast<const short8*>(&Xl[(arow0 + tr * 16 + fr) * LDK + kb]);
    }
#pragma unroll
    for (int tc = 0; tc < 4; ++tc) {
      bh[tc] = *reinterpret_cast<const short8*>(&Wh[(brow0 + tc * 16 + fr) * LDK + kb]);
      bl[tc] = *reinterpret_cast<const short8*>(&Wl[(brow0 + tc * 16 + fr) * LDK + kb]);
    }
#pragma unroll
    for (int tr = 0; tr < 4; ++tr)
#pragma unroll
      for (int tc = 0; tc < 4; ++tc) {
        acc[tr][tc] = __builtin_amdgcn_mfma_f32_16x16x32_bf16(ah[tr], bh[tc], acc[tr][tc], 0, 0, 0);
        acc[tr][tc] = __builtin_amdgcn_mfma_f32_16x16x32_bf16(ah[tr], bl[tc], acc[tr][tc], 0, 0, 0);
        acc[tr][tc] = __builtin_amdgcn_mfma_f32_16x16x32_bf16(al[tr], bh[tc], acc[tr][tc], 0, 0, 0);
      }
  }
  const int rq = (lane >> 4) << 2;
#pragma unroll
  for (int tc = 0; tc < 4; ++tc) {
    const int gc = brow0 + tc * 16 + fr;
#pragma unroll
    for (int tr = 0; tr < 4; ++tr) {
      const int gr = arow0 + tr * 16 + rq;
      ushort4 h4, l4;
      split_bf16(acc[tr][tc][0], h4.x, l4.x);
      split_bf16(acc[tr][tc][1], h4.y, l4.y);
      split_bf16(acc[tr][tc][2], h4.z, l4.z);
      split_bf16(acc[tr][tc][3], h4.w, l4.w);
      const size_t off = ((size_t)c * 1024 + n0 + gc) * 128 + gr;
      *reinterpret_cast<ushort4*>(&WThi[off]) = h4;
      *reinterpret_cast<ushort4*>(&WTlo[off]) = l4;
    }
  }
}

// -------------------- chainC with triangular skip ----
__global__ __launch_bounds__(256) void chainc_kernel(
    const unsigned short* __restrict__ YThi, const unsigned short* __restrict__ YTlo,
    const unsigned short* __restrict__ WThi, const unsigned short* __restrict__ WTlo,
    unsigned short* __restrict__ chains) {
  const int tid = threadIdx.x;
  const int lane = tid & 63, wave = tid >> 6;
  const int c = blockIdx.x >> 6, b6 = blockIdx.x & 63;
  const int bm = b6 & 7, bn = b6 >> 3;
  const int m0 = bm * 128, n0 = bn * 128;
  const int wm = wave & 1, wn = wave >> 1;
  const int arow0 = wm * 64, brow0 = wn * 64;
  const int fr = lane & 15, kb = (lane >> 4) << 3;
  const int rq = (lane >> 4) << 2;
  unsigned short* dst = chains + (size_t)c * ME;

  const int z0 = (c < 8) ? (128 * c) : (896 - 128 * (c - 8));
  if (m0 < z0 || n0 < z0) {
    if ((c & 1) == 0) {
#pragma unroll
      for (int tc = 0; tc < 4; ++tc) {
        const int gcg = n0 + brow0 + tc * 16 + fr;
#pragma unroll
        for (int tr = 0; tr < 4; ++tr) {
          const int grg = m0 + arow0 + tr * 16 + rq;
#pragma unroll
          for (int q = 0; q < 4; ++q)
            dst[(size_t)(grg + q) * NN + gcg] = f32_to_bf16_rne((grg + q) == gcg ? 1.0f : 0.0f);
        }
      }
    } else {
#pragma unroll
      for (int tc = 0; tc < 4; ++tc) {
        const int gcg = n0 + brow0 + tc * 16 + fr;
#pragma unroll
        for (int tr = 0; tr < 4; ++tr) {
          const int grg = m0 + arow0 + tr * 16 + rq;
          ushort4 pk;
          pk.x = f32_to_bf16_rne((grg + 0) == gcg ? 1.0f : 0.0f);
          pk.y = f32_to_bf16_rne((grg + 1) == gcg ? 1.0f : 0.0f);
          pk.z = f32_to_bf16_rne((grg + 2) == gcg ? 1.0f : 0.0f);
          pk.w = f32_to_bf16_rne((grg + 3) == gcg ? 1.0f : 0.0f);
          *reinterpret_cast<ushort4*>(&dst[(size_t)gcg * NN + grg]) = pk;
        }
      }
    }
    return;
  }

  __shared__ unsigned short Xh[128 * LDK], Xl[128 * LDK];
  __shared__ unsigned short Wh[128 * LDK], Wl[128 * LDK];
  const int srow = tid >> 1, scol = (tid & 1) << 4;
  const unsigned short* pxh = YThi + ((size_t)c * 1024 + m0 + srow) * 128 + scol;
  const unsigned short* pxl = YTlo + ((size_t)c * 1024 + m0 + srow) * 128 + scol;
  const unsigned short* pwh = WThi + ((size_t)c * 1024 + n0 + srow) * 128 + scol;
  const unsigned short* pwl = WTlo + ((size_t)c * 1024 + n0 + srow) * 128 + scol;

  f32x4 acc[4][4];
#pragma unroll
  for (int a = 0; a < 4; ++a)
#pragma unroll
    for (int b = 0; b < 4; ++b) acc[a][b] = 0.f;

#pragma unroll 1
  for (int kt = 0; kt < 4; ++kt) {
    __syncthreads();
    *reinterpret_cast<uint4*>(&Xh[srow * LDK + scol]) = *reinterpret_cast<const uint4*>(pxh + kt * 32);
    *reinterpret_cast<uint4*>(&Xh[srow * LDK + scol + 8]) = *reinterpret_cast<const uint4*>(pxh + kt * 32 + 8);
    *reinterpret_cast<uint4*>(&Xl[srow * LDK + scol]) = *reinterpret_cast<const uint4*>(pxl + kt * 32);
    *reinterpret_cast<uint4*>(&Xl[srow * LDK + scol + 8]) = *reinterpret_cast<const uint4*>(pxl + kt * 32 + 8);
    *reinterpret_cast<uint4*>(&Wh[srow * LDK + scol]) = *reinterpret_cast<const uint4*>(pwh + kt * 32);
    *reinterpret_cast<uint4*>(&Wh[srow * LDK + scol + 8]) = *reinterpret_cast<const uint4*>(pwh + kt * 32 + 8);
    *reinterpret_cast<uint4*>(&Wl[srow * LDK + scol]) = *reinterpret_cast<const uint4*>(pwl + kt * 32);
    *reinterpret_cast<uint4*>(&Wl[srow * LDK + scol + 8]) = *reinterpret_cast<const uint4*>(pwl + kt * 32 + 8);
    __syncthreads();
    short8 ah[4], al[4], bh[4], bl[4];
#pragma unroll
    for (int tr = 0; tr < 4; ++tr) {
      ah[tr] = *reinterpret_cast<const short8*>(&Xh[(arow0 + tr * 16 + fr) * LDK + kb]);
      al[tr] = *reinterpret_cast<const short8*>(&Xl[(arow0 + tr * 16 + fr) * LDK + kb]);
    }
#pragma unroll
    for (int tc = 0; tc < 4; ++tc) {
      bh[tc] = *reinterpret_cast<const short8*>(&Wh[(brow0 + tc * 16 + fr) * LDK + kb]);
      bl[tc] = *reinterpret_cast<const short8*>(&Wl[(brow0 + tc * 16 + fr) * LDK + kb]);
    }
#pragma unroll
    for (int tr = 0; tr < 4; ++tr)
#pragma unroll
      for (int tc = 0; tc < 4; ++tc) {
        acc[tr][tc] = __builtin_amdgcn_mfma_f32_16x16x32_bf16(ah[tr], bh[tc], acc[tr][tc], 0, 0, 0);
        acc[tr][tc] = __builtin_amdgcn_mfma_f32_16x16x32_bf16(ah[tr], bl[tc], acc[tr][tc], 0, 0, 0);
        acc[tr][tc] = __builtin_amdgcn_mfma_f32_16x16x32_bf16(al[tr], bh[tc], acc[tr][tc], 0, 0, 0);
      }
  }
  if ((c & 1) == 0) {
#pragma unroll
    for (int tc = 0; tc < 4; ++tc) {
      const int gcg = n0 + brow0 + tc * 16 + fr;
#pragma unroll
      for (int tr = 0; tr < 4; ++tr) {
        const int grg = m0 + arow0 + tr * 16 + rq;
#pragma unroll
        for (int q = 0; q < 4; ++q) {
          const float val = ((grg + q) == gcg ? 1.0f : 0.0f) - acc[tr][tc][q];
          dst[(size_t)(grg + q) * NN + gcg] = f32_to_bf16_rne(val);
        }
      }
    }
  } else {
#pragma unroll
    for (int tc = 0; tc < 4; ++tc) {
      const int gcg = n0 + brow0 + tc * 16 + fr;
#pragma unroll
      for (int tr = 0; tr < 4; ++tr) {
        const int grg = m0 + arow0 + tr * 16 + rq;
        ushort4 pk;
        pk.x = f32_to_bf16_rne(((grg + 0) == gcg ? 1.0f : 0.0f) - acc[tr][tc][0]);
        pk.y = f32_to_bf16_rne(((grg + 1) == gcg ? 1.0f : 0.0f) - acc[tr][tc][1]);
        pk.z = f32_to_bf16_rne(((grg + 2) == gcg ? 1.0f : 0.0f) - acc[tr][tc][2]);
        pk.w = f32_to_bf16_rne(((grg + 3) == gcg ? 1.0f : 0.0f) - acc[tr][tc][3]);
        *reinterpret_cast<ushort4*>(&dst[(size_t)gcg * NN + grg]) = pk;
      }
    }
  }
}

// -------------------- compose core: 3-buf counted vmcnt, variable k-range ----
__device__ __forceinline__ void cb_stage(
    const unsigned short* __restrict__ agbase, const unsigned short* __restrict__ bgbase,
    unsigned short* __restrict__ la, unsigned short* __restrict__ lb, int tid, int kt) {
#pragma unroll
  for (int i = 0; i < 2; ++i) {
    const int slot = tid + 256 * i;
    const int row = slot >> 2, s = slot & 3;
    const int cs = s ^ ((row >> 1) & 3);
    __builtin_amdgcn_global_load_lds(
        AS1(agbase + (size_t)row * NN + kt * 32 + cs * 8), AS3(la + row * 32 + s * 8), 16, 0, 0);
  }
#pragma unroll
  for (int i = 0; i < 2; ++i) {
    const int slot = tid + 256 * i;
    const int row = slot >> 2, s = slot & 3;
    const int cs = s ^ ((row >> 1) & 3);
    __builtin_amdgcn_global_load_lds(
        AS1(bgbase + (size_t)row * NN + kt * 32 + cs * 8), AS3(lb + row * 32 + s * 8), 16, 0, 0);
  }
}

__device__ __forceinline__ void cb_compute(
    const unsigned short* __restrict__ As, const unsigned short* __restrict__ Bs,
    f32x4 acc[4][4], int arow0, int brow0, int fr, int kb) {
  short8 af[4], bf[4];
  const int ck = kb >> 3;
#pragma unroll
  for (int tr = 0; tr < 4; ++tr) {
    const int row = arow0 + tr * 16 + fr;
    const int sl = ck ^ ((row >> 1) & 3);
    af[tr] = *reinterpret_cast<const short8*>(&As[row * 32 + sl * 8]);
  }
#pragma unroll
  for (int tc = 0; tc < 4; ++tc) {
    const int row = brow0 + tc * 16 + fr;
    const int sl = ck ^ ((row >> 1) & 3);
    bf[tc] = *reinterpret_cast<const short8*>(&Bs[row * 32 + sl * 8]);
  }
#pragma unroll
  for (int tr = 0; tr < 4; ++tr)
#pragma unroll
    for (int tc = 0; tc < 4; ++tc)
      acc[tr][tc] = __builtin_amdgcn_mfma_f32_16x16x32_bf16(af[tr], bf[tc], acc[tr][tc], 0, 0, 0);
}

__device__ __forceinline__ void compose_core(
    const unsigned short* __restrict__ agbase, const unsigned short* __restrict__ bgbase,
    unsigned short (*As)[BM * 32], unsigned short (*Bs)[BN * 32],
    f32x4 acc[4][4], int tid, int arow0, int brow0, int fr, int kb, int kt0, int nk) {
  cb_stage(agbase, bgbase, &As[0][0], &Bs[0][0], tid, kt0);
  if (nk >= 2) cb_stage(agbase, bgbase, &As[1][0], &Bs[1][0], tid, kt0 + 1);
#pragma unroll 1
  for (int i = 0; i < nk - 1; ++i) {
    asm volatile("s_waitcnt vmcnt(4)" ::: "memory");
    __builtin_amdgcn_s_barrier();
    __builtin_amdgcn_sched_barrier(0);
    if (i + 2 < nk) {
      const int nb = (i + 2) % 3;
      cb_stage(agbase, bgbase, &As[nb][0], &Bs[nb][0], tid, kt0 + i + 2);
    }
    cb_compute(&As[i % 3][0], &Bs[i % 3][0], acc, arow0, brow0, fr, kb);
  }
  asm volatile("s_waitcnt vmcnt(0)" ::: "memory");
  __builtin_amdgcn_s_barrier();
  __builtin_amdgcn_sched_barrier(0);
  cb_compute(&As[(nk - 1) % 3][0], &Bs[(nk - 1) % 3][0], acc, arow0, brow0, fr, kb);
}

// Direct-bf16 compose (L1, L2) with identity skip + K-support skip.
__device__ __forceinline__ void compose_body(
    const unsigned short* __restrict__ Xb, const unsigned short* __restrict__ Wb,
    unsigned short* __restrict__ Op, const float* __restrict__ sig, int b, bool tstore,
    int z0) {
  const int tid = threadIdx.x;
  const int lane = tid & 63, wave = tid >> 6;
  const int bm = b & 7, bn = b >> 3;
  const int m0 = bm * BM, n0 = bn * BN;
  const int wm = wave & 1, wn = wave >> 1;
  const int arow0 = wm * 64, brow0 = wn * 64;
  const int fr = lane & 15, kb = (lane >> 4) << 3;
  const int rq = (lane >> 4) << 2;

  if (m0 < z0 || n0 < z0) {
    if (!tstore) {
#pragma unroll
      for (int tc = 0; tc < 4; ++tc) {
        const int gc = n0 + brow0 + tc * 16 + fr;
        const float s = sig ? sig[gc] : 1.0f;
#pragma unroll
        for (int tr = 0; tr < 4; ++tr) {
          const int gr = m0 + arow0 + tr * 16 + rq;
#pragma unroll
          for (int q = 0; q < 4; ++q)
            Op[(size_t)(gr + q) * NN + gc] = f32_to_bf16_rne((gr + q == gc) ? s : 0.0f);
        }
      }
    } else {
#pragma unroll
      for (int tc = 0; tc < 4; ++tc) {
        const int gc = n0 + brow0 + tc * 16 + fr;
#pragma unroll
        for (int tr = 0; tr < 4; ++tr) {
          const int gr = m0 + arow0 + tr * 16 + rq;
          ushort4 pk;
          pk.x = f32_to_bf16_rne((gr + 0 == gc) ? 1.0f : 0.0f);
          pk.y = f32_to_bf16_rne((gr + 1 == gc) ? 1.0f : 0.0f);
          pk.z = f32_to_bf16_rne((gr + 2 == gc) ? 1.0f : 0.0f);
          pk.w = f32_to_bf16_rne((gr + 3 == gc) ? 1.0f : 0.0f);
          *reinterpret_cast<ushort4*>(&Op[(size_t)gc * NN + gr]) = pk;
        }
      }
    }
    return;
  }

  __shared__ unsigned short As[3][BM * 32];
  __shared__ unsigned short Bs[3][BN * 32];
  f32x4 acc[4][4];
#pragma unroll
  for (int a = 0; a < 4; ++a)
#pragma unroll
    for (int bb = 0; bb < 4; ++bb) acc[a][bb] = 0.f;

  const int kt0 = z0 >> 5;  // K-support: k < z0 contributes 0 on productive tiles
  const int nk = 32 - kt0;
  compose_core(Xb + (size_t)m0 * NN, Wb + (size_t)n0 * NN, As, Bs, acc,
               tid, arow0, brow0, fr, kb, kt0, nk);

  if (!tstore) {
#pragma unroll
    for (int tc = 0; tc < 4; ++tc) {
      const int gc = n0 + brow0 + tc * 16 + fr;
      const float s = sig ? sig[gc] : 1.0f;
#pragma unroll
      for (int tr = 0; tr < 4; ++tr) {
        const int gr = m0 + arow0 + tr * 16 + rq;
#pragma unroll
        for (int q = 0; q < 4; ++q) {
          Op[(size_t)(gr + q) * NN + gc] = f32_to_bf16_rne(acc[tr][tc][q] * s);
        }
      }
    }
  } else {
#pragma unroll
    for (int tc = 0; tc < 4; ++tc) {
      const int gc = n0 + brow0 + tc * 16 + fr;
#pragma unroll
      for (int tr = 0; tr < 4; ++tr) {
        const int gr = m0 + arow0 + tr * 16 + rq;
        ushort4 pk;
        pk.x = f32_to_bf16_rne(acc[tr][tc][0]);
        pk.y = f32_to_bf16_rne(acc[tr][tc][1]);
        pk.z = f32_to_bf16_rne(acc[tr][tc][2]);
        pk.w = f32_to_bf16_rne(acc[tr][tc][3]);
        *reinterpret_cast<ushort4*>(&Op[(size_t)gc * NN + gr]) = pk;
      }
    }
  }
}

// K-split partial compose (L3, L4): f32 partial output, slice covers 16 k-steps.
__device__ __forceinline__ void compose_ks_body(
    const unsigned short* __restrict__ Xb, const unsigned short* __restrict__ Wb,
    float* __restrict__ Pp, int b, bool tstore, int slice) {
  const int tid = threadIdx.x;
  const int lane = tid & 63, wave = tid >> 6;
  const int bm = b & 7, bn = b >> 3;
  const int m0 = bm * BM, n0 = bn * BN;
  const int wm = wave & 1, wn = wave >> 1;
  const int arow0 = wm * 64, brow0 = wn * 64;
  const int fr = lane & 15, kb = (lane >> 4) << 3;
  const int rq = (lane >> 4) << 2;

  __shared__ unsigned short As[3][BM * 32];
  __shared__ unsigned short Bs[3][BN * 32];
  f32x4 acc[4][4];
#pragma unroll
  for (int a = 0; a < 4; ++a)
#pragma unroll
    for (int bb = 0; bb < 4; ++bb) acc[a][bb] = 0.f;

  compose_core(Xb + (size_t)m0 * NN, Wb + (size_t)n0 * NN, As, Bs, acc,
               tid, arow0, brow0, fr, kb, slice * 16, 16);

  if (!tstore) {
#pragma unroll
    for (int tc = 0; tc < 4; ++tc) {
      const int gc = n0 + brow0 + tc * 16 + fr;
#pragma unroll
      for (int tr = 0; tr < 4; ++tr) {
        const int gr = m0 + arow0 + tr * 16 + rq;
#pragma unroll
        for (int q = 0; q < 4; ++q)
          Pp[(size_t)(gr + q) * NN + gc] = acc[tr][tc][q];
      }
    }
  } else {
#pragma unroll
    for (int tc = 0; tc < 4; ++tc) {
      const int gc = n0 + brow0 + tc * 16 + fr;
#pragma unroll
      for (int tr = 0; tr < 4; ++tr) {
        const int gr = m0 + arow0 + tr * 16 + rq;
        float4 v = {acc[tr][tc][0], acc[tr][tc][1], acc[tr][tc][2], acc[tr][tc][3]};
        *reinterpret_cast<float4*>(&Pp[(size_t)gc * NN + gr]) = v;  // gr%4==0
      }
    }
  }
}

// L1: direct bf16, z0 = U:256i / V:768-256i (K-support skip inside).
__global__ __launch_bounds__(256) void composeL1_kernel(
    const unsigned short* __restrict__ ch, unsigned short* __restrict__ P) {
  const int sub = blockIdx.x >> 6, b = blockIdx.x & 63;
  const int i = sub & 3;
  const unsigned short* x = ch + (size_t)((sub < 4 ? 0 : 8) + 2 * i) * ME;
  const int z0 = (sub < 4) ? (256 * i) : (768 - 256 * i);
  compose_body(x, x + ME, P + (size_t)sub * ME, nullptr, b, (i & 1) != 0, z0);
}

// L2: direct bf16, z0 = {0,512,512,0}.
__global__ __launch_bounds__(256) void composeL2_kernel(
    const unsigned short* __restrict__ P, unsigned short* __restrict__ Q) {
  const int sub = blockIdx.x >> 6, b = blockIdx.x & 63;
  const int z0 = (sub == 1 || sub == 2) ? 512 : 0;
  compose_body(P + (size_t)(2 * sub) * ME, P + (size_t)(2 * sub + 1) * ME,
               Q + (size_t)sub * ME, nullptr, b, (sub & 1) != 0, z0);
}

// L3 K-split-2: grid 256. sub0: Q0*Q1 rm; sub1: (Q2*Q3)^T. Partials f32.
__global__ __launch_bounds__(256) void composeL3ks_kernel(
    const unsigned short* __restrict__ Q, float* __restrict__ P32) {
  const int sub = blockIdx.x >> 7, slice = (blockIdx.x >> 6) & 1, b = blockIdx.x & 63;
  const unsigned short* X = Q + (size_t)(2 * sub) * ME;
  const unsigned short* W = Q + (size_t)(2 * sub + 1) * ME;
  compose_ks_body(X, W, P32 + (size_t)(sub * 2 + slice) * ME, b, sub == 1, slice);
}

// L4 K-split-2: grid 128. Mt = MVt x MUsig (rm).
__global__ __launch_bounds__(256) void composeL4ks_kernel(
    const unsigned short* __restrict__ F, float* __restrict__ P32) {
  const int slice = blockIdx.x >> 6, b = blockIdx.x & 63;
  compose_ks_body(F + ME, F, P32 + (size_t)slice * ME, b, false, slice);
}

// reduce2: out = bf16((p0+p1) * sig[col]) ; grid 1024 x 256, 1 float4/thread.
__global__ __launch_bounds__(256) void reduce2_kernel(
    const float* __restrict__ p0, const float* __restrict__ p1,
    const float* __restrict__ sig, unsigned short* __restrict__ out) {
  const size_t i4 = (size_t)blockIdx.x * 256 + threadIdx.x;
  float4 a = reinterpret_cast<const float4*>(p0)[i4];
  float4 b = reinterpret_cast<const float4*>(p1)[i4];
  float4 s = {1.f, 1.f, 1.f, 1.f};
  if (sig) s = *reinterpret_cast<const float4*>(&sig[(i4 * 4) & 1023]);
  ushort4 o;
  o.x = f32_to_bf16_rne((a.x + b.x) * s.x);
  o.y = f32_to_bf16_rne((a.y + b.y) * s.y);
  o.z = f32_to_bf16_rne((a.z + b.z) * s.z);
  o.w = f32_to_bf16_rne((a.w + b.w) * s.w);
  reinterpret_cast<ushort4*>(out)[i4] = o;
}

// -------------------- gemm256 (unchanged from R16) --------------------
__global__ __launch_bounds__(512) void gemm256_kernel(
    const unsigned short* __restrict__ Xb, const unsigned short* __restrict__ Mt,
    const float* __restrict__ bias, float* __restrict__ Out) {
  __shared__ unsigned short As[3][256 * 32];
  __shared__ unsigned short Bs[3][128 * 32];
  const int tid = threadIdx.x;
  const int lane = tid & 63, wave = tid >> 6;
  const int bm = blockIdx.x & 63, bn = blockIdx.x >> 6;
  const int m0 = bm * 256, n0 = bn * 128;
  const int wm = wave & 3, wn = wave >> 2;
  const int arow0 = wm * 64, brow0 = wn * 64;
  const int fr = lane & 15, kb = (lane >> 4) << 3;

  f32x4 acc[4][4];
#pragma unroll
  for (int a = 0; a < 4; ++a)
#pragma unroll
    for (int b = 0; b < 4; ++b) acc[a][b] = 0.f;

  const unsigned short* agbase = Xb + (size_t)m0 * NN;
  const unsigned short* bgbase = Mt + (size_t)n0 * NN;

#define G256_STAGE(B, KT)                                                        \
  {                                                                              \
    _Pragma("unroll")                                                            \
    for (int i = 0; i < 2; ++i) {                                                \
      const int slot = tid + 512 * i;                                            \
      const int row = slot >> 2, s = slot & 3;                                   \
      const int cs = s ^ ((row >> 1) & 3);                                       \
      __builtin_amdgcn_global_load_lds(                                          \
          AS1(agbase + (size_t)row * NN + (KT) * 32 + cs * 8),                   \
          AS3(&As[B][row * 32 + s * 8]), 16, 0, 0);                              \
    }                                                                            \
    {                                                                            \
      const int row = tid >> 2, s = tid & 3;                                     \
      const int cs = s ^ ((row >> 1) & 3);                                       \
      __builtin_amdgcn_global_load_lds(                                          \
          AS1(bgbase + (size_t)row * NN + (KT) * 32 + cs * 8),                   \
          AS3(&Bs[B][row * 32 + s * 8]), 16, 0, 0);                              \
    }                                                                            \
  }

#define G256_CMP(B)                                                              \
  {                                                                              \
    short8 af[4], bf4[4];                                                        \
    const int ck = kb >> 3;                                                      \
    _Pragma("unroll")                                                            \
    for (int tr = 0; tr < 4; ++tr) {                                             \
      const int row = arow0 + tr * 16 + fr;                                      \
      const int sl = ck ^ ((row >> 1) & 3);                                      \
      af[tr] = *reinterpret_cast<const short8*>(&As[B][row * 32 + sl * 8]);      \
    }                                                                            \
    _Pragma("unroll")                                                            \
    for (int tc = 0; tc < 4; ++tc) {                                             \
      const int row = brow0 + tc * 16 + fr;                                      \
      const int sl = ck ^ ((row >> 1) & 3);                                      \
      bf4[tc] = *reinterpret_cast<const short8*>(&Bs[B][row * 32 + sl * 8]);     \
    }                                                                            \
    _Pragma("unroll")                                                            \
    for (int tr = 0; tr < 4; ++tr)                                               \
      _Pragma("unroll")                                                          \
      for (int tc = 0; tc < 4; ++tc)                                             \
        acc[tr][tc] = __builtin_amdgcn_mfma_f32_16x16x32_bf16(af[tr], bf4[tc], acc[tr][tc], 0, 0, 0); \
  }

  G256_STAGE(0, 0)
  G256_STAGE(1, 1)
#pragma unroll 1
  for (int kt = 0; kt < 31; ++kt) {
    asm volatile("s_waitcnt vmcnt(3)" ::: "memory");
    __builtin_amdgcn_s_barrier();
    __builtin_amdgcn_sched_barrier(0);
    if (kt + 2 < 32) {
      const int nb = (kt + 2) % 3;
      G256_STAGE(nb, kt + 2)
    }
    G256_CMP(kt % 3)
  }
  asm volatile("s_waitcnt vmcnt(0)" ::: "memory");
  __builtin_amdgcn_s_barrier();
  __builtin_amdgcn_sched_barrier(0);
  G256_CMP(1)
#undef G256_STAGE
#undef G256_CMP

  const int rq = (lane >> 4) << 2;
#pragma unroll
  for (int tc = 0; tc < 4; ++tc) {
    const int gc = n0 + brow0 + tc * 16 + fr;
    const float bv = bias[gc];
#pragma unroll
    for (int tr = 0; tr < 4; ++tr) {
      const int gr = m0 + arow0 + tr * 16 + rq;
#pragma unroll
      for (int q = 0; q < 4; ++q) {
        Out[(size_t)(gr + q) * NN + gc] = acc[tr][tc][q] + bv;
      }
    }
  }
}

// -------------------- fallback gemm --------------------
__global__ __launch_bounds__(256) void gemm_fb_kernel(
    const float* __restrict__ X, const unsigned short* __restrict__ Mt,
    const float* __restrict__ bias, float* __restrict__ Out) {
  __shared__ float Af[2][BM * 32];
  __shared__ unsigned short Bsl[2][BN * 32];
  const int tid = threadIdx.x;
  const int lane = tid & 63, wave = tid >> 6;
  const int bm = blockIdx.x & 127;
  const int bn = blockIdx.x >> 7;
  const int m0 = bm * BM, n0 = bn * BN;
  const int wm = wave & 1, wn = wave >> 1;
  const int arow0 = wm * 64, brow0 = wn * 64;
  const int fr = lane & 15, kb = (lane >> 4) << 3;

  f32x4 acc[4][4];
#pragma unroll
  for (int a = 0; a < 4; ++a)
#pragma unroll
    for (int b = 0; b < 4; ++b) acc[a][b] = 0.f;

  const float* agbase = X + (size_t)m0 * NN;
  const unsigned short* bgbase = Mt + (size_t)n0 * NN;

#define FB_STAGE(PB, KT)                                                        \
  {                                                                             \
    _Pragma("unroll")                                                           \
    for (int i = 0; i < 4; ++i) {                                               \
      const int slot = tid + 256 * i;                                           \
      const int row = slot >> 3, s = slot & 7;                                  \
      __builtin_amdgcn_global_load_lds(                                         \
          AS1(agbase + (size_t)row * NN + (KT) * 32 + s * 4),                   \
          AS3(&Af[PB][row * 32 + s * 4]), 16, 0, 0);                            \
    }                                                                           \
    _Pragma("unroll")                                                           \
    for (int i = 0; i < 2; ++i) {                                               \
      const int slot = tid + 256 * i;                                           \
      const int row = slot >> 2, s = slot & 3;                                  \
      __builtin_amdgcn_global_load_lds(                                         \
          AS1(bgbase + (size_t)row * NN + (KT) * 32 + s * 8),                   \
          AS3(&Bsl[PB][row * 32 + s * 8]), 16, 0, 0);                           \
    }                                                                           \
  }

  FB_STAGE(0, 0)
  int pb = 0;
#pragma unroll 1
  for (int kt = 0; kt < 32; ++kt) {
    __syncthreads();
    if (kt + 1 < 32) FB_STAGE(pb ^ 1, kt + 1)
    {
      short8 af[4], bf[4];
      const int c0 = kb >> 2;
#pragma unroll
      for (int tr = 0; tr < 4; ++tr) {
        const int row = arow0 + tr * 16 + fr;
        const f32x4 a0 = *reinterpret_cast<const f32x4*>(&Af[pb][row * 32 + c0 * 4]);
        const f32x4 a1 = *reinterpret_cast<const f32x4*>(&Af[pb][row * 32 + (c0 + 1) * 4]);
        uint4 w;
        w.x = pack2bf(a0[0], a0[1]); w.y = pack2bf(a0[2], a0[3]);
        w.z = pack2bf(a1[0], a1[1]); w.w = pack2bf(a1[2], a1[3]);
        af[tr] = *reinterpret_cast<const short8*>(&w);
      }
#pragma unroll
      for (int tc = 0; tc < 4; ++tc) {
        const int row = brow0 + tc * 16 + fr;
        bf[tc] = *reinterpret_cast<const short8*>(&Bsl[pb][row * 32 + kb]);
      }
#pragma unroll
      for (int tr = 0; tr < 4; ++tr)
#pragma unroll
        for (int tc = 0; tc < 4; ++tc)
          acc[tr][tc] = __builtin_amdgcn_mfma_f32_16x16x32_bf16(af[tr], bf[tc], acc[tr][tc], 0, 0, 0);
    }
    pb ^= 1;
  }
#undef FB_STAGE

  const int rq = (lane >> 4) << 2;
#pragma unroll
  for (int tc = 0; tc < 4; ++tc) {
    const int gc = n0 + brow0 + tc * 16 + fr;
    const float bv = bias[gc];
#pragma unroll
    for (int tr = 0; tr < 4; ++tr) {
      const int gr = m0 + arow0 + tr * 16 + rq;
#pragma unroll
      for (int q = 0; q < 4; ++q) {
        Out[(size_t)(gr + q) * NN + gc] = acc[tr][tc][q] + bv;
      }
    }
  }
}

extern "C" void kernel_launch(void* const* d_in, const int* in_sizes, int n_in,
                              void* d_out, int out_size, void* d_ws, size_t ws_size,
                              hipStream_t stream) {
  const float* x = (const float*)d_in[0];
  const float* U = (const float*)d_in[1];
  const float* V = (const float*)d_in[2];
  const float* p = (const float*)d_in[3];
  const float* bias = (const float*)d_in[4];
  float* out = (float*)d_out;

  char* ws = (char*)d_ws;
  float* tau_u = (float*)(ws);
  float* tau_v = (float*)(ws + 4096);
  float* sigmas = (float*)(ws + 8192);
  float* T8all = (float*)(ws + 16384);                 // 64 KB
  unsigned short* Mt = (unsigned short*)(ws + 81920);  // 2 MB

  const size_t XB_OFF = 4u * 1024 * 1024;
  const size_t XB_BYTES = (size_t)NBATCH * NN * 2;     // 32 MB
  const bool fast = ws_size >= XB_OFF + XB_BYTES;
  unsigned short* Xb = (unsigned short*)(ws + XB_OFF);

  unsigned short* sc = (unsigned short*)d_out;
  unsigned short* chains = sc;
  unsigned short* P = sc + 16 * ME;
  unsigned short* Q = sc + 24 * ME;
  unsigned short* F = sc + 28 * ME;
  unsigned short* YThi = sc + 16 * ME;
  unsigned short* YTlo = sc + 18 * ME;
  unsigned short* WThi = sc + 20 * ME;
  unsigned short* WTlo = sc + 22 * ME;
  unsigned short* Yhi = sc + 24 * ME;
  unsigned short* Ylo = sc + 26 * ME;
  float* Gp = (float*)(sc + 28 * ME);
  float* G = (float*)sc;                               // chains region, dead until chainc
  float* Tg = (float*)(sc + ME);
  unsigned short* Thi = sc + 24 * ME;                  // dead Yhi region
  unsigned short* Tlo = Thi + 262144;
  // K-split partials (chains region, dead after L1): L3 4 bufs, L4 2 bufs.
  float* P32L3 = (float*)sc;                           // 4 x ME f32 = 16 MB
  float* P32L4 = (float*)(sc + 8 * ME);                // 2 x ME f32 = 8 MB

  prep_kernel<<<516, 256, 0, stream>>>(U, V, p, tau_u, tau_v, sigmas);
  if (fast) castx_kernel<<<2048, 256, 0, stream>>>(x, Xb);
  gram_t8_kernel<<<256, 64, 0, stream>>>(U, V, tau_u, tau_v, T8all);
  splity_kernel<<<128, 256, 0, stream>>>(U, V, Yhi, Ylo, YThi, YTlo);
  gramt_kernel<<<128, 256, 0, stream>>>(Yhi, Ylo, Gp);
  gsum_tinit_kernel<<<1088, 256, 0, stream>>>(Gp, T8all, G, Tg);
  tmerge_kernel<8><<<128, 256, 0, stream>>>(G, Tg);
  tmerge_kernel<16><<<64, 256, 0, stream>>>(G, Tg);
  tmerge_kernel<32><<<32, 256, 0, stream>>>(G, Tg);
  tmerge_kernel<64><<<16, 256, 0, stream>>>(G, Tg);
  tsplit_kernel<<<64, 256, 0, stream>>>(Tg, Thi, Tlo);
  zw_kernel<<<128, 256, 0, stream>>>(Thi, Tlo, YThi, YTlo, WThi, WTlo);
  chainc_kernel<<<1024, 256, 0, stream>>>(YThi, YTlo, WThi, WTlo, chains);
  composeL1_kernel<<<512, 256, 0, stream>>>(chains, P);
  composeL2_kernel<<<256, 256, 0, stream>>>(P, Q);
  composeL3ks_kernel<<<256, 256, 0, stream>>>(Q, P32L3);
  reduce2_kernel<<<1024, 256, 0, stream>>>(P32L3, P32L3 + ME, sigmas, F);
  reduce2_kernel<<<1024, 256, 0, stream>>>(P32L3 + 2 * ME, P32L3 + 3 * ME, nullptr, F + ME);
  composeL4ks_kernel<<<128, 256, 0, stream>>>(F, P32L4);
  reduce2_kernel<<<1024, 256, 0, stream>>>(P32L4, P32L4 + ME, nullptr, Mt);
  if (fast) gemm256_kernel<<<512, 512, 0, stream>>>(Xb, Mt, bias, out);
  else gemm_fb_kernel<<<1024, 256, 0, stream>>>(x, Mt, bias, out);
}

// Round 18
// 289.230 us; speedup vs baseline: 1.2001x; 1.0462x over previous
//
#include <hip/hip_runtime.h>
#include <stdint.h>

typedef __attribute__((ext_vector_type(8))) short short8;
typedef __attribute__((ext_vector_type(4))) float f32x4;

#define NN 1024
#define NBATCH 16384
#define ME ((size_t)NN * NN)
#define AS1 (const __attribute__((address_space(1))) void*)
#define AS3 (__attribute__((address_space(3))) void*)

__device__ __forceinline__ unsigned short f32_to_bf16_rne(float f) {
  unsigned int u = __float_as_uint(f);
  unsigned int r = (u + 0x7fffu + ((u >> 16) & 1u)) >> 16;
  return (unsigned short)r;
}

__device__ __forceinline__ unsigned int pack2bf(float lo, float hi) {
  return (unsigned int)f32_to_bf16_rne(lo) | ((unsigned int)f32_to_bf16_rne(hi) << 16);
}

__device__ __forceinline__ void split_bf16(float x, unsigned short& h, unsigned short& l) {
  h = f32_to_bf16_rne(x);
  float hf = __uint_as_float((unsigned int)h << 16);
  l = f32_to_bf16_rne(x - hf);
}

__device__ __forceinline__ float allsum64(float x) {
  x += __int_as_float(__builtin_amdgcn_update_dpp(0, __float_as_int(x), 0xB1, 0xF, 0xF, true));
  x += __int_as_float(__builtin_amdgcn_update_dpp(0, __float_as_int(x), 0x4E, 0xF, 0xF, true));
  x += __int_as_float(__builtin_amdgcn_update_dpp(0, __float_as_int(x), 0x141, 0xF, 0xF, true));
  x += __int_as_float(__builtin_amdgcn_update_dpp(0, __float_as_int(x), 0x140, 0xF, 0xF, true));
#if __has_builtin(__builtin_amdgcn_permlane16_swap) && __has_builtin(__builtin_amdgcn_permlane32_swap)
  {
    auto r16 = __builtin_amdgcn_permlane16_swap(__float_as_uint(x), __float_as_uint(x), false, false);
    x = __uint_as_float(r16[0]) + __uint_as_float(r16[1]);
    auto r32 = __builtin_amdgcn_permlane32_swap(__float_as_uint(x), __float_as_uint(x), false, false);
    x = __uint_as_float(r32[0]) + __uint_as_float(r32[1]);
  }
#else
  x += __int_as_float(__builtin_amdgcn_ds_swizzle(__float_as_int(x), 0x401F));
  x += __shfl_xor(x, 32);
#endif
  return x;
}

// -------------------- fused_pre: prep (0..515) | splity (516..643) | castx (644..1667) ----
// All three sections are mutually independent (read-only inputs, disjoint outputs);
// fusing lets castx's HBM streaming overlap prep/splity compute.
__global__ __launch_bounds__(256) void fused_pre_kernel(
    const float* __restrict__ X, const float* __restrict__ U, const float* __restrict__ V,
    const float* __restrict__ p, float* __restrict__ tau_u, float* __restrict__ tau_v,
    float* __restrict__ sigmas, unsigned short* __restrict__ Xb,
    unsigned short* __restrict__ Yhi, unsigned short* __restrict__ Ylo,
    unsigned short* __restrict__ YThi, unsigned short* __restrict__ YTlo) {
  const int bid = blockIdx.x;
  const int tid = threadIdx.x;
  if (bid < 516) {
    // ---- prep ----
    int wave = tid >> 6, lane = tid & 63;
    int row = bid * 4 + wave;
    if (row < 2048) {
      const float* u = (row < NN) ? (U + (size_t)row * NN) : (V + (size_t)(row - NN) * NN);
      float s = 0.f;
#pragma unroll
      for (int t = 0; t < 16; ++t) { float a = u[lane + (t << 6)]; s += a * a; }
      s = allsum64(s);
      if (lane == 0) {
        float tau = 2.0f / s;
        if (row < NN) tau_u[row] = tau;
        else tau_v[row - NN] = tau;
      }
    } else if (row < 2064) {
      int j = ((row - 2048) << 6) + lane;
      float pj = p[j];
      float sg = 1.0f / (1.0f + expf(-pj));
      sigmas[j] = 0.9f * (sg - 0.5f) + 0.55f;
    }
  } else if (bid < 644) {
    // ---- splity ----
    __shared__ float ys[128][129];
    const int sbid = bid - 516;
    const int c = sbid >> 3, et = sbid & 7;
    const int half = tid & 1;
    const int slot = tid >> 1;
    const int e0 = et << 7;
    const int grow = (c < 8) ? ((c << 7) + slot) : (1023 - ((c - 8) << 7) - slot);
    const float* src = ((c < 8) ? U : V) + (size_t)grow * NN + e0 + (half << 6);
#pragma unroll
    for (int i = 0; i < 16; ++i) {
      float4 v4 = *reinterpret_cast<const float4*>(src + (i << 2));
      const int kk = (half << 6) + (i << 2);
      ys[slot][kk + 0] = v4.x; ys[slot][kk + 1] = v4.y;
      ys[slot][kk + 2] = v4.z; ys[slot][kk + 3] = v4.w;
    }
    __syncthreads();
    {
      const size_t rbase = ((size_t)(c * 128 + slot)) * NN + e0 + (half << 6);
#pragma unroll
      for (int i = 0; i < 16; ++i) {
        const int kk = (half << 6) + (i << 2);
        ushort4 h4, l4;
        split_bf16(ys[slot][kk + 0], h4.x, l4.x);
        split_bf16(ys[slot][kk + 1], h4.y, l4.y);
        split_bf16(ys[slot][kk + 2], h4.z, l4.z);
        split_bf16(ys[slot][kk + 3], h4.w, l4.w);
        *reinterpret_cast<ushort4*>(&Yhi[rbase + (i << 2)]) = h4;
        *reinterpret_cast<ushort4*>(&Ylo[rbase + (i << 2)]) = l4;
      }
    }
    {
      const int e = slot;
      const size_t tbase = ((size_t)c * 1024 + e0 + e) * 128 + (half << 6);
#pragma unroll
      for (int i = 0; i < 16; ++i) {
        const int k0 = (half << 6) + (i << 2);
        ushort4 h4, l4;
        split_bf16(ys[k0 + 0][e], h4.x, l4.x);
        split_bf16(ys[k0 + 1][e], h4.y, l4.y);
        split_bf16(ys[k0 + 2][e], h4.z, l4.z);
        split_bf16(ys[k0 + 3][e], h4.w, l4.w);
        *reinterpret_cast<ushort4*>(&YThi[tbase + (i << 2)]) = h4;
        *reinterpret_cast<ushort4*>(&YTlo[tbase + (i << 2)]) = l4;
      }
    }
  } else {
    // ---- castx (1024 blocks, grid-stride) ----
    const size_t cbid = bid - 644;
    const size_t n4 = (size_t)NBATCH * NN / 4;
    for (size_t i = cbid * 256 + tid; i < n4; i += (size_t)1024 * 256) {
      float4 v = reinterpret_cast<const float4*>(X)[i];
      uint2 o;
      o.x = pack2bf(v.x, v.y);
      o.y = pack2bf(v.z, v.w);
      reinterpret_cast<uint2*>(Xb)[i] = o;
    }
  }
}

#define LDK 40
#define BM 128
#define BN 128
#define BK 32

// -------------------- fused_gram: gram_t8 (0..255) | gramt (256..383) ----
__global__ __launch_bounds__(256) void fused_gram_kernel(
    const float* __restrict__ U, const float* __restrict__ V,
    const float* __restrict__ tau_u, const float* __restrict__ tau_v,
    float* __restrict__ T8all,
    const unsigned short* __restrict__ Yhi, const unsigned short* __restrict__ Ylo,
    float* __restrict__ Gp) {
  const int bid = blockIdx.x;
  const int tid = threadIdx.x;
  if (bid < 256) {
    // ---- gram_t8 (256 threads; lanes >= 28/8 idle but cross barriers) ----
    __shared__ float G[64];
    const int blk = bid;
    const int lane = tid;
    const float* bank;
    int rbase, rsign, st;
    if (blk < 128) { bank = U; rbase = 8 * blk; rsign = 1; st = 8 * blk; }
    else { int s = blk - 128; bank = V; rbase = 1023 - 8 * s; rsign = -1; st = 1016 - 8 * s; }

    if (lane < 28) {
      int j = 1, k = 0, t = lane;
      for (int jj = 1; jj < 8; ++jj) {
        int lo = jj * (jj - 1) / 2, hi = jj * (jj + 1) / 2;
        if (t >= lo && t < hi) { j = jj; k = t - lo; }
      }
      const float* rk = bank + (size_t)(rbase + rsign * k) * NN;
      const float* rj = bank + (size_t)(rbase + rsign * j) * NN;
      float acc = 0.f;
      for (int i = st >> 2; i < 256; ++i) {
        float4 a = *reinterpret_cast<const float4*>(rk + 4 * i);
        float4 b = *reinterpret_cast<const float4*>(rj + 4 * i);
        acc += a.x * b.x + a.y * b.y + a.z * b.z + a.w * b.w;
      }
      G[k * 8 + j] = acc;
    }
    __syncthreads();

    if (lane < 8) {
      float Tr[8];
#pragma unroll
      for (int j = 0; j < 8; ++j) Tr[j] = 0.f;
#pragma unroll
      for (int j = 0; j < 8; ++j) {
        int grow = rbase + rsign * j;
        float tj = (blk < 128) ? tau_u[grow] : tau_v[grow];
        float a = 0.f;
#pragma unroll
        for (int k = 0; k < 8; ++k) {
          if (k < j) a += Tr[k] * G[k * 8 + j];
        }
        Tr[j] = (lane == j) ? tj : (-tj * a);
      }
#pragma unroll
      for (int j = 0; j < 8; ++j) T8all[(size_t)blk * 64 + lane * 8 + j] = Tr[j];
    }
    return;
  }
  // ---- gramt (K-split 8x) with triangular skip ----
  const int g = bid - 256;
  const int c = g >> 3, ks = g & 7;
  const bool productive = (c < 8) ? (ks >= c) : (ks >= 7 - (c - 8));
  if (!productive) {
    float4 z = {0.f, 0.f, 0.f, 0.f};
    float4* dst = reinterpret_cast<float4*>(Gp + (((size_t)c * 8 + ks) << 14));
    for (int i = tid; i < 4096; i += 256) dst[i] = z;
    return;
  }
  __shared__ unsigned short Hs[128 * LDK];
  __shared__ unsigned short Ls[128 * LDK];
  const int lane = tid & 63, wave = tid >> 6;
  const int wm = wave & 1, wn = wave >> 1;
  const int srow = tid >> 1, scol = (tid & 1) << 4;
  const unsigned short* ph = Yhi + ((size_t)(c * 128 + srow)) * NN + ks * 128 + scol;
  const unsigned short* pl = Ylo + ((size_t)(c * 128 + srow)) * NN + ks * 128 + scol;

  f32x4 acc[4][4];
#pragma unroll
  for (int a = 0; a < 4; ++a)
#pragma unroll
    for (int b = 0; b < 4; ++b) acc[a][b] = 0.f;

  const int arow0 = wm * 64, brow0 = wn * 64;
  const int fr = lane & 15, kb = (lane >> 4) << 3;

#pragma unroll 1
  for (int kt = 0; kt < 4; ++kt) {
    __syncthreads();
    *reinterpret_cast<uint4*>(&Hs[srow * LDK + scol]) = *reinterpret_cast<const uint4*>(ph + kt * 32);
    *reinterpret_cast<uint4*>(&Hs[srow * LDK + scol + 8]) = *reinterpret_cast<const uint4*>(ph + kt * 32 + 8);
    *reinterpret_cast<uint4*>(&Ls[srow * LDK + scol]) = *reinterpret_cast<const uint4*>(pl + kt * 32);
    *reinterpret_cast<uint4*>(&Ls[srow * LDK + scol + 8]) = *reinterpret_cast<const uint4*>(pl + kt * 32 + 8);
    __syncthreads();
    short8 ah[4], al[4], bh[4], bl[4];
#pragma unroll
    for (int tr = 0; tr < 4; ++tr) {
      ah[tr] = *reinterpret_cast<const short8*>(&Hs[(arow0 + tr * 16 + fr) * LDK + kb]);
      al[tr] = *reinterpret_cast<const short8*>(&Ls[(arow0 + tr * 16 + fr) * LDK + kb]);
    }
#pragma unroll
    for (int tc = 0; tc < 4; ++tc) {
      bh[tc] = *reinterpret_cast<const short8*>(&Hs[(brow0 + tc * 16 + fr) * LDK + kb]);
      bl[tc] = *reinterpret_cast<const short8*>(&Ls[(brow0 + tc * 16 + fr) * LDK + kb]);
    }
#pragma unroll
    for (int tr = 0; tr < 4; ++tr)
#pragma unroll
      for (int tc = 0; tc < 4; ++tc) {
        acc[tr][tc] = __builtin_amdgcn_mfma_f32_16x16x32_bf16(ah[tr], bh[tc], acc[tr][tc], 0, 0, 0);
        acc[tr][tc] = __builtin_amdgcn_mfma_f32_16x16x32_bf16(ah[tr], bl[tc], acc[tr][tc], 0, 0, 0);
        acc[tr][tc] = __builtin_amdgcn_mfma_f32_16x16x32_bf16(al[tr], bh[tc], acc[tr][tc], 0, 0, 0);
      }
  }
  const int rq = (lane >> 4) << 2;
#pragma unroll
  for (int tc = 0; tc < 4; ++tc) {
    const int gc = brow0 + tc * 16 + fr;
#pragma unroll
    for (int tr = 0; tr < 4; ++tr) {
      const int gr = arow0 + tr * 16 + rq;
#pragma unroll
      for (int q = 0; q < 4; ++q)
        Gp[(((size_t)c * 8 + ks) * 128 + gr + q) * 128 + gc] = acc[tr][tc][q];
    }
  }
}

// -------------------- gsum + Tg init --------------------
__global__ __launch_bounds__(256) void gsum_tinit_kernel(
    const float* __restrict__ Gp, const float* __restrict__ T8all,
    float* __restrict__ G, float* __restrict__ Tg) {
  const int bid = blockIdx.x;
  if (bid < 1024) {
    const size_t i = (size_t)bid * 256 + threadIdx.x;
    const size_t c = i >> 14, rc = i & 16383;
    float s = 0.f;
#pragma unroll
    for (int sl = 0; sl < 8; ++sl)
      s += Gp[(c * 8 + sl) * 16384 + rc];
    G[i] = s;
  } else {
    const size_t base = ((size_t)(bid - 1024) * 256 + threadIdx.x) * 16;
#pragma unroll 1
    for (int e = 0; e < 16; ++e) {
      const size_t i = base + e;
      const int c = (int)(i >> 14), rc = (int)(i & 16383);
      const int r = rc >> 7, cl = rc & 127;
      float v = 0.f;
      if ((r >> 3) == (cl >> 3)) {
        const int sb = r >> 3;
        const int t8i = (c < 8) ? (16 * c + sb) : (128 + 16 * (c - 8) + sb);
        v = T8all[(size_t)t8i * 64 + (r & 7) * 8 + (cl & 7)];
      }
      Tg[i] = v;
    }
  }
}

// -------------------- tmerge<B> --------------------
template <int B>
__global__ __launch_bounds__(256) void tmerge_kernel(
    const float* __restrict__ G, float* __restrict__ Tg) {
  __shared__ float T1s[B * B], T2s[B * B], Gs[B * B], Xs[B * B];
  const int nm = 128 / (2 * B);
  const int c = blockIdx.x / nm, m = blockIdx.x % nm;
  const int a0 = 2 * B * m;
  const int tid = threadIdx.x;
  float* Tc = Tg + (size_t)c * 16384;
  for (int i = tid; i < B * B; i += 256) {
    const int r = i / B, cl = i % B;
    T1s[i] = Tc[(a0 + r) * 128 + a0 + cl];
    T2s[i] = Tc[(a0 + B + r) * 128 + a0 + B + cl];
    Gs[i] = G[((size_t)c * 128 + a0 + r) * 128 + a0 + B + cl];
  }
  __syncthreads();
  for (int i = tid; i < B * B; i += 256) {
    const int r = i / B, cl = i % B;
    float s = 0.f;
    for (int k = 0; k <= cl; ++k) s += Gs[r * B + k] * T2s[k * B + cl];
    Xs[i] = s;
  }
  __syncthreads();
  for (int i = tid; i < B * B; i += 256) {
    const int r = i / B, cl = i % B;
    float s = 0.f;
    for (int k = r; k < B; ++k) s -= T1s[r * B + k] * Xs[k * B + cl];
    Tc[(a0 + r) * 128 + a0 + B + cl] = s;
  }
}

// -------------------- zw (stages T directly from Tg f32, split on the fly) ----
__global__ __launch_bounds__(256) void zw_kernel(
    const float* __restrict__ Tg,
    const unsigned short* __restrict__ YThi, const unsigned short* __restrict__ YTlo,
    unsigned short* __restrict__ WThi, unsigned short* __restrict__ WTlo) {
  __shared__ unsigned short Xh[128 * LDK], Xl[128 * LDK];
  __shared__ unsigned short Wh[128 * LDK], Wl[128 * LDK];
  const int tid = threadIdx.x;
  const int lane = tid & 63, wave = tid >> 6;
  const int c = blockIdx.x >> 3, bn = blockIdx.x & 7;
  const int n0 = bn * 128;
  const int wm = wave & 1, wn = wave >> 1;
  const int srow = tid >> 1, scol = (tid & 1) << 4;
  const float* pt = Tg + (size_t)c * 16384 + (size_t)srow * 128 + scol;
  const unsigned short* pwh = YThi + ((size_t)c * 1024 + n0 + srow) * 128 + scol;
  const unsigned short* pwl = YTlo + ((size_t)c * 1024 + n0 + srow) * 128 + scol;

  f32x4 acc[4][4];
#pragma unroll
  for (int a = 0; a < 4; ++a)
#pragma unroll
    for (int b = 0; b < 4; ++b) acc[a][b] = 0.f;

  const int arow0 = wm * 64, brow0 = wn * 64;
  const int fr = lane & 15, kb = (lane >> 4) << 3;

#pragma unroll 1
  for (int kt = 0; kt < 4; ++kt) {
    __syncthreads();
#pragma unroll
    for (int h = 0; h < 2; ++h) {
      float4 t0 = *reinterpret_cast<const float4*>(pt + kt * 32 + 8 * h);
      float4 t1 = *reinterpret_cast<const float4*>(pt + kt * 32 + 8 * h + 4);
      ushort4 ha, la, hb, lb2;
      split_bf16(t0.x, ha.x, la.x); split_bf16(t0.y, ha.y, la.y);
      split_bf16(t0.z, ha.z, la.z); split_bf16(t0.w, ha.w, la.w);
      split_bf16(t1.x, hb.x, lb2.x); split_bf16(t1.y, hb.y, lb2.y);
      split_bf16(t1.z, hb.z, lb2.z); split_bf16(t1.w, hb.w, lb2.w);
      *reinterpret_cast<ushort4*>(&Xh[srow * LDK + scol + 8 * h]) = ha;
      *reinterpret_cast<ushort4*>(&Xh[srow * LDK + scol + 8 * h + 4]) = hb;
      *reinterpret_cast<ushort4*>(&Xl[srow * LDK + scol + 8 * h]) = la;
      *reinterpret_cast<ushort4*>(&Xl[srow * LDK + scol + 8 * h + 4]) = lb2;
    }
    *reinterpret_cast<uint4*>(&Wh[srow * LDK + scol]) = *reinterpret_cast<const uint4*>(pwh + kt * 32);
    *reinterpret_cast<uint4*>(&Wh[srow * LDK + scol + 8]) = *reinterpret_cast<const uint4*>(pwh + kt * 32 + 8);
    *reinterpret_cast<uint4*>(&Wl[srow * LDK + scol]) = *reinterpret_cast<const uint4*>(pwl + kt * 32);
    *reinterpret_cast<uint4*>(&Wl[srow * LDK + scol + 8]) = *reinterpret_cast<const uint4*>(pwl + kt * 32 + 8);
    __syncthreads();
    short8 ah[4], al[4], bh[4], bl[4];
#pragma unroll
    for (int tr = 0; tr < 4; ++tr) {
      ah[tr] = *reinterpret_cast<const short8*>(&Xh[(arow0 + tr * 16 + fr) * LDK + kb]);
      al[tr] = *reinterpret_cast<const short8*>(&Xl[(arow0 + tr * 16 + fr) * LDK + kb]);
    }
#pragma unroll
    for (int tc = 0; tc < 4; ++tc) {
      bh[tc] = *reinterpret_cast<const short8*>(&Wh[(brow0 + tc * 16 + fr) * LDK + kb]);
      bl[tc] = *reinterpret_cast<const short8*>(&Wl[(brow0 + tc * 16 + fr) * LDK + kb]);
    }
#pragma unroll
    for (int tr = 0; tr < 4; ++tr)
#pragma unroll
      for (int tc = 0; tc < 4; ++tc) {
        acc[tr][tc] = __builtin_amdgcn_mfma_f32_16x16x32_bf16(ah[tr], bh[tc], acc[tr][tc], 0, 0, 0);
        acc[tr][tc] = __builtin_amdgcn_mfma_f32_16x16x32_bf16(ah[tr], bl[tc], acc[tr][tc], 0, 0, 0);
        acc[tr][tc] = __builtin_amdgcn_mfma_f32_16x16x32_bf16(al[tr], bh[tc], acc[tr][tc], 0, 0, 0);
      }
  }
  const int rq = (lane >> 4) << 2;
#pragma unroll
  for (int tc = 0; tc < 4; ++tc) {
    const int gc = brow0 + tc * 16 + fr;
#pragma unroll
    for (int tr = 0; tr < 4; ++tr) {
      const int gr = arow0 + tr * 16 + rq;
      ushort4 h4, l4;
      split_bf16(acc[tr][tc][0], h4.x, l4.x);
      split_bf16(acc[tr][tc][1], h4.y, l4.y);
      split_bf16(acc[tr][tc][2], h4.z, l4.z);
      split_bf16(acc[tr][tc][3], h4.w, l4.w);
      const size_t off = ((size_t)c * 1024 + n0 + gc) * 128 + gr;
      *reinterpret_cast<ushort4*>(&WThi[off]) = h4;
      *reinterpret_cast<ushort4*>(&WTlo[off]) = l4;
    }
  }
}

// -------------------- chainC with triangular skip ----
__global__ __launch_bounds__(256) void chainc_kernel(
    const unsigned short* __restrict__ YThi, const unsigned short* __restrict__ YTlo,
    const unsigned short* __restrict__ WThi, const unsigned short* __restrict__ WTlo,
    unsigned short* __restrict__ chains) {
  const int tid = threadIdx.x;
  const int lane = tid & 63, wave = tid >> 6;
  const int c = blockIdx.x >> 6, b6 = blockIdx.x & 63;
  const int bm = b6 & 7, bn = b6 >> 3;
  const int m0 = bm * 128, n0 = bn * 128;
  const int wm = wave & 1, wn = wave >> 1;
  const int arow0 = wm * 64, brow0 = wn * 64;
  const int fr = lane & 15, kb = (lane >> 4) << 3;
  const int rq = (lane >> 4) << 2;
  unsigned short* dst = chains + (size_t)c * ME;

  const int z0 = (c < 8) ? (128 * c) : (896 - 128 * (c - 8));
  if (m0 < z0 || n0 < z0) {
    if ((c & 1) == 0) {
#pragma unroll
      for (int tc = 0; tc < 4; ++tc) {
        const int gcg = n0 + brow0 + tc * 16 + fr;
#pragma unroll
        for (int tr = 0; tr < 4; ++tr) {
          const int grg = m0 + arow0 + tr * 16 + rq;
#pragma unroll
          for (int q = 0; q < 4; ++q)
            dst[(size_t)(grg + q) * NN + gcg] = f32_to_bf16_rne((grg + q) == gcg ? 1.0f : 0.0f);
        }
      }
    } else {
#pragma unroll
      for (int tc = 0; tc < 4; ++tc) {
        const int gcg = n0 + brow0 + tc * 16 + fr;
#pragma unroll
        for (int tr = 0; tr < 4; ++tr) {
          const int grg = m0 + arow0 + tr * 16 + rq;
          ushort4 pk;
          pk.x = f32_to_bf16_rne((grg + 0) == gcg ? 1.0f : 0.0f);
          pk.y = f32_to_bf16_rne((grg + 1) == gcg ? 1.0f : 0.0f);
          pk.z = f32_to_bf16_rne((grg + 2) == gcg ? 1.0f : 0.0f);
          pk.w = f32_to_bf16_rne((grg + 3) == gcg ? 1.0f : 0.0f);
          *reinterpret_cast<ushort4*>(&dst[(size_t)gcg * NN + grg]) = pk;
        }
      }
    }
    return;
  }

  __shared__ unsigned short Xh[128 * LDK], Xl[128 * LDK];
  __shared__ unsigned short Wh[128 * LDK], Wl[128 * LDK];
  const int srow = tid >> 1, scol = (tid & 1) << 4;
  const unsigned short* pxh = YThi + ((size_t)c * 1024 + m0 + srow) * 128 + scol;
  const unsigned short* pxl = YTlo + ((size_t)c * 1024 + m0 + srow) * 128 + scol;
  const unsigned short* pwh = WThi + ((size_t)c * 1024 + n0 + srow) * 128 + scol;
  const unsigned short* pwl = WTlo + ((size_t)c * 1024 + n0 + srow) * 128 + scol;

  f32x4 acc[4][4];
#pragma unroll
  for (int a = 0; a < 4; ++a)
#pragma unroll
    for (int b = 0; b < 4; ++b) acc[a][b] = 0.f;

#pragma unroll 1
  for (int kt = 0; kt < 4; ++kt) {
    __syncthreads();
    *reinterpret_cast<uint4*>(&Xh[srow * LDK + scol]) = *reinterpret_cast<const uint4*>(pxh + kt * 32);
    *reinterpret_cast<uint4*>(&Xh[srow * LDK + scol + 8]) = *reinterpret_cast<const uint4*>(pxh + kt * 32 + 8);
    *reinterpret_cast<uint4*>(&Xl[srow * LDK + scol]) = *reinterpret_cast<const uint4*>(pxl + kt * 32);
    *reinterpret_cast<uint4*>(&Xl[srow * LDK + scol + 8]) = *reinterpret_cast<const uint4*>(pxl + kt * 32 + 8);
    *reinterpret_cast<uint4*>(&Wh[srow * LDK + scol]) = *reinterpret_cast<const uint4*>(pwh + kt * 32);
    *reinterpret_cast<uint4*>(&Wh[srow * LDK + scol + 8]) = *reinterpret_cast<const uint4*>(pwh + kt * 32 + 8);
    *reinterpret_cast<uint4*>(&Wl[srow * LDK + scol]) = *reinterpret_cast<const uint4*>(pwl + kt * 32);
    *reinterpret_cast<uint4*>(&Wl[srow * LDK + scol + 8]) = *reinterpret_cast<const uint4*>(pwl + kt * 32 + 8);
    __syncthreads();
    short8 ah[4], al[4], bh[4], bl[4];
#pragma unroll
    for (int tr = 0; tr < 4; ++tr) {
      ah[tr] = *reinterpret_cast<const short8*>(&Xh[(arow0 + tr * 16 + fr) * LDK + kb]);
      al[tr] = *reinterpret_cast<const short8*>(&Xl[(arow0 + tr * 16 + fr) * LDK + kb]);
    }
#pragma unroll
    for (int tc = 0; tc < 4; ++tc) {
      bh[tc] = *reinterpret_cast<const short8*>(&Wh[(brow0 + tc * 16 + fr) * LDK + kb]);
      bl[tc] = *reinterpret_cast<const short8*>(&Wl[(brow0 + tc * 16 + fr) * LDK + kb]);
    }
#pragma unroll
    for (int tr = 0; tr < 4; ++tr)
#pragma unroll
      for (int tc = 0; tc < 4; ++tc) {
        acc[tr][tc] = __builtin_amdgcn_mfma_f32_16x16x32_bf16(ah[tr], bh[tc], acc[tr][tc], 0, 0, 0);
        acc[tr][tc] = __builtin_amdgcn_mfma_f32_16x16x32_bf16(ah[tr], bl[tc], acc[tr][tc], 0, 0, 0);
        acc[tr][tc] = __builtin_amdgcn_mfma_f32_16x16x32_bf16(al[tr], bh[tc], acc[tr][tc], 0, 0, 0);
      }
  }
  if ((c & 1) == 0) {
#pragma unroll
    for (int tc = 0; tc < 4; ++tc) {
      const int gcg = n0 + brow0 + tc * 16 + fr;
#pragma unroll
      for (int tr = 0; tr < 4; ++tr) {
        const int grg = m0 + arow0 + tr * 16 + rq;
#pragma unroll
        for (int q = 0; q < 4; ++q) {
          const float val = ((grg + q) == gcg ? 1.0f : 0.0f) - acc[tr][tc][q];
          dst[(size_t)(grg + q) * NN + gcg] = f32_to_bf16_rne(val);
        }
      }
    }
  } else {
#pragma unroll
    for (int tc = 0; tc < 4; ++tc) {
      const int gcg = n0 + brow0 + tc * 16 + fr;
#pragma unroll
      for (int tr = 0; tr < 4; ++tr) {
        const int grg = m0 + arow0 + tr * 16 + rq;
        ushort4 pk;
        pk.x = f32_to_bf16_rne(((grg + 0) == gcg ? 1.0f : 0.0f) - acc[tr][tc][0]);
        pk.y = f32_to_bf16_rne(((grg + 1) == gcg ? 1.0f : 0.0f) - acc[tr][tc][1]);
        pk.z = f32_to_bf16_rne(((grg + 2) == gcg ? 1.0f : 0.0f) - acc[tr][tc][2]);
        pk.w = f32_to_bf16_rne(((grg + 3) == gcg ? 1.0f : 0.0f) - acc[tr][tc][3]);
        *reinterpret_cast<ushort4*>(&dst[(size_t)gcg * NN + grg]) = pk;
      }
    }
  }
}

// -------------------- compose core: 3-buf counted vmcnt, variable k-range ----
__device__ __forceinline__ void cb_stage(
    const unsigned short* __restrict__ agbase, const unsigned short* __restrict__ bgbase,
    unsigned short* __restrict__ la, unsigned short* __restrict__ lb, int tid, int kt) {
#pragma unroll
  for (int i = 0; i < 2; ++i) {
    const int slot = tid + 256 * i;
    const int row = slot >> 2, s = slot & 3;
    const int cs = s ^ ((row >> 1) & 3);
    __builtin_amdgcn_global_load_lds(
        AS1(agbase + (size_t)row * NN + kt * 32 + cs * 8), AS3(la + row * 32 + s * 8), 16, 0, 0);
  }
#pragma unroll
  for (int i = 0; i < 2; ++i) {
    const int slot = tid + 256 * i;
    const int row = slot >> 2, s = slot & 3;
    const int cs = s ^ ((row >> 1) & 3);
    __builtin_amdgcn_global_load_lds(
        AS1(bgbase + (size_t)row * NN + kt * 32 + cs * 8), AS3(lb + row * 32 + s * 8), 16, 0, 0);
  }
}

__device__ __forceinline__ void cb_compute(
    const unsigned short* __restrict__ As, const unsigned short* __restrict__ Bs,
    f32x4 acc[4][4], int arow0, int brow0, int fr, int kb) {
  short8 af[4], bf[4];
  const int ck = kb >> 3;
#pragma unroll
  for (int tr = 0; tr < 4; ++tr) {
    const int row = arow0 + tr * 16 + fr;
    const int sl = ck ^ ((row >> 1) & 3);
    af[tr] = *reinterpret_cast<const short8*>(&As[row * 32 + sl * 8]);
  }
#pragma unroll
  for (int tc = 0; tc < 4; ++tc) {
    const int row = brow0 + tc * 16 + fr;
    const int sl = ck ^ ((row >> 1) & 3);
    bf[tc] = *reinterpret_cast<const short8*>(&Bs[row * 32 + sl * 8]);
  }
#pragma unroll
  for (int tr = 0; tr < 4; ++tr)
#pragma unroll
    for (int tc = 0; tc < 4; ++tc)
      acc[tr][tc] = __builtin_amdgcn_mfma_f32_16x16x32_bf16(af[tr], bf[tc], acc[tr][tc], 0, 0, 0);
}

__device__ __forceinline__ void compose_core(
    const unsigned short* __restrict__ agbase, const unsigned short* __restrict__ bgbase,
    unsigned short (*As)[BM * 32], unsigned short (*Bs)[BN * 32],
    f32x4 acc[4][4], int tid, int arow0, int brow0, int fr, int kb, int kt0, int nk) {
  cb_stage(agbase, bgbase, &As[0][0], &Bs[0][0], tid, kt0);
  if (nk >= 2) cb_stage(agbase, bgbase, &As[1][0], &Bs[1][0], tid, kt0 + 1);
#pragma unroll 1
  for (int i = 0; i < nk - 1; ++i) {
    asm volatile("s_waitcnt vmcnt(4)" ::: "memory");
    __builtin_amdgcn_s_barrier();
    __builtin_amdgcn_sched_barrier(0);
    if (i + 2 < nk) {
      const int nb = (i + 2) % 3;
      cb_stage(agbase, bgbase, &As[nb][0], &Bs[nb][0], tid, kt0 + i + 2);
    }
    cb_compute(&As[i % 3][0], &Bs[i % 3][0], acc, arow0, brow0, fr, kb);
  }
  asm volatile("s_waitcnt vmcnt(0)" ::: "memory");
  __builtin_amdgcn_s_barrier();
  __builtin_amdgcn_sched_barrier(0);
  cb_compute(&As[(nk - 1) % 3][0], &Bs[(nk - 1) % 3][0], acc, arow0, brow0, fr, kb);
}

// Direct-bf16 compose (L1, L2) with identity skip + K-support skip.
__device__ __forceinline__ void compose_body(
    const unsigned short* __restrict__ Xb, const unsigned short* __restrict__ Wb,
    unsigned short* __restrict__ Op, const float* __restrict__ sig, int b, bool tstore,
    int z0) {
  const int tid = threadIdx.x;
  const int lane = tid & 63, wave = tid >> 6;
  const int bm = b & 7, bn = b >> 3;
  const int m0 = bm * BM, n0 = bn * BN;
  const int wm = wave & 1, wn = wave >> 1;
  const int arow0 = wm * 64, brow0 = wn * 64;
  const int fr = lane & 15, kb = (lane >> 4) << 3;
  const int rq = (lane >> 4) << 2;

  if (m0 < z0 || n0 < z0) {
    if (!tstore) {
#pragma unroll
      for (int tc = 0; tc < 4; ++tc) {
        const int gc = n0 + brow0 + tc * 16 + fr;
        const float s = sig ? sig[gc] : 1.0f;
#pragma unroll
        for (int tr = 0; tr < 4; ++tr) {
          const int gr = m0 + arow0 + tr * 16 + rq;
#pragma unroll
          for (int q = 0; q < 4; ++q)
            Op[(size_t)(gr + q) * NN + gc] = f32_to_bf16_rne((gr + q == gc) ? s : 0.0f);
        }
      }
    } else {
#pragma unroll
      for (int tc = 0; tc < 4; ++tc) {
        const int gc = n0 + brow0 + tc * 16 + fr;
#pragma unroll
        for (int tr = 0; tr < 4; ++tr) {
          const int gr = m0 + arow0 + tr * 16 + rq;
          ushort4 pk;
          pk.x = f32_to_bf16_rne((gr + 0 == gc) ? 1.0f : 0.0f);
          pk.y = f32_to_bf16_rne((gr + 1 == gc) ? 1.0f : 0.0f);
          pk.z = f32_to_bf16_rne((gr + 2 == gc) ? 1.0f : 0.0f);
          pk.w = f32_to_bf16_rne((gr + 3 == gc) ? 1.0f : 0.0f);
          *reinterpret_cast<ushort4*>(&Op[(size_t)gc * NN + gr]) = pk;
        }
      }
    }
    return;
  }

  __shared__ unsigned short As[3][BM * 32];
  __shared__ unsigned short Bs[3][BN * 32];
  f32x4 acc[4][4];
#pragma unroll
  for (int a = 0; a < 4; ++a)
#pragma unroll
    for (int bb = 0; bb < 4; ++bb) acc[a][bb] = 0.f;

  const int kt0 = z0 >> 5;
  const int nk = 32 - kt0;
  compose_core(Xb + (size_t)m0 * NN, Wb + (size_t)n0 * NN, As, Bs, acc,
               tid, arow0, brow0, fr, kb, kt0, nk);

  if (!tstore) {
#pragma unroll
    for (int tc = 0; tc < 4; ++tc) {
      const int gc = n0 + brow0 + tc * 16 + fr;
      const float s = sig ? sig[gc] : 1.0f;
#pragma unroll
      for (int tr = 0; tr < 4; ++tr) {
        const int gr = m0 + arow0 + tr * 16 + rq;
#pragma unroll
        for (int q = 0; q < 4; ++q) {
          Op[(size_t)(gr + q) * NN + gc] = f32_to_bf16_rne(acc[tr][tc][q] * s);
        }
      }
    }
  } else {
#pragma unroll
    for (int tc = 0; tc < 4; ++tc) {
      const int gc = n0 + brow0 + tc * 16 + fr;
#pragma unroll
      for (int tr = 0; tr < 4; ++tr) {
        const int gr = m0 + arow0 + tr * 16 + rq;
        ushort4 pk;
        pk.x = f32_to_bf16_rne(acc[tr][tc][0]);
        pk.y = f32_to_bf16_rne(acc[tr][tc][1]);
        pk.z = f32_to_bf16_rne(acc[tr][tc][2]);
        pk.w = f32_to_bf16_rne(acc[tr][tc][3]);
        *reinterpret_cast<ushort4*>(&Op[(size_t)gc * NN + gr]) = pk;
      }
    }
  }
}

// K-split partial compose (L3, L4): f32 partial output, slice covers 16 k-steps.
__device__ __forceinline__ void compose_ks_body(
    const unsigned short* __restrict__ Xb, const unsigned short* __restrict__ Wb,
    float* __restrict__ Pp, int b, bool tstore, int slice) {
  const int tid = threadIdx.x;
  const int lane = tid & 63, wave = tid >> 6;
  const int bm = b & 7, bn = b >> 3;
  const int m0 = bm * BM, n0 = bn * BN;
  const int wm = wave & 1, wn = wave >> 1;
  const int arow0 = wm * 64, brow0 = wn * 64;
  const int fr = lane & 15, kb = (lane >> 4) << 3;
  const int rq = (lane >> 4) << 2;

  __shared__ unsigned short As[3][BM * 32];
  __shared__ unsigned short Bs[3][BN * 32];
  f32x4 acc[4][4];
#pragma unroll
  for (int a = 0; a < 4; ++a)
#pragma unroll
    for (int bb = 0; bb < 4; ++bb) acc[a][bb] = 0.f;

  compose_core(Xb + (size_t)m0 * NN, Wb + (size_t)n0 * NN, As, Bs, acc,
               tid, arow0, brow0, fr, kb, slice * 16, 16);

  if (!tstore) {
#pragma unroll
    for (int tc = 0; tc < 4; ++tc) {
      const int gc = n0 + brow0 + tc * 16 + fr;
#pragma unroll
      for (int tr = 0; tr < 4; ++tr) {
        const int gr = m0 + arow0 + tr * 16 + rq;
#pragma unroll
        for (int q = 0; q < 4; ++q)
          Pp[(size_t)(gr + q) * NN + gc] = acc[tr][tc][q];
      }
    }
  } else {
#pragma unroll
    for (int tc = 0; tc < 4; ++tc) {
      const int gc = n0 + brow0 + tc * 16 + fr;
#pragma unroll
      for (int tr = 0; tr < 4; ++tr) {
        const int gr = m0 + arow0 + tr * 16 + rq;
        float4 v = {acc[tr][tc][0], acc[tr][tc][1], acc[tr][tc][2], acc[tr][tc][3]};
        *reinterpret_cast<float4*>(&Pp[(size_t)gc * NN + gr]) = v;  // gr%4==0
      }
    }
  }
}

// L1: direct bf16, z0 = U:256i / V:768-256i.
__global__ __launch_bounds__(256) void composeL1_kernel(
    const unsigned short* __restrict__ ch, unsigned short* __restrict__ P) {
  const int sub = blockIdx.x >> 6, b = blockIdx.x & 63;
  const int i = sub & 3;
  const unsigned short* x = ch + (size_t)((sub < 4 ? 0 : 8) + 2 * i) * ME;
  const int z0 = (sub < 4) ? (256 * i) : (768 - 256 * i);
  compose_body(x, x + ME, P + (size_t)sub * ME, nullptr, b, (i & 1) != 0, z0);
}

// L2: direct bf16, z0 = {0,512,512,0}.
__global__ __launch_bounds__(256) void composeL2_kernel(
    const unsigned short* __restrict__ P, unsigned short* __restrict__ Q) {
  const int sub = blockIdx.x >> 6, b = blockIdx.x & 63;
  const int z0 = (sub == 1 || sub == 2) ? 512 : 0;
  compose_body(P + (size_t)(2 * sub) * ME, P + (size_t)(2 * sub + 1) * ME,
               Q + (size_t)sub * ME, nullptr, b, (sub & 1) != 0, z0);
}

// L3 K-split-2: grid 256.
__global__ __launch_bounds__(256) void composeL3ks_kernel(
    const unsigned short* __restrict__ Q, float* __restrict__ P32) {
  const int sub = blockIdx.x >> 7, slice = (blockIdx.x >> 6) & 1, b = blockIdx.x & 63;
  const unsigned short* X = Q + (size_t)(2 * sub) * ME;
  const unsigned short* W = Q + (size_t)(2 * sub + 1) * ME;
  compose_ks_body(X, W, P32 + (size_t)(sub * 2 + slice) * ME, b, sub == 1, slice);
}

// L4 K-split-2: grid 128.
__global__ __launch_bounds__(256) void composeL4ks_kernel(
    const unsigned short* __restrict__ F, float* __restrict__ P32) {
  const int slice = blockIdx.x >> 6, b = blockIdx.x & 63;
  compose_ks_body(F + ME, F, P32 + (size_t)slice * ME, b, false, slice);
}

// fused L3 reduce: bid<1024 -> F (with sigma); else -> F+ME.
__global__ __launch_bounds__(256) void reduce2L3_kernel(
    const float* __restrict__ P32, const float* __restrict__ sig,
    unsigned short* __restrict__ F) {
  const int bid = blockIdx.x;
  const float* p0;
  const float* p1;
  const float* sg;
  unsigned short* out;
  size_t i4;
  if (bid < 1024) {
    p0 = P32; p1 = P32 + ME; sg = sig; out = F;
    i4 = (size_t)bid * 256 + threadIdx.x;
  } else {
    p0 = P32 + 2 * ME; p1 = P32 + 3 * ME; sg = nullptr; out = F + ME;
    i4 = (size_t)(bid - 1024) * 256 + threadIdx.x;
  }
  float4 a = reinterpret_cast<const float4*>(p0)[i4];
  float4 b = reinterpret_cast<const float4*>(p1)[i4];
  float4 s = {1.f, 1.f, 1.f, 1.f};
  if (sg) s = *reinterpret_cast<const float4*>(&sg[(i4 * 4) & 1023]);
  ushort4 o;
  o.x = f32_to_bf16_rne((a.x + b.x) * s.x);
  o.y = f32_to_bf16_rne((a.y + b.y) * s.y);
  o.z = f32_to_bf16_rne((a.z + b.z) * s.z);
  o.w = f32_to_bf16_rne((a.w + b.w) * s.w);
  reinterpret_cast<ushort4*>(out)[i4] = o;
}

// reduce2 (single, for L4)
__global__ __launch_bounds__(256) void reduce2_kernel(
    const float* __restrict__ p0, const float* __restrict__ p1,
    const float* __restrict__ sig, unsigned short* __restrict__ out) {
  const size_t i4 = (size_t)blockIdx.x * 256 + threadIdx.x;
  float4 a = reinterpret_cast<const float4*>(p0)[i4];
  float4 b = reinterpret_cast<const float4*>(p1)[i4];
  float4 s = {1.f, 1.f, 1.f, 1.f};
  if (sig) s = *reinterpret_cast<const float4*>(&sig[(i4 * 4) & 1023]);
  ushort4 o;
  o.x = f32_to_bf16_rne((a.x + b.x) * s.x);
  o.y = f32_to_bf16_rne((a.y + b.y) * s.y);
  o.z = f32_to_bf16_rne((a.z + b.z) * s.z);
  o.w = f32_to_bf16_rne((a.w + b.w) * s.w);
  reinterpret_cast<ushort4*>(out)[i4] = o;
}

// -------------------- gemm256 (unchanged) --------------------
__global__ __launch_bounds__(512) void gemm256_kernel(
    const unsigned short* __restrict__ Xb, const unsigned short* __restrict__ Mt,
    const float* __restrict__ bias, float* __restrict__ Out) {
  __shared__ unsigned short As[3][256 * 32];
  __shared__ unsigned short Bs[3][128 * 32];
  const int tid = threadIdx.x;
  const int lane = tid & 63, wave = tid >> 6;
  const int bm = blockIdx.x & 63, bn = blockIdx.x >> 6;
  const int m0 = bm * 256, n0 = bn * 128;
  const int wm = wave & 3, wn = wave >> 2;
  const int arow0 = wm * 64, brow0 = wn * 64;
  const int fr = lane & 15, kb = (lane >> 4) << 3;

  f32x4 acc[4][4];
#pragma unroll
  for (int a = 0; a < 4; ++a)
#pragma unroll
    for (int b = 0; b < 4; ++b) acc[a][b] = 0.f;

  const unsigned short* agbase = Xb + (size_t)m0 * NN;
  const unsigned short* bgbase = Mt + (size_t)n0 * NN;

#define G256_STAGE(B, KT)                                                        \
  {                                                                              \
    _Pragma("unroll")                                                            \
    for (int i = 0; i < 2; ++i) {                                                \
      const int slot = tid + 512 * i;                                            \
      const int row = slot >> 2, s = slot & 3;                                   \
      const int cs = s ^ ((row >> 1) & 3);                                       \
      __builtin_amdgcn_global_load_lds(                                          \
          AS1(agbase + (size_t)row * NN + (KT) * 32 + cs * 8),                   \
          AS3(&As[B][row * 32 + s * 8]), 16, 0, 0);                              \
    }                                                                            \
    {                                                                            \
      const int row = tid >> 2, s = tid & 3;                                     \
      const int cs = s ^ ((row >> 1) & 3);                                       \
      __builtin_amdgcn_global_load_lds(                                          \
          AS1(bgbase + (size_t)row * NN + (KT) * 32 + cs * 8),                   \
          AS3(&Bs[B][row * 32 + s * 8]), 16, 0, 0);                              \
    }                                                                            \
  }

#define G256_CMP(B)                                                              \
  {                                                                              \
    short8 af[4], bf4[4];                                                        \
    const int ck = kb >> 3;                                                      \
    _Pragma("unroll")                                                            \
    for (int tr = 0; tr < 4; ++tr) {                                             \
      const int row = arow0 + tr * 16 + fr;                                      \
      const int sl = ck ^ ((row >> 1) & 3);                                      \
      af[tr] = *reinterpret_cast<const short8*>(&As[B][row * 32 + sl * 8]);      \
    }                                                                            \
    _Pragma("unroll")                                                            \
    for (int tc = 0; tc < 4; ++tc) {                                             \
      const int row = brow0 + tc * 16 + fr;                                      \
      const int sl = ck ^ ((row >> 1) & 3);                                      \
      bf4[tc] = *reinterpret_cast<const short8*>(&Bs[B][row * 32 + sl * 8]);     \
    }                                                                            \
    _Pragma("unroll")                                                            \
    for (int tr = 0; tr < 4; ++tr)                                               \
      _Pragma("unroll")                                                          \
      for (int tc = 0; tc < 4; ++tc)                                             \
        acc[tr][tc] = __builtin_amdgcn_mfma_f32_16x16x32_bf16(af[tr], bf4[tc], acc[tr][tc], 0, 0, 0); \
  }

  G256_STAGE(0, 0)
  G256_STAGE(1, 1)
#pragma unroll 1
  for (int kt = 0; kt < 31; ++kt) {
    asm volatile("s_waitcnt vmcnt(3)" ::: "memory");
    __builtin_amdgcn_s_barrier();
    __builtin_amdgcn_sched_barrier(0);
    if (kt + 2 < 32) {
      const int nb = (kt + 2) % 3;
      G256_STAGE(nb, kt + 2)
    }
    G256_CMP(kt % 3)
  }
  asm volatile("s_waitcnt vmcnt(0)" ::: "memory");
  __builtin_amdgcn_s_barrier();
  __builtin_amdgcn_sched_barrier(0);
  G256_CMP(1)
#undef G256_STAGE
#undef G256_CMP

  const int rq = (lane >> 4) << 2;
#pragma unroll
  for (int tc = 0; tc < 4; ++tc) {
    const int gc = n0 + brow0 + tc * 16 + fr;
    const float bv = bias[gc];
#pragma unroll
    for (int tr = 0; tr < 4; ++tr) {
      const int gr = m0 + arow0 + tr * 16 + rq;
#pragma unroll
      for (int q = 0; q < 4; ++q) {
        Out[(size_t)(gr + q) * NN + gc] = acc[tr][tc][q] + bv;
      }
    }
  }
}

// -------------------- fallback gemm --------------------
__global__ __launch_bounds__(256) void gemm_fb_kernel(
    const float* __restrict__ X, const unsigned short* __restrict__ Mt,
    const float* __restrict__ bias, float* __restrict__ Out) {
  __shared__ float Af[2][BM * 32];
  __shared__ unsigned short Bsl[2][BN * 32];
  const int tid = threadIdx.x;
  const int lane = tid & 63, wave = tid >> 6;
  const int bm = blockIdx.x & 127;
  const int bn = blockIdx.x >> 7;
  const int m0 = bm * BM, n0 = bn * BN;
  const int wm = wave & 1, wn = wave >> 1;
  const int arow0 = wm * 64, brow0 = wn * 64;
  const int fr = lane & 15, kb = (lane >> 4) << 3;

  f32x4 acc[4][4];
#pragma unroll
  for (int a = 0; a < 4; ++a)
#pragma unroll
    for (int b = 0; b < 4; ++b) acc[a][b] = 0.f;

  const float* agbase = X + (size_t)m0 * NN;
  const unsigned short* bgbase = Mt + (size_t)n0 * NN;

#define FB_STAGE(PB, KT)                                                        \
  {                                                                             \
    _Pragma("unroll")                                                           \
    for (int i = 0; i < 4; ++i) {                                               \
      const int slot = tid + 256 * i;                                           \
      const int row = slot >> 3, s = slot & 7;                                  \
      __builtin_amdgcn_global_load_lds(                                         \
          AS1(agbase + (size_t)row * NN + (KT) * 32 + s * 4),                   \
          AS3(&Af[PB][row * 32 + s * 4]), 16, 0, 0);                            \
    }                                                                           \
    _Pragma("unroll")                                                           \
    for (int i = 0; i < 2; ++i) {                                               \
      const int slot = tid + 256 * i;                                           \
      const int row = slot >> 2, s = slot & 3;                                  \
      __builtin_amdgcn_global_load_lds(                                         \
          AS1(bgbase + (size_t)row * NN + (KT) * 32 + s * 8),                   \
          AS3(&Bsl[PB][row * 32 + s * 8]), 16, 0, 0);                           \
    }                                                                           \
  }

  FB_STAGE(0, 0)
  int pb = 0;
#pragma unroll 1
  for (int kt = 0; kt < 32; ++kt) {
    __syncthreads();
    if (kt + 1 < 32) FB_STAGE(pb ^ 1, kt + 1)
    {
      short8 af[4], bf[4];
      const int c0 = kb >> 2;
#pragma unroll
      for (int tr = 0; tr < 4; ++tr) {
        const int row = arow0 + tr * 16 + fr;
        const f32x4 a0 = *reinterpret_cast<const f32x4*>(&Af[pb][row * 32 + c0 * 4]);
        const f32x4 a1 = *reinterpret_cast<const f32x4*>(&Af[pb][row * 32 + (c0 + 1) * 4]);
        uint4 w;
        w.x = pack2bf(a0[0], a0[1]); w.y = pack2bf(a0[2], a0[3]);
        w.z = pack2bf(a1[0], a1[1]); w.w = pack2bf(a1[2], a1[3]);
        af[tr] = *reinterpret_cast<const short8*>(&w);
      }
#pragma unroll
      for (int tc = 0; tc < 4; ++tc) {
        const int row = brow0 + tc * 16 + fr;
        bf[tc] = *reinterpret_cast<const short8*>(&Bsl[pb][row * 32 + kb]);
      }
#pragma unroll
      for (int tr = 0; tr < 4; ++tr)
#pragma unroll
        for (int tc = 0; tc < 4; ++tc)
          acc[tr][tc] = __builtin_amdgcn_mfma_f32_16x16x32_bf16(af[tr], bf[tc], acc[tr][tc], 0, 0, 0);
    }
    pb ^= 1;
  }
#undef FB_STAGE

  const int rq = (lane >> 4) << 2;
#pragma unroll
  for (int tc = 0; tc < 4; ++tc) {
    const int gc = n0 + brow0 + tc * 16 + fr;
    const float bv = bias[gc];
#pragma unroll
    for (int tr = 0; tr < 4; ++tr) {
      const int gr = m0 + arow0 + tr * 16 + rq;
#pragma unroll
      for (int q = 0; q < 4; ++q) {
        Out[(size_t)(gr + q) * NN + gc] = acc[tr][tc][q] + bv;
      }
    }
  }
}

extern "C" void kernel_launch(void* const* d_in, const int* in_sizes, int n_in,
                              void* d_out, int out_size, void* d_ws, size_t ws_size,
                              hipStream_t stream) {
  const float* x = (const float*)d_in[0];
  const float* U = (const float*)d_in[1];
  const float* V = (const float*)d_in[2];
  const float* p = (const float*)d_in[3];
  const float* bias = (const float*)d_in[4];
  float* out = (float*)d_out;

  char* ws = (char*)d_ws;
  float* tau_u = (float*)(ws);
  float* tau_v = (float*)(ws + 4096);
  float* sigmas = (float*)(ws + 8192);
  float* T8all = (float*)(ws + 16384);                 // 64 KB
  unsigned short* Mt = (unsigned short*)(ws + 81920);  // 2 MB

  const size_t XB_OFF = 4u * 1024 * 1024;
  const size_t XB_BYTES = (size_t)NBATCH * NN * 2;     // 32 MB
  const bool fast = ws_size >= XB_OFF + XB_BYTES;
  unsigned short* Xb = (unsigned short*)(ws + XB_OFF);

  unsigned short* sc = (unsigned short*)d_out;
  unsigned short* chains = sc;
  unsigned short* P = sc + 16 * ME;
  unsigned short* Q = sc + 24 * ME;
  unsigned short* F = sc + 28 * ME;
  unsigned short* YThi = sc + 16 * ME;
  unsigned short* YTlo = sc + 18 * ME;
  unsigned short* WThi = sc + 20 * ME;
  unsigned short* WTlo = sc + 22 * ME;
  unsigned short* Yhi = sc + 24 * ME;
  unsigned short* Ylo = sc + 26 * ME;
  float* Gp = (float*)(sc + 28 * ME);
  float* G = (float*)sc;                               // chains region, dead until chainc
  float* Tg = (float*)(sc + ME);
  float* P32L3 = (float*)sc;                           // 4 x ME f32 = 16 MB
  float* P32L4 = (float*)(sc + 8 * ME);                // 2 x ME f32 = 8 MB

  fused_pre_kernel<<<fast ? 1668 : 644, 256, 0, stream>>>(
      x, U, V, p, tau_u, tau_v, sigmas, Xb, Yhi, Ylo, YThi, YTlo);
  fused_gram_kernel<<<384, 256, 0, stream>>>(U, V, tau_u, tau_v, T8all, Yhi, Ylo, Gp);
  gsum_tinit_kernel<<<1088, 256, 0, stream>>>(Gp, T8all, G, Tg);
  tmerge_kernel<8><<<128, 256, 0, stream>>>(G, Tg);
  tmerge_kernel<16><<<64, 256, 0, stream>>>(G, Tg);
  tmerge_kernel<32><<<32, 256, 0, stream>>>(G, Tg);
  tmerge_kernel<64><<<16, 256, 0, stream>>>(G, Tg);
  zw_kernel<<<128, 256, 0, stream>>>(Tg, YThi, YTlo, WThi, WTlo);
  chainc_kernel<<<1024, 256, 0, stream>>>(YThi, YTlo, WThi, WTlo, chains);
  composeL1_kernel<<<512, 256, 0, stream>>>(chains, P);
  composeL2_kernel<<<256, 256, 0, stream>>>(P, Q);
  composeL3ks_kernel<<<256, 256, 0, stream>>>(Q, P32L3);
  reduce2L3_kernel<<<2048, 256, 0, stream>>>(P32L3, sigmas, F);
  composeL4ks_kernel<<<128, 256, 0, stream>>>(F, P32L4);
  reduce2_kernel<<<1024, 256, 0, stream>>>(P32L4, P32L4 + ME, nullptr, Mt);
  if (fast) gemm256_kernel<<<512, 512, 0, stream>>>(Xb, Mt, bias, out);
  else gemm_fb_kernel<<<1024, 256, 0, stream>>>(x, Mt, bias, out);
}